// Round 6
// baseline (6738.077 us; speedup 1.0000x reference)
//
#include <hip/hip_runtime.h>
#include <hip/hip_bf16.h>

// Problem dims
#define SS 256
#define BB 512
#define II 46
#define HH 256
#define CC 40
#define SB (SS*BB)        // 131072 rows
#define G3 (3*HH)         // 768
#define EPSF 1e-5f
#define NPART (SB/64)     // 2048 bn partials

typedef __attribute__((ext_vector_type(8))) short bf16x8;
typedef __attribute__((ext_vector_type(4))) float f32x4;

// ---------------------------------------------------------------------------
// helpers
// ---------------------------------------------------------------------------
__device__ __forceinline__ unsigned short f2bf_rne(float f){
  unsigned u = __float_as_uint(f);
  unsigned r = (u + 0x7FFFu + ((u >> 16) & 1u)) >> 16;
  return (unsigned short)r;
}
__device__ __forceinline__ float bf2f(unsigned short b){
  return __uint_as_float(((unsigned)b) << 16);
}
__device__ __forceinline__ void cvt8(const float* v, bf16x8& hi, bf16x8& lo){
  #pragma unroll
  for (int e=0;e<8;e++){
    unsigned short hb = f2bf_rne(v[e]);
    hi[e] = (short)hb;
    lo[e] = (short)f2bf_rne(v[e] - bf2f(hb));
  }
}

// ---------------------------------------------------------------------------
// split f32 weight array -> bf16 {hi, lo} (precision-identical to in-GEMM split)
// ---------------------------------------------------------------------------
__global__ void split_w_k(const float* __restrict__ w, unsigned short* __restrict__ wh,
                          unsigned short* __restrict__ wl, int n){
  int i = blockIdx.x*256 + threadIdx.x;
  if (i >= n) return;
  float v = w[i];
  unsigned short hb = f2bf_rne(v);
  wh[i] = hb;
  wl[i] = f2bf_rne(v - bf2f(hb));
}

// ---------------------------------------------------------------------------
// h0[b,j] = sum_{c<6} X[0,b,40+c] * i2h_w[j,c] + i2h_b[j]  -> both carries
// ---------------------------------------------------------------------------
__global__ void h0_k(const float* __restrict__ X, const float* __restrict__ w,
                     const float* __restrict__ bias, float* __restrict__ h1c,
                     float* __restrict__ h2c){
  int b = blockIdx.x, jj = threadIdx.x;
  const float* p = X + (long long)b*II + (II - 6);
  float acc = bias[jj];
  #pragma unroll
  for (int c2=0;c2<6;c2++) acc = fmaf(p[c2], w[jj*6 + c2], acc);
  h1c[(long long)b*HH + jj] = acc;
  h2c[(long long)b*HH + jj] = acc;
}

// ---------------------------------------------------------------------------
// transpose whh (768x256) -> whhT (256x768), once per launch
// ---------------------------------------------------------------------------
__global__ void whht_k(const float* __restrict__ w, float* __restrict__ wt){
  int idx = blockIdx.x*blockDim.x + threadIdx.x;
  if (idx >= G3*HH) return;
  int u = idx / HH, k = idx - u*HH;      // w[u][k]
  wt[(size_t)k*G3 + u] = w[idx];
}

// ---------------------------------------------------------------------------
// Generic f32 GEMM (small-K ops: comb K=80, down/conv1 K=40).
// MODE 0: store; 1: store relu; 2: accumulate.
// XM 1: A is implicit [X | Mi] with row stride II (pack_xm fused away);
//       A = X base, A2 = Mi base, rows offset by r0.
// ---------------------------------------------------------------------------
template<int MODE, int XM>
__global__ void gemm_tn(const float* __restrict__ A, int lda,
                        const float* __restrict__ W, int ldw,
                        const float* __restrict__ bias,
                        float* __restrict__ Co, int ldc,
                        int Mrows, int N, int K,
                        const float* __restrict__ A2, long long r0)
{
  __shared__ __align__(16) float As[32][132];
  __shared__ __align__(16) float Ws[32][132];
  const int m0 = blockIdx.x*128, n0 = blockIdx.y*128;
  const int t  = threadIdx.x;
  const int tm = t >> 4, tn = t & 15;
  float acc[8][8];
  #pragma unroll
  for (int i=0;i<8;i++)
    #pragma unroll
    for (int j2=0;j2<8;j2++) acc[i][j2] = 0.f;

  for (int k0=0;k0<K;k0+=32){
    #pragma unroll
    for (int u=0;u<16;u++){
      int idx = u*256 + t;
      int r = idx >> 5, c = idx & 31;
      int gk = k0 + c;
      float av = 0.f, wv = 0.f;
      if (gk < K){
        int gm = m0 + r;
        if (gm < Mrows){
          if (XM){
            long long gr = r0 + gm;
            av = (gk < CC) ? A[gr*II + gk] : A2[gr*II + (gk - CC)];
          } else {
            av = A[(long long)gm*lda + gk];
          }
        }
        int gn = n0 + r;
        if (gn < N)     wv = W[(long long)gn*ldw + gk];
      }
      As[c][r] = av;
      Ws[c][r] = wv;
    }
    __syncthreads();
    #pragma unroll
    for (int kk=0;kk<32;kk++){
      const float4 a0 = *(const float4*)&As[kk][tm*8];
      const float4 a1 = *(const float4*)&As[kk][tm*8+4];
      const float4 b0 = *(const float4*)&Ws[kk][tn*8];
      const float4 b1 = *(const float4*)&Ws[kk][tn*8+4];
      const float av[8] = {a0.x,a0.y,a0.z,a0.w,a1.x,a1.y,a1.z,a1.w};
      const float bv[8] = {b0.x,b0.y,b0.z,b0.w,b1.x,b1.y,b1.z,b1.w};
      #pragma unroll
      for (int i=0;i<8;i++)
        #pragma unroll
        for (int j2=0;j2<8;j2++) acc[i][j2] = fmaf(av[i], bv[j2], acc[i][j2]);
    }
    __syncthreads();
  }
  #pragma unroll
  for (int i=0;i<8;i++){
    int gm = m0 + tm*8 + i;
    if (gm < Mrows){
      #pragma unroll
      for (int j2=0;j2<8;j2++){
        int gn = n0 + tn*8 + j2;
        if (gn < N){
          long long oi = (long long)gm*ldc + gn;
          float val = acc[i][j2] + bias[gn];
          if (MODE == 1) val = fmaxf(val, 0.f);
          if (MODE == 2) val += Co[oi];
          Co[oi] = val;
        }
      }
    }
  }
}

// ---------------------------------------------------------------------------
// Split-bf16 MFMA GEMM with PRE-SPLIT B (static weights split once on device):
// Co[m,n] = sum_k A[m][k]*W[n][k] + bias[n]; B staging = raw ushort8 loads.
// Identical arithmetic to the former in-kernel split (same hi/lo bits).
// MODE 0: store; MODE 2: accumulate. M,N % 128 == 0, K % 32 == 0.
// ---------------------------------------------------------------------------
template<int MODE>
__global__ __launch_bounds__(256) void gemm_mfp(
    const float* __restrict__ A, int lda,
    const unsigned short* __restrict__ Wh, const unsigned short* __restrict__ Wl, int ldw,
    const float* __restrict__ bias,
    float* __restrict__ Co, int ldc,
    int N, int K)
{
  __shared__ __align__(16) unsigned short Ah[128*32];
  __shared__ __align__(16) unsigned short Al[128*32];
  __shared__ __align__(16) unsigned short Bh[128*32];
  __shared__ __align__(16) unsigned short Bl[128*32];
  const int t = threadIdx.x;
  const int m0 = blockIdx.x*128, n0 = blockIdx.y*128;
  const int lane = t & 63, w = t >> 6;
  const int wm = (w & 1)*64, wn = (w >> 1)*64;
  const int fr = lane & 15, fg = lane >> 4;

  f32x4 acc[4][4];
  #pragma unroll
  for (int i=0;i<4;i++)
    #pragma unroll
    for (int j=0;j<4;j++){ f32x4 z; z[0]=0;z[1]=0;z[2]=0;z[3]=0; acc[i][j]=z; }

  for (int k0=0; k0<K; k0+=32){
    #pragma unroll
    for (int cc=0; cc<2; cc++){
      const int c   = t + cc*256;
      const int row = c >> 2, kg = c & 3;
      const int byte = row*64 + ((kg*16) ^ (((row>>1)&3)<<4));
      {
        const float* ap = A + (size_t)(m0+row)*lda + k0 + kg*8;
        float v[8];
        *(float4*)&v[0] = *(const float4*)ap;
        *(float4*)&v[4] = *(const float4*)(ap+4);
        bf16x8 hi, lo; cvt8(v, hi, lo);
        *(bf16x8*)((char*)Ah + byte) = hi;
        *(bf16x8*)((char*)Al + byte) = lo;
      }
      {
        const size_t off = (size_t)(n0+row)*ldw + k0 + kg*8;
        *(bf16x8*)((char*)Bh + byte) = *(const bf16x8*)&Wh[off];
        *(bf16x8*)((char*)Bl + byte) = *(const bf16x8*)&Wl[off];
      }
    }
    __syncthreads();
    bf16x8 ahi[4], alo[4], bhi[4], blo[4];
    #pragma unroll
    for (int mt=0; mt<4; mt++){
      const int r = wm + mt*16 + fr;
      const int byte = r*64 + ((fg*16) ^ (((r>>1)&3)<<4));
      ahi[mt] = *(const bf16x8*)((const char*)Ah + byte);
      alo[mt] = *(const bf16x8*)((const char*)Al + byte);
    }
    #pragma unroll
    for (int nt=0; nt<4; nt++){
      const int r = wn + nt*16 + fr;
      const int byte = r*64 + ((fg*16) ^ (((r>>1)&3)<<4));
      bhi[nt] = *(const bf16x8*)((const char*)Bh + byte);
      blo[nt] = *(const bf16x8*)((const char*)Bl + byte);
    }
    #pragma unroll
    for (int mt=0; mt<4; mt++)
      #pragma unroll
      for (int nt=0; nt<4; nt++){
        acc[mt][nt] = __builtin_amdgcn_mfma_f32_16x16x32_bf16(alo[mt], bhi[nt], acc[mt][nt], 0,0,0);
        acc[mt][nt] = __builtin_amdgcn_mfma_f32_16x16x32_bf16(ahi[mt], blo[nt], acc[mt][nt], 0,0,0);
        acc[mt][nt] = __builtin_amdgcn_mfma_f32_16x16x32_bf16(ahi[mt], bhi[nt], acc[mt][nt], 0,0,0);
      }
    __syncthreads();
  }

  #pragma unroll
  for (int mt=0; mt<4; mt++){
    #pragma unroll
    for (int nt=0; nt<4; nt++){
      const int col = n0 + wn + nt*16 + fr;
      const float bv = bias[col];
      #pragma unroll
      for (int i=0;i<4;i++){
        const int row = m0 + wm + mt*16 + fg*4 + i;
        const size_t oi = (size_t)row*ldc + col;
        float val = acc[mt][nt][i] + bv;
        if (MODE == 2) val += Co[oi];
        Co[oi] = val;
      }
    }
  }
}

// ---------------------------------------------------------------------------
// Dual-A fused out-projection GEMM with pre-split B (cw):
// Co[m,n] = A1[m]·W[n,0:256] + A2[m]·W[n,256:512] + bias[n]
// ---------------------------------------------------------------------------
__global__ __launch_bounds__(256) void gemm_mfp_dual(
    const float* __restrict__ A1, const float* __restrict__ A2,
    const unsigned short* __restrict__ Wh, const unsigned short* __restrict__ Wl,
    const float* __restrict__ bias,
    float* __restrict__ Co, int ldc, int N)
{
  __shared__ __align__(16) unsigned short Ah[128*32];
  __shared__ __align__(16) unsigned short Al[128*32];
  __shared__ __align__(16) unsigned short Bh[128*32];
  __shared__ __align__(16) unsigned short Bl[128*32];
  const int t = threadIdx.x;
  const int m0 = blockIdx.x*128, n0 = blockIdx.y*128;
  const int lane = t & 63, w = t >> 6;
  const int wm = (w & 1)*64, wn = (w >> 1)*64;
  const int fr = lane & 15, fg = lane >> 4;

  f32x4 acc[4][4];
  #pragma unroll
  for (int i=0;i<4;i++)
    #pragma unroll
    for (int j=0;j<4;j++){ f32x4 z; z[0]=0;z[1]=0;z[2]=0;z[3]=0; acc[i][j]=z; }

  for (int k0=0; k0<2*HH; k0+=32){
    const float* Abase = (k0 < HH) ? A1 : A2;
    const int    kofs  = (k0 < HH) ? k0 : (k0 - HH);
    #pragma unroll
    for (int cc=0; cc<2; cc++){
      const int c   = t + cc*256;
      const int row = c >> 2, kg = c & 3;
      const int byte = row*64 + ((kg*16) ^ (((row>>1)&3)<<4));
      {
        const float* ap = Abase + (size_t)(m0+row)*HH + kofs + kg*8;
        float v[8];
        *(float4*)&v[0] = *(const float4*)ap;
        *(float4*)&v[4] = *(const float4*)(ap+4);
        bf16x8 hi, lo; cvt8(v, hi, lo);
        *(bf16x8*)((char*)Ah + byte) = hi;
        *(bf16x8*)((char*)Al + byte) = lo;
      }
      {
        const size_t off = (size_t)(n0+row)*(2*HH) + k0 + kg*8;
        *(bf16x8*)((char*)Bh + byte) = *(const bf16x8*)&Wh[off];
        *(bf16x8*)((char*)Bl + byte) = *(const bf16x8*)&Wl[off];
      }
    }
    __syncthreads();
    bf16x8 ahi[4], alo[4], bhi[4], blo[4];
    #pragma unroll
    for (int mt=0; mt<4; mt++){
      const int r = wm + mt*16 + fr;
      const int byte = r*64 + ((fg*16) ^ (((r>>1)&3)<<4));
      ahi[mt] = *(const bf16x8*)((const char*)Ah + byte);
      alo[mt] = *(const bf16x8*)((const char*)Al + byte);
    }
    #pragma unroll
    for (int nt=0; nt<4; nt++){
      const int r = wn + nt*16 + fr;
      const int byte = r*64 + ((fg*16) ^ (((r>>1)&3)<<4));
      bhi[nt] = *(const bf16x8*)((const char*)Bh + byte);
      blo[nt] = *(const bf16x8*)((const char*)Bl + byte);
    }
    #pragma unroll
    for (int mt=0; mt<4; mt++)
      #pragma unroll
      for (int nt=0; nt<4; nt++){
        acc[mt][nt] = __builtin_amdgcn_mfma_f32_16x16x32_bf16(alo[mt], bhi[nt], acc[mt][nt], 0,0,0);
        acc[mt][nt] = __builtin_amdgcn_mfma_f32_16x16x32_bf16(ahi[mt], blo[nt], acc[mt][nt], 0,0,0);
        acc[mt][nt] = __builtin_amdgcn_mfma_f32_16x16x32_bf16(ahi[mt], bhi[nt], acc[mt][nt], 0,0,0);
      }
    __syncthreads();
  }

  #pragma unroll
  for (int mt=0; mt<4; mt++){
    #pragma unroll
    for (int nt=0; nt<4; nt++){
      const int col = n0 + wn + nt*16 + fr;
      const float bv = bias[col];
      #pragma unroll
      for (int i=0;i<4;i++){
        const int row = m0 + wm + mt*16 + fg*4 + i;
        const size_t oi = (size_t)row*ldc + col;
        Co[oi] = acc[mt][nt][i] + bv;
      }
    }
  }
}

// ---------------------------------------------------------------------------
// BatchNorm stats (64 rows/block -> 4x more blocks than the old 512-row
// version; 32 blocks on a 256-CU chip was badly underparallelized) + fold
// ---------------------------------------------------------------------------
__global__ void bn_partial_k(const float* __restrict__ Xc, float* __restrict__ ps,
                             float* __restrict__ pq, int pblk0){
  int blk = blockIdx.x, t = threadIdx.x;
  long long base = (long long)blk*64*HH;
  float s = 0.f, q = 0.f;
  for (int r=0;r<64;r++){
    float v = Xc[base + (long long)r*HH + t];
    s += v; q = fmaf(v, v, q);
  }
  ps[(size_t)(pblk0+blk)*HH + t] = s;
  pq[(size_t)(pblk0+blk)*HH + t] = q;
}

__global__ void bn_final_k(const float* __restrict__ ps, const float* __restrict__ pq,
                           const float* __restrict__ g, const float* __restrict__ b,
                           float* __restrict__ sc, float* __restrict__ sh){
  int t = threadIdx.x;
  double s = 0.0, q = 0.0;
  for (int i=0;i<NPART;i++){ s += (double)ps[(size_t)i*HH + t]; q += (double)pq[(size_t)i*HH + t]; }
  double mu  = s / (double)SB;
  double var = q / (double)SB - mu*mu;
  float scv = (float)((double)g[t] / sqrt(var + 1e-5));
  sc[t] = scv;
  sh[t] = (float)((double)b[t] - mu*(double)scv);
}

__global__ void fold_k(const float* __restrict__ w, const float* __restrict__ b,
                       const float* __restrict__ sc, const float* __restrict__ sh,
                       float* __restrict__ wf, float* __restrict__ bf, int K){
  int idx = blockIdx.x*blockDim.x + threadIdx.x;
  if (idx < 256*K){ int o = idx / K; wf[idx] = w[idx]*sc[o]; }
  if (idx < 256)  bf[idx] = b[idx]*sc[idx] + sh[idx];
}

// ---------------------------------------------------------------------------
// LayerNorm over last dim (256), out-of-place. One block per row.
// ---------------------------------------------------------------------------
__global__ void ln_rows_k(const float* __restrict__ Xi, float* __restrict__ Xo,
                          const float* __restrict__ g, const float* __restrict__ b){
  long long row = blockIdx.x;
  int t = threadIdx.x;
  float v = Xi[row*HH + t];
  float s = v, q = v*v;
  #pragma unroll
  for (int o=32;o>0;o>>=1){ s += __shfl_down(s,o); q += __shfl_down(q,o); }
  __shared__ float ssm[4], qqm[4];
  int w = t >> 6;
  if ((t & 63) == 0){ ssm[w] = s; qqm[w] = q; }
  __syncthreads();
  if (t == 0){ ssm[0] = ssm[0]+ssm[1]+ssm[2]+ssm[3]; qqm[0] = qqm[0]+qqm[1]+qqm[2]+qqm[3]; }
  __syncthreads();
  s = ssm[0]; q = qqm[0];
  float mu  = s * (1.f/HH);
  float var = q * (1.f/HH) - mu*mu;
  float rs  = rsqrtf(var + EPSF);
  Xo[row*HH + t] = (v - mu)*rs*g[t] + b[t];
}

// ---------------------------------------------------------------------------
// FUSED dual-GRU gate scan (proven R5 structure). Even blocks: GRU1(c);
// odd blocks: GRU2(c-1). Parity interleave keeps 16 CUs per weight image
// per XCD (R1: 32 CUs on ONE image thrashes L2). Body = proven 128x4
// k-split scan (unroll 4; R3 unroll-8 regressed; R4 rotation null).
// ---------------------------------------------------------------------------
#define DOT4(hv,A0,A1,A2,A3) \
  A0=fmaf(hv.x,w0.x,A0); A0=fmaf(hv.y,w1.x,A0); A0=fmaf(hv.z,w2.x,A0); A0=fmaf(hv.w,w3.x,A0); \
  A1=fmaf(hv.x,w0.y,A1); A1=fmaf(hv.y,w1.y,A1); A1=fmaf(hv.z,w2.y,A1); A1=fmaf(hv.w,w3.y,A1); \
  A2=fmaf(hv.x,w0.z,A2); A2=fmaf(hv.y,w1.z,A2); A2=fmaf(hv.z,w2.z,A2); A2=fmaf(hv.w,w3.z,A2); \
  A3=fmaf(hv.x,w0.w,A3); A3=fmaf(hv.y,w1.w,A3); A3=fmaf(hv.z,w2.w,A3); A3=fmaf(hv.w,w3.w,A3);

__global__ __launch_bounds__(768) void gru_scan_fused_k(
  const float* __restrict__ gi1, const float* __restrict__ w1T,
  const float* __restrict__ b1v, const float* __restrict__ m1v,
  float* __restrict__ hc1, float* __restrict__ Hh1o, int nst1,
  const float* __restrict__ gi2, const float* __restrict__ w2T,
  const float* __restrict__ b2v, const float* __restrict__ m2v,
  float* __restrict__ hc2, float* __restrict__ Hh2o, int nst2)
{
  const int gsel = blockIdx.x & 1;
  const int blk  = blockIdx.x >> 1;
  const float* gi    = gsel ? gi2 : gi1;
  const float* whhT  = gsel ? w2T : w1T;
  const float* bhh   = gsel ? b2v : b1v;
  const float* mask0 = gsel ? m2v : m1v;
  float* hcar        = gsel ? hc2 : hc1;
  float* Hh          = gsel ? Hh2o : Hh1o;
  const int nst      = gsel ? nst2 : nst1;
  if (nst <= 0) return;

  const int t  = threadIdx.x;
  const int b0 = blk*4;
  const int cg = t % 192;            // column group (4 cols)
  const int ks = t / 192;            // k-slice (64 k)
  const int c0 = cg*4;
  const int k0 = ks*64;
  __shared__ __align__(16) float h[4][260];
  __shared__ __align__(16) float part[4][4][776];
  __shared__ float mkz[4];

  const int uj = t & 255;            // update col (t < 512)
  const int ur = t >> 8;             // update rows ur, ur+2
  if (t < 512){
    h[ur  ][uj] = hcar[(size_t)(b0+ur  )*HH + uj];
    h[ur+2][uj] = hcar[(size_t)(b0+ur+2)*HH + uj];
  }
  float br=0.f, bz=0.f, bn_=0.f;
  if (t < 512){ br = bhh[uj]; bz = bhh[uj+HH]; bn_ = bhh[uj+2*HH]; }
  __syncthreads();

  const float* wbase = whhT + (size_t)k0*G3 + c0;

  for (int st=0; st<nst; ++st){
    float i0r=0,i0z=0,i0n=0, i1r=0,i1z=0,i1n=0;
    if (t < 512){
      const size_t ga = ((size_t)st*BB + b0 + ur  )*G3 + uj;
      const size_t gb = ((size_t)st*BB + b0 + ur+2)*G3 + uj;
      i0r=gi[ga]; i0z=gi[ga+HH]; i0n=gi[ga+2*HH];
      i1r=gi[gb]; i1z=gi[gb+HH]; i1n=gi[gb+2*HH];
    }
    if (t < 4) mkz[t] = mask0[(size_t)st*BB + b0 + t];

    float a00=0,a01=0,a02=0,a03=0;
    float a10=0,a11=0,a12=0,a13=0;
    float a20=0,a21=0,a22=0,a23=0;
    float a30=0,a31=0,a32=0,a33=0;
    #pragma unroll 4
    for (int kk=0; kk<64; kk+=4){
      const float4 w0 = *(const float4*)(wbase + (size_t)(kk  )*G3);
      const float4 w1 = *(const float4*)(wbase + (size_t)(kk+1)*G3);
      const float4 w2 = *(const float4*)(wbase + (size_t)(kk+2)*G3);
      const float4 w3 = *(const float4*)(wbase + (size_t)(kk+3)*G3);
      const float4 h0 = *(const float4*)&h[0][k0+kk];
      const float4 h1 = *(const float4*)&h[1][k0+kk];
      const float4 h2 = *(const float4*)&h[2][k0+kk];
      const float4 h3 = *(const float4*)&h[3][k0+kk];
      DOT4(h0,a00,a01,a02,a03);
      DOT4(h1,a10,a11,a12,a13);
      DOT4(h2,a20,a21,a22,a23);
      DOT4(h3,a30,a31,a32,a33);
    }
    *(float4*)&part[ks][0][c0] = make_float4(a00,a01,a02,a03);
    *(float4*)&part[ks][1][c0] = make_float4(a10,a11,a12,a13);
    *(float4*)&part[ks][2][c0] = make_float4(a20,a21,a22,a23);
    *(float4*)&part[ks][3][c0] = make_float4(a30,a31,a32,a33);
    __syncthreads();

    if (t < 512){
      {
        const int r_ = ur;
        const float ar = part[0][r_][uj]+part[1][r_][uj]+part[2][r_][uj]+part[3][r_][uj] + br;
        const float az = part[0][r_][uj+HH]+part[1][r_][uj+HH]+part[2][r_][uj+HH]+part[3][r_][uj+HH] + bz;
        const float an = part[0][r_][uj+2*HH]+part[1][r_][uj+2*HH]+part[2][r_][uj+2*HH]+part[3][r_][uj+2*HH] + bn_;
        const float rr = 1.f/(1.f + __expf(-(i0r + ar)));
        const float zz = 1.f/(1.f + __expf(-(i0z + az)));
        const float nn = tanhf(fmaf(rr, an, i0n));
        const float hold = h[r_][uj];
        const float m = mkz[r_];
        const float hnew = (1.f - zz)*nn + zz*hold;
        const float hv = hnew*m + hold*(1.f - m);
        h[r_][uj] = hv;
        Hh[((size_t)st*BB + b0 + r_)*HH + uj] = hv;
      }
      {
        const int r_ = ur + 2;
        const float ar = part[0][r_][uj]+part[1][r_][uj]+part[2][r_][uj]+part[3][r_][uj] + br;
        const float az = part[0][r_][uj+HH]+part[1][r_][uj+HH]+part[2][r_][uj+HH]+part[3][r_][uj+HH] + bz;
        const float an = part[0][r_][uj+2*HH]+part[1][r_][uj+2*HH]+part[2][r_][uj+2*HH]+part[3][r_][uj+2*HH] + bn_;
        const float rr = 1.f/(1.f + __expf(-(i1r + ar)));
        const float zz = 1.f/(1.f + __expf(-(i1z + az)));
        const float nn = tanhf(fmaf(rr, an, i1n));
        const float hold = h[r_][uj];
        const float m = mkz[r_];
        const float hnew = (1.f - zz)*nn + zz*hold;
        const float hv = hnew*m + hold*(1.f - m);
        h[r_][uj] = hv;
        Hh[((size_t)st*BB + b0 + r_)*HH + uj] = hv;
      }
    }
    __syncthreads();
  }
  if (t < 512){
    hcar[(size_t)(b0+ur  )*HH + uj] = h[ur  ][uj];
    hcar[(size_t)(b0+ur+2)*HH + uj] = h[ur+2][uj];
  }
}

// ---------------------------------------------------------------------------
// Head (fused LN2): x=LN2(row); relu(x@nn1.T+b1) -> LN(8) -> @nn2.T+b2.
// ---------------------------------------------------------------------------
__global__ void head_ln_k(const float* __restrict__ hx,
                          const float* __restrict__ g2, const float* __restrict__ b2,
                          const float* __restrict__ w1, const float* __restrict__ b1,
                          const float* __restrict__ g3, const float* __restrict__ b3,
                          const float* __restrict__ w2, const float* __restrict__ b2h,
                          float* __restrict__ outp, long long r0){
  long long row = blockIdx.x;
  int t = threadIdx.x;
  float v = hx[row*HH + t];
  float s = v, q = v*v;
  #pragma unroll
  for (int o=32;o>0;o>>=1){ s += __shfl_down(s,o); q += __shfl_down(q,o); }
  __shared__ float ssm[4], qqm[4];
  int w = t >> 6;
  if ((t & 63) == 0){ ssm[w] = s; qqm[w] = q; }
  __syncthreads();
  if (t == 0){ ssm[0] = ssm[0]+ssm[1]+ssm[2]+ssm[3]; qqm[0] = qqm[0]+qqm[1]+qqm[2]+qqm[3]; }
  __syncthreads();
  s = ssm[0]; q = qqm[0];
  float mu  = s * (1.f/HH);
  float var = q * (1.f/HH) - mu*mu;
  float rs  = rsqrtf(var + EPSF);
  __shared__ float xs[HH];
  xs[t] = (v - mu)*rs*g2[t] + b2[t];
  __syncthreads();
  int o = t >> 5, l = t & 31;
  const float* wv = w1 + o*HH;
  float acc = 0.f;
  for (int k=l;k<HH;k+=32) acc = fmaf(xs[k], wv[k], acc);
  #pragma unroll
  for (int d=16;d>0;d>>=1) acc += __shfl_down(acc, d, 32);
  __shared__ float a8[8];
  if (l == 0) a8[o] = fmaxf(acc + b1[o], 0.f);
  __syncthreads();
  if (t == 0){
    float ss = 0.f;
    #pragma unroll
    for (int i=0;i<8;i++) ss += a8[i];
    float m8 = ss*0.125f;
    float qq = 0.f;
    #pragma unroll
    for (int i=0;i<8;i++){ float d = a8[i]-m8; qq = fmaf(d,d,qq); }
    float r8 = rsqrtf(qq*0.125f + EPSF);
    float y0 = b2h[0], y1 = b2h[1];
    #pragma unroll
    for (int i=0;i<8;i++){
      float vv = (a8[i]-m8)*r8*g3[i] + b3[i];
      y0 = fmaf(vv, w2[i],   y0);
      y1 = fmaf(vv, w2[8+i], y1);
    }
    outp[(r0+row)*2+0] = y0; outp[(r0+row)*2+1] = y1;
  }
}

// ---------------------------------------------------------------------------
// Host launcher — fused-scan pipeline (R5) + R6 trims:
//  * Cxp overlays GI1 (GI1 dead after the scan; Cxp lives only after it)
//  * pack_xm fused into comb GEMM (XM mode)
//  * bn_partial 64 rows/block
//  * static weights pre-split to bf16 hi/lo (gemm_mfp / gemm_mfp_dual)
// ---------------------------------------------------------------------------
extern "C" void kernel_launch(void* const* d_in, const int* in_sizes, int n_in,
                              void* d_out, int out_size, void* d_ws, size_t ws_size,
                              hipStream_t stream) {
  const float* X      = (const float*)d_in[0];
  const float* Mi     = (const float*)d_in[1];
  const float* mask   = (const float*)d_in[2];
  const float* i2h_w  = (const float*)d_in[3];
  const float* i2h_b  = (const float*)d_in[4];
  const float* comb_w = (const float*)d_in[5];
  const float* comb_b = (const float*)d_in[6];
  const float* down_w = (const float*)d_in[7];
  const float* down_b = (const float*)d_in[8];
  const float* conv1_w= (const float*)d_in[9];
  const float* conv1_b= (const float*)d_in[10];
  const float* conv2_w= (const float*)d_in[11];
  const float* conv2_b= (const float*)d_in[12];
  const float* bn1_g  = (const float*)d_in[13];
  const float* bn1_b  = (const float*)d_in[14];
  const float* bn2_g  = (const float*)d_in[15];
  const float* bn2_b  = (const float*)d_in[16];
  const float* r1_wih = (const float*)d_in[17];
  const float* r1_whh = (const float*)d_in[18];
  const float* r1_bih = (const float*)d_in[19];
  const float* r1_bhh = (const float*)d_in[20];
  const float* r1_cw  = (const float*)d_in[21];
  const float* r1_cb  = (const float*)d_in[22];
  const float* r2_wih = (const float*)d_in[23];
  const float* r2_whh = (const float*)d_in[24];
  const float* r2_bih = (const float*)d_in[25];
  const float* r2_bhh = (const float*)d_in[26];
  const float* r2_cw  = (const float*)d_in[27];
  const float* r2_cb  = (const float*)d_in[28];
  const float* ln1_g  = (const float*)d_in[29];
  const float* ln1_b  = (const float*)d_in[30];
  const float* ln2_g  = (const float*)d_in[31];
  const float* ln2_b  = (const float*)d_in[32];
  const float* ln3_g  = (const float*)d_in[33];
  const float* ln3_b  = (const float*)d_in[34];
  const float* nn1_w  = (const float*)d_in[35];
  const float* nn1_b  = (const float*)d_in[36];
  const float* nn2_w  = (const float*)d_in[37];
  const float* nn2_b  = (const float*)d_in[38];
  float* outp = (float*)d_out;

  // tail floats: H1C,H2C | PS,PQ | SCv,SHv | W1F,B1F | W2F,B2F | W1T,W2T | XcF
  // + ushort region: C2{h,l} W2F{h,l} WI1{h,l} WI2{h,l} CW1{h,l} CW2{h,l}
  const size_t us_elems = 2*((size_t)HH*HH + (size_t)HH*HH + (size_t)G3*HH
                           + (size_t)G3*HH + (size_t)HH*2*HH + (size_t)HH*2*HH);
  const size_t tail_floats = 2*(size_t)BB*HH + 2*(size_t)NPART*HH + 2*HH
                           + (size_t)256*40 + 256 + (size_t)HH*HH + 256
                           + 2*(size_t)G3*HH + (size_t)SB*CC
                           + (us_elems + 1)/2;
  // per-chunk rows: A(256) + GI1(768, Cxp aliased) + GI2(768) + Ee(256)
  //               + Hh2(256) + Hx1(256) = 2560 floats/row
  int cands[6] = {256,128,64,32,16,8};
  int sc_chunk = 0;
  for (int ci=0; ci<6; ci++){
    size_t R = (size_t)512*cands[ci];
    size_t need = (R*2560 + tail_floats)*sizeof(float);
    if (need <= ws_size){ sc_chunk = cands[ci]; break; }
  }
  if (!sc_chunk) return;

  const size_t R = (size_t)512*sc_chunk;     // rows per chunk
  const int Ri = (int)R;
  const int nchunks = SB / Ri;

  float* wsf = (float*)d_ws;
  float* A   = wsf;                    // R*256  (res -> hx)
  float* GI1 = A + R*HH;               // R*768  gi for GRU1(c)
  float* Cxp = GI1;                    // ALIAS: GI1 dead after scan; Cxp lives after
  float* GI2 = GI1 + R*G3;             // R*768  gi for GRU2(c)
  float* Ee  = GI2 + R*G3;             // R*256  out1r -> Hh1
  float* Hh2 = Ee + R*HH;              // R*256  Hh of GRU2(c-1)
  float* Hx1 = Hh2 + R*HH;             // R*256  hx1(c) = LN1 out
  float* tl  = Hx1 + R*HH;
  float* H1C = tl;                     // BB*HH
  float* H2C = H1C + (size_t)BB*HH;
  float* PS  = H2C + (size_t)BB*HH;    // NPART*HH
  float* PQ  = PS  + (size_t)NPART*HH;
  float* SCv = PQ  + (size_t)NPART*HH; // HH
  float* SHv = SCv + HH;
  float* W1F = SHv + HH;               // 256*40
  float* B1F = W1F + (size_t)256*40;   // 256
  float* W2F = B1F + HH;               // 256*256
  float* B2F = W2F + (size_t)HH*HH;    // 256
  float* W1T = B2F + HH;               // 256*768 whhT (GRU1)
  float* W2T = W1T + (size_t)HH*G3;    // 256*768 whhT (GRU2)
  float* XcF = W2T + (size_t)HH*G3;    // SB*40 persisted comb output
  unsigned short* usb = (unsigned short*)(XcF + (size_t)SB*CC);
  unsigned short* C2H  = usb;                       // conv2_w raw split (HH*HH)
  unsigned short* C2L  = C2H  + (size_t)HH*HH;
  unsigned short* W2FH = C2L  + (size_t)HH*HH;      // folded conv2 (HH*HH)
  unsigned short* W2FL = W2FH + (size_t)HH*HH;
  unsigned short* WI1H = W2FL + (size_t)HH*HH;      // r1_wih (G3*HH)
  unsigned short* WI1L = WI1H + (size_t)G3*HH;
  unsigned short* WI2H = WI1L + (size_t)G3*HH;      // r2_wih (G3*HH)
  unsigned short* WI2L = WI2H + (size_t)G3*HH;
  unsigned short* CW1H = WI2L + (size_t)G3*HH;      // r1_cw (HH*2HH)
  unsigned short* CW1L = CW1H + (size_t)HH*2*HH;
  unsigned short* CW2H = CW1L + (size_t)HH*2*HH;    // r2_cw (HH*2HH)
  unsigned short* CW2L = CW2H + (size_t)HH*2*HH;

  // one-time transposes + static weight splits
  whht_k<<<(G3*HH + 255)/256, 256, 0, stream>>>(r1_whh, W1T);
  whht_k<<<(G3*HH + 255)/256, 256, 0, stream>>>(r2_whh, W2T);
  split_w_k<<<(HH*HH + 255)/256, 256, 0, stream>>>(conv2_w, C2H, C2L, HH*HH);
  split_w_k<<<(G3*HH + 255)/256, 256, 0, stream>>>(r1_wih, WI1H, WI1L, G3*HH);
  split_w_k<<<(G3*HH + 255)/256, 256, 0, stream>>>(r2_wih, WI2H, WI2L, G3*HH);
  split_w_k<<<(HH*2*HH + 255)/256, 256, 0, stream>>>(r1_cw, CW1H, CW1L, HH*2*HH);
  split_w_k<<<(HH*2*HH + 255)/256, 256, 0, stream>>>(r2_cw, CW2H, CW2L, HH*2*HH);

  const int MB = Ri/128;

  // ---------- pass A: comb (XM-fused) -> XcF, conv1, BN1 stats ----------
  for (int c=0;c<nchunks;c++){
    long long r0 = (long long)c*R;
    gemm_tn<0,1><<<dim3(MB,1), 256, 0, stream>>>(X, II, comb_w, 80, comb_b, XcF + r0*CC, CC, Ri, CC, 80, Mi, r0);
    gemm_tn<0,0><<<dim3(MB,2), 256, 0, stream>>>(XcF + r0*CC, CC, conv1_w, CC, conv1_b, Ee, HH, Ri, HH, CC, nullptr, 0);
    bn_partial_k<<<Ri/64, 256, 0, stream>>>(Ee, PS, PQ, (int)(r0/64));
  }
  bn_final_k<<<1, 256, 0, stream>>>(PS, PQ, bn1_g, bn1_b, SCv, SHv);
  fold_k<<<(256*40 + 255)/256, 256, 0, stream>>>(conv1_w, conv1_b, SCv, SHv, W1F, B1F, 40);

  // ---------- pass B: BN2 stats (conv2 raw on folded-relu out1) ----------
  for (int c=0;c<nchunks;c++){
    long long r0 = (long long)c*R;
    gemm_tn<1,0><<<dim3(MB,2), 256, 0, stream>>>(XcF + r0*CC, CC, W1F, CC, B1F, Ee, HH, Ri, HH, CC, nullptr, 0);
    gemm_mfp<0><<<dim3(MB,2), 256, 0, stream>>>(Ee, HH, C2H, C2L, HH, conv2_b, A, HH, HH, HH);
    bn_partial_k<<<Ri/64, 256, 0, stream>>>(A, PS, PQ, (int)(r0/64));
  }
  bn_final_k<<<1, 256, 0, stream>>>(PS, PQ, bn2_g, bn2_b, SCv, SHv);
  fold_k<<<(256*256 + 255)/256, 256, 0, stream>>>(conv2_w, conv2_b, SCv, SHv, W2F, B2F, 256);
  split_w_k<<<(HH*HH + 255)/256, 256, 0, stream>>>(W2F, W2FH, W2FL, HH*HH);

  // ---------- h0 -> carries ----------
  h0_k<<<BB, HH, 0, stream>>>(X, i2h_w, i2h_b, H1C, H2C);

  // ---------- pass C: pipelined main loop ----------
  for (int c=0;c<nchunks;c++){
    long long r0 = (long long)c*R;
    long long rp = r0 - (long long)R;   // previous chunk base (valid for c>0)
    // ---- S1(c): hx(c) and gi1(c)
    gemm_tn<0,0><<<dim3(MB,2), 256, 0, stream>>>(X + r0*II, II, down_w, CC, down_b, A, HH, Ri, HH, CC, nullptr, 0); // res
    gemm_tn<1,0><<<dim3(MB,2), 256, 0, stream>>>(XcF + r0*CC, CC, W1F, CC, B1F, Ee, HH, Ri, HH, CC, nullptr, 0);    // out1r
    gemm_mfp<2><<<dim3(MB,2), 256, 0, stream>>>(Ee, HH, W2FH, W2FL, HH, B2F, A, HH, HH, HH);                        // hx
    gemm_mfp<0><<<dim3(MB,6), 256, 0, stream>>>(A, HH, WI1H, WI1L, HH, r1_bih, GI1, G3, G3, HH);                    // gi1
    // ---- fused scan: GRU1(c) || GRU2(c-1)
    gru_scan_fused_k<<<2*(BB/4), 768, 0, stream>>>(
        GI1, W1T, r1_bhh, mask + r0, H1C, Ee, sc_chunk,
        GI2, W2T, r2_bhh, (c > 0) ? (mask + rp) : mask, H2C, Hh2, (c > 0) ? sc_chunk : 0);
    // ---- S3(c-1): finish previous chunk (Cxp = GI1 region, dead after scan)
    if (c > 0){
      gemm_mfp_dual<<<dim3(MB,2), 256, 0, stream>>>(Hx1, Hh2, CW2H, CW2L, r2_cb, Cxp, HH, HH);                      // outs2
      head_ln_k<<<Ri, 256, 0, stream>>>(Cxp, ln2_g, ln2_b, nn1_w, nn1_b, ln3_g, ln3_b, nn2_w, nn2_b, outp, rp);
    }
    // ---- S2(c): GRU1 out-projection, LN1, gi2(c)
    gemm_mfp_dual<<<dim3(MB,2), 256, 0, stream>>>(A, Ee, CW1H, CW1L, r1_cb, Cxp, HH, HH);                           // outs1
    ln_rows_k<<<Ri, 256, 0, stream>>>(Cxp, Hx1, ln1_g, ln1_b);                                                       // hx1(c)
    gemm_mfp<0><<<dim3(MB,6), 256, 0, stream>>>(Hx1, HH, WI2H, WI2L, HH, r2_bih, GI2, G3, G3, HH);                   // gi2(c)
  }
  // ---------- drain: GRU2(last chunk) ----------
  {
    long long rl = (long long)(nchunks-1)*R;
    gru_scan_fused_k<<<2*(BB/4), 768, 0, stream>>>(
        GI1, W1T, r1_bhh, mask, H1C, Ee, 0,
        GI2, W2T, r2_bhh, mask + rl, H2C, Hh2, sc_chunk);
    gemm_mfp_dual<<<dim3(MB,2), 256, 0, stream>>>(Hx1, Hh2, CW2H, CW2L, r2_cb, Cxp, HH, HH);
    head_ln_k<<<Ri, 256, 0, stream>>>(Cxp, ln2_g, ln2_b, nn1_w, nn1_b, ln3_g, ln3_b, nn2_w, nn2_b, outp, rl);
  }
}

// Round 7
// 6573.076 us; speedup vs baseline: 1.0251x; 1.0251x over previous
//
#include <hip/hip_runtime.h>
#include <hip/hip_bf16.h>

// Problem dims
#define SS 256
#define BB 512
#define II 46
#define HH 256
#define CC 40
#define SB (SS*BB)        // 131072 rows
#define G3 (3*HH)         // 768
#define EPSF 1e-5f
#define NPART (SB/64)     // 2048 bn partials

typedef __attribute__((ext_vector_type(8))) short bf16x8;
typedef __attribute__((ext_vector_type(4))) float f32x4;

// ---------------------------------------------------------------------------
// helpers
// ---------------------------------------------------------------------------
__device__ __forceinline__ unsigned short f2bf_rne(float f){
  unsigned u = __float_as_uint(f);
  unsigned r = (u + 0x7FFFu + ((u >> 16) & 1u)) >> 16;
  return (unsigned short)r;
}
__device__ __forceinline__ float bf2f(unsigned short b){
  return __uint_as_float(((unsigned)b) << 16);
}
__device__ __forceinline__ void cvt8(const float* v, bf16x8& hi, bf16x8& lo){
  #pragma unroll
  for (int e=0;e<8;e++){
    unsigned short hb = f2bf_rne(v[e]);
    hi[e] = (short)hb;
    lo[e] = (short)f2bf_rne(v[e] - bf2f(hb));
  }
}

// ---------------------------------------------------------------------------
// split f32 weight array -> bf16 {hi, lo}
// ---------------------------------------------------------------------------
__global__ void split_w_k(const float* __restrict__ w, unsigned short* __restrict__ wh,
                          unsigned short* __restrict__ wl, int n){
  int i = blockIdx.x*256 + threadIdx.x;
  if (i >= n) return;
  float v = w[i];
  unsigned short hb = f2bf_rne(v);
  wh[i] = hb;
  wl[i] = f2bf_rne(v - bf2f(hb));
}

// ---------------------------------------------------------------------------
// h0[b,j] = sum_{c<6} X[0,b,40+c] * i2h_w[j,c] + i2h_b[j]  -> both carries
// ---------------------------------------------------------------------------
__global__ void h0_k(const float* __restrict__ X, const float* __restrict__ w,
                     const float* __restrict__ bias, float* __restrict__ h1c,
                     float* __restrict__ h2c){
  int b = blockIdx.x, jj = threadIdx.x;
  const float* p = X + (long long)b*II + (II - 6);
  float acc = bias[jj];
  #pragma unroll
  for (int c2=0;c2<6;c2++) acc = fmaf(p[c2], w[jj*6 + c2], acc);
  h1c[(long long)b*HH + jj] = acc;
  h2c[(long long)b*HH + jj] = acc;
}

// ---------------------------------------------------------------------------
// transpose whh (768x256) -> whhT (256x768), once per launch
// ---------------------------------------------------------------------------
__global__ void whht_k(const float* __restrict__ w, float* __restrict__ wt){
  int idx = blockIdx.x*blockDim.x + threadIdx.x;
  if (idx >= G3*HH) return;
  int u = idx / HH, k = idx - u*HH;      // w[u][k]
  wt[(size_t)k*G3 + u] = w[idx];
}

// ---------------------------------------------------------------------------
// Generic f32 GEMM (small-K ops: comb K=80, conv1 K=40).
// MODE 0: store; 1: store relu; 2: accumulate.
// XM 1: A is implicit [X | Mi] with row stride II; A=X base, A2=Mi base, +r0.
// ---------------------------------------------------------------------------
template<int MODE, int XM>
__global__ void gemm_tn(const float* __restrict__ A, int lda,
                        const float* __restrict__ W, int ldw,
                        const float* __restrict__ bias,
                        float* __restrict__ Co, int ldc,
                        int Mrows, int N, int K,
                        const float* __restrict__ A2, long long r0)
{
  __shared__ __align__(16) float As[32][132];
  __shared__ __align__(16) float Ws[32][132];
  const int m0 = blockIdx.x*128, n0 = blockIdx.y*128;
  const int t  = threadIdx.x;
  const int tm = t >> 4, tn = t & 15;
  float acc[8][8];
  #pragma unroll
  for (int i=0;i<8;i++)
    #pragma unroll
    for (int j2=0;j2<8;j2++) acc[i][j2] = 0.f;

  for (int k0=0;k0<K;k0+=32){
    #pragma unroll
    for (int u=0;u<16;u++){
      int idx = u*256 + t;
      int r = idx >> 5, c = idx & 31;
      int gk = k0 + c;
      float av = 0.f, wv = 0.f;
      if (gk < K){
        int gm = m0 + r;
        if (gm < Mrows){
          if (XM){
            long long gr = r0 + gm;
            av = (gk < CC) ? A[gr*II + gk] : A2[gr*II + (gk - CC)];
          } else {
            av = A[(long long)gm*lda + gk];
          }
        }
        int gn = n0 + r;
        if (gn < N)     wv = W[(long long)gn*ldw + gk];
      }
      As[c][r] = av;
      Ws[c][r] = wv;
    }
    __syncthreads();
    #pragma unroll
    for (int kk=0;kk<32;kk++){
      const float4 a0 = *(const float4*)&As[kk][tm*8];
      const float4 a1 = *(const float4*)&As[kk][tm*8+4];
      const float4 b0 = *(const float4*)&Ws[kk][tn*8];
      const float4 b1 = *(const float4*)&Ws[kk][tn*8+4];
      const float av[8] = {a0.x,a0.y,a0.z,a0.w,a1.x,a1.y,a1.z,a1.w};
      const float bv[8] = {b0.x,b0.y,b0.z,b0.w,b1.x,b1.y,b1.z,b1.w};
      #pragma unroll
      for (int i=0;i<8;i++)
        #pragma unroll
        for (int j2=0;j2<8;j2++) acc[i][j2] = fmaf(av[i], bv[j2], acc[i][j2]);
    }
    __syncthreads();
  }
  #pragma unroll
  for (int i=0;i<8;i++){
    int gm = m0 + tm*8 + i;
    if (gm < Mrows){
      #pragma unroll
      for (int j2=0;j2<8;j2++){
        int gn = n0 + tn*8 + j2;
        if (gn < N){
          long long oi = (long long)gm*ldc + gn;
          float val = acc[i][j2] + bias[gn];
          if (MODE == 1) val = fmaxf(val, 0.f);
          if (MODE == 2) val += Co[oi];
          Co[oi] = val;
        }
      }
    }
  }
}

// ---------------------------------------------------------------------------
// Dual-output small-K GEMM (S1 fusion): over rows [0,Mrows) of a chunk:
//   Co1[m,n] = sum_k X[(r0+m)*II + k] * W1[n*CC + k] + b1[n]          (res)
//   Co2[m,n] = relu(sum_k A2[m*CC + k] * W2[n*CC + k] + b2[n])        (out1r)
// N=256, K=40 both. Same tiling/k-order as two gemm_tn calls -> bit-identical.
// ---------------------------------------------------------------------------
__global__ void gemm_tn_dual2(const float* __restrict__ Xb, long long r0,
                              const float* __restrict__ W1, const float* __restrict__ b1,
                              float* __restrict__ Co1,
                              const float* __restrict__ A2, const float* __restrict__ W2,
                              const float* __restrict__ b2, float* __restrict__ Co2,
                              int Mrows)
{
  __shared__ __align__(16) float As1[32][132];
  __shared__ __align__(16) float As2[32][132];
  __shared__ __align__(16) float Ws1[32][132];
  __shared__ __align__(16) float Ws2[32][132];
  const int m0 = blockIdx.x*128, n0 = blockIdx.y*128;
  const int t  = threadIdx.x;
  const int tm = t >> 4, tn = t & 15;
  float acc1[8][8], acc2[8][8];
  #pragma unroll
  for (int i=0;i<8;i++)
    #pragma unroll
    for (int j2=0;j2<8;j2++){ acc1[i][j2] = 0.f; acc2[i][j2] = 0.f; }

  for (int k0=0;k0<CC;k0+=32){
    #pragma unroll
    for (int u=0;u<16;u++){
      int idx = u*256 + t;
      int r = idx >> 5, c = idx & 31;
      int gk = k0 + c;
      float a1=0.f, a2=0.f, w1=0.f, w2=0.f;
      if (gk < CC){
        int gm = m0 + r;
        if (gm < Mrows){
          long long gr = r0 + gm;
          a1 = Xb[gr*II + gk];
          a2 = A2[(long long)gm*CC + gk];
        }
        int gn = n0 + r;
        w1 = W1[(long long)gn*CC + gk];
        w2 = W2[(long long)gn*CC + gk];
      }
      As1[c][r] = a1; As2[c][r] = a2;
      Ws1[c][r] = w1; Ws2[c][r] = w2;
    }
    __syncthreads();
    #pragma unroll
    for (int kk=0;kk<32;kk++){
      const float4 p0 = *(const float4*)&As1[kk][tm*8];
      const float4 p1 = *(const float4*)&As1[kk][tm*8+4];
      const float4 q0 = *(const float4*)&As2[kk][tm*8];
      const float4 q1 = *(const float4*)&As2[kk][tm*8+4];
      const float4 u0 = *(const float4*)&Ws1[kk][tn*8];
      const float4 u1 = *(const float4*)&Ws1[kk][tn*8+4];
      const float4 v0 = *(const float4*)&Ws2[kk][tn*8];
      const float4 v1 = *(const float4*)&Ws2[kk][tn*8+4];
      const float a1v[8] = {p0.x,p0.y,p0.z,p0.w,p1.x,p1.y,p1.z,p1.w};
      const float a2v[8] = {q0.x,q0.y,q0.z,q0.w,q1.x,q1.y,q1.z,q1.w};
      const float w1v[8] = {u0.x,u0.y,u0.z,u0.w,u1.x,u1.y,u1.z,u1.w};
      const float w2v[8] = {v0.x,v0.y,v0.z,v0.w,v1.x,v1.y,v1.z,v1.w};
      #pragma unroll
      for (int i=0;i<8;i++)
        #pragma unroll
        for (int j2=0;j2<8;j2++){
          acc1[i][j2] = fmaf(a1v[i], w1v[j2], acc1[i][j2]);
          acc2[i][j2] = fmaf(a2v[i], w2v[j2], acc2[i][j2]);
        }
    }
    __syncthreads();
  }
  #pragma unroll
  for (int i=0;i<8;i++){
    int gm = m0 + tm*8 + i;
    if (gm < Mrows){
      #pragma unroll
      for (int j2=0;j2<8;j2++){
        int gn = n0 + tn*8 + j2;
        long long oi = (long long)gm*HH + gn;
        Co1[oi] = acc1[i][j2] + b1[gn];
        Co2[oi] = fmaxf(acc2[i][j2] + b2[gn], 0.f);
      }
    }
  }
}

// ---------------------------------------------------------------------------
// Split-bf16 MFMA GEMM with PRE-SPLIT B. MODE 0: store; 2: accumulate.
// ---------------------------------------------------------------------------
template<int MODE>
__global__ __launch_bounds__(256) void gemm_mfp(
    const float* __restrict__ A, int lda,
    const unsigned short* __restrict__ Wh, const unsigned short* __restrict__ Wl, int ldw,
    const float* __restrict__ bias,
    float* __restrict__ Co, int ldc,
    int N, int K)
{
  __shared__ __align__(16) unsigned short Ah[128*32];
  __shared__ __align__(16) unsigned short Al[128*32];
  __shared__ __align__(16) unsigned short Bh[128*32];
  __shared__ __align__(16) unsigned short Bl[128*32];
  const int t = threadIdx.x;
  const int m0 = blockIdx.x*128, n0 = blockIdx.y*128;
  const int lane = t & 63, w = t >> 6;
  const int wm = (w & 1)*64, wn = (w >> 1)*64;
  const int fr = lane & 15, fg = lane >> 4;

  f32x4 acc[4][4];
  #pragma unroll
  for (int i=0;i<4;i++)
    #pragma unroll
    for (int j=0;j<4;j++){ f32x4 z; z[0]=0;z[1]=0;z[2]=0;z[3]=0; acc[i][j]=z; }

  for (int k0=0; k0<K; k0+=32){
    #pragma unroll
    for (int cc=0; cc<2; cc++){
      const int c   = t + cc*256;
      const int row = c >> 2, kg = c & 3;
      const int byte = row*64 + ((kg*16) ^ (((row>>1)&3)<<4));
      {
        const float* ap = A + (size_t)(m0+row)*lda + k0 + kg*8;
        float v[8];
        *(float4*)&v[0] = *(const float4*)ap;
        *(float4*)&v[4] = *(const float4*)(ap+4);
        bf16x8 hi, lo; cvt8(v, hi, lo);
        *(bf16x8*)((char*)Ah + byte) = hi;
        *(bf16x8*)((char*)Al + byte) = lo;
      }
      {
        const size_t off = (size_t)(n0+row)*ldw + k0 + kg*8;
        *(bf16x8*)((char*)Bh + byte) = *(const bf16x8*)&Wh[off];
        *(bf16x8*)((char*)Bl + byte) = *(const bf16x8*)&Wl[off];
      }
    }
    __syncthreads();
    bf16x8 ahi[4], alo[4], bhi[4], blo[4];
    #pragma unroll
    for (int mt=0; mt<4; mt++){
      const int r = wm + mt*16 + fr;
      const int byte = r*64 + ((fg*16) ^ (((r>>1)&3)<<4));
      ahi[mt] = *(const bf16x8*)((const char*)Ah + byte);
      alo[mt] = *(const bf16x8*)((const char*)Al + byte);
    }
    #pragma unroll
    for (int nt=0; nt<4; nt++){
      const int r = wn + nt*16 + fr;
      const int byte = r*64 + ((fg*16) ^ (((r>>1)&3)<<4));
      bhi[nt] = *(const bf16x8*)((const char*)Bh + byte);
      blo[nt] = *(const bf16x8*)((const char*)Bl + byte);
    }
    #pragma unroll
    for (int mt=0; mt<4; mt++)
      #pragma unroll
      for (int nt=0; nt<4; nt++){
        acc[mt][nt] = __builtin_amdgcn_mfma_f32_16x16x32_bf16(alo[mt], bhi[nt], acc[mt][nt], 0,0,0);
        acc[mt][nt] = __builtin_amdgcn_mfma_f32_16x16x32_bf16(ahi[mt], blo[nt], acc[mt][nt], 0,0,0);
        acc[mt][nt] = __builtin_amdgcn_mfma_f32_16x16x32_bf16(ahi[mt], bhi[nt], acc[mt][nt], 0,0,0);
      }
    __syncthreads();
  }

  #pragma unroll
  for (int mt=0; mt<4; mt++){
    #pragma unroll
    for (int nt=0; nt<4; nt++){
      const int col = n0 + wn + nt*16 + fr;
      const float bv = bias[col];
      #pragma unroll
      for (int i=0;i<4;i++){
        const int row = m0 + wm + mt*16 + fg*4 + i;
        const size_t oi = (size_t)row*ldc + col;
        float val = acc[mt][nt][i] + bv;
        if (MODE == 2) val += Co[oi];
        Co[oi] = val;
      }
    }
  }
}

// ---------------------------------------------------------------------------
// Dual-A fused out-projection GEMM with pre-split B (cw).
// ---------------------------------------------------------------------------
__global__ __launch_bounds__(256) void gemm_mfp_dual(
    const float* __restrict__ A1, const float* __restrict__ A2,
    const unsigned short* __restrict__ Wh, const unsigned short* __restrict__ Wl,
    const float* __restrict__ bias,
    float* __restrict__ Co, int ldc, int N)
{
  __shared__ __align__(16) unsigned short Ah[128*32];
  __shared__ __align__(16) unsigned short Al[128*32];
  __shared__ __align__(16) unsigned short Bh[128*32];
  __shared__ __align__(16) unsigned short Bl[128*32];
  const int t = threadIdx.x;
  const int m0 = blockIdx.x*128, n0 = blockIdx.y*128;
  const int lane = t & 63, w = t >> 6;
  const int wm = (w & 1)*64, wn = (w >> 1)*64;
  const int fr = lane & 15, fg = lane >> 4;

  f32x4 acc[4][4];
  #pragma unroll
  for (int i=0;i<4;i++)
    #pragma unroll
    for (int j=0;j<4;j++){ f32x4 z; z[0]=0;z[1]=0;z[2]=0;z[3]=0; acc[i][j]=z; }

  for (int k0=0; k0<2*HH; k0+=32){
    const float* Abase = (k0 < HH) ? A1 : A2;
    const int    kofs  = (k0 < HH) ? k0 : (k0 - HH);
    #pragma unroll
    for (int cc=0; cc<2; cc++){
      const int c   = t + cc*256;
      const int row = c >> 2, kg = c & 3;
      const int byte = row*64 + ((kg*16) ^ (((row>>1)&3)<<4));
      {
        const float* ap = Abase + (size_t)(m0+row)*HH + kofs + kg*8;
        float v[8];
        *(float4*)&v[0] = *(const float4*)ap;
        *(float4*)&v[4] = *(const float4*)(ap+4);
        bf16x8 hi, lo; cvt8(v, hi, lo);
        *(bf16x8*)((char*)Ah + byte) = hi;
        *(bf16x8*)((char*)Al + byte) = lo;
      }
      {
        const size_t off = (size_t)(n0+row)*(2*HH) + k0 + kg*8;
        *(bf16x8*)((char*)Bh + byte) = *(const bf16x8*)&Wh[off];
        *(bf16x8*)((char*)Bl + byte) = *(const bf16x8*)&Wl[off];
      }
    }
    __syncthreads();
    bf16x8 ahi[4], alo[4], bhi[4], blo[4];
    #pragma unroll
    for (int mt=0; mt<4; mt++){
      const int r = wm + mt*16 + fr;
      const int byte = r*64 + ((fg*16) ^ (((r>>1)&3)<<4));
      ahi[mt] = *(const bf16x8*)((const char*)Ah + byte);
      alo[mt] = *(const bf16x8*)((const char*)Al + byte);
    }
    #pragma unroll
    for (int nt=0; nt<4; nt++){
      const int r = wn + nt*16 + fr;
      const int byte = r*64 + ((fg*16) ^ (((r>>1)&3)<<4));
      bhi[nt] = *(const bf16x8*)((const char*)Bh + byte);
      blo[nt] = *(const bf16x8*)((const char*)Bl + byte);
    }
    #pragma unroll
    for (int mt=0; mt<4; mt++)
      #pragma unroll
      for (int nt=0; nt<4; nt++){
        acc[mt][nt] = __builtin_amdgcn_mfma_f32_16x16x32_bf16(alo[mt], bhi[nt], acc[mt][nt], 0,0,0);
        acc[mt][nt] = __builtin_amdgcn_mfma_f32_16x16x32_bf16(ahi[mt], blo[nt], acc[mt][nt], 0,0,0);
        acc[mt][nt] = __builtin_amdgcn_mfma_f32_16x16x32_bf16(ahi[mt], bhi[nt], acc[mt][nt], 0,0,0);
      }
    __syncthreads();
  }

  #pragma unroll
  for (int mt=0; mt<4; mt++){
    #pragma unroll
    for (int nt=0; nt<4; nt++){
      const int col = n0 + wn + nt*16 + fr;
      const float bv = bias[col];
      #pragma unroll
      for (int i=0;i<4;i++){
        const int row = m0 + wm + mt*16 + fg*4 + i;
        const size_t oi = (size_t)row*ldc + col;
        Co[oi] = acc[mt][nt][i] + bv;
      }
    }
  }
}

// ---------------------------------------------------------------------------
// BatchNorm stats (64 rows/block) + fold
// ---------------------------------------------------------------------------
__global__ void bn_partial_k(const float* __restrict__ Xc, float* __restrict__ ps,
                             float* __restrict__ pq, int pblk0){
  int blk = blockIdx.x, t = threadIdx.x;
  long long base = (long long)blk*64*HH;
  float s = 0.f, q = 0.f;
  for (int r=0;r<64;r++){
    float v = Xc[base + (long long)r*HH + t];
    s += v; q = fmaf(v, v, q);
  }
  ps[(size_t)(pblk0+blk)*HH + t] = s;
  pq[(size_t)(pblk0+blk)*HH + t] = q;
}

__global__ void bn_final_k(const float* __restrict__ ps, const float* __restrict__ pq,
                           const float* __restrict__ g, const float* __restrict__ b,
                           float* __restrict__ sc, float* __restrict__ sh){
  int t = threadIdx.x;
  double s = 0.0, q = 0.0;
  for (int i=0;i<NPART;i++){ s += (double)ps[(size_t)i*HH + t]; q += (double)pq[(size_t)i*HH + t]; }
  double mu  = s / (double)SB;
  double var = q / (double)SB - mu*mu;
  float scv = (float)((double)g[t] / sqrt(var + 1e-5));
  sc[t] = scv;
  sh[t] = (float)((double)b[t] - mu*(double)scv);
}

__global__ void fold_k(const float* __restrict__ w, const float* __restrict__ b,
                       const float* __restrict__ sc, const float* __restrict__ sh,
                       float* __restrict__ wf, float* __restrict__ bf, int K){
  int idx = blockIdx.x*blockDim.x + threadIdx.x;
  if (idx < 256*K){ int o = idx / K; wf[idx] = w[idx]*sc[o]; }
  if (idx < 256)  bf[idx] = b[idx]*sc[idx] + sh[idx];
}

// ---------------------------------------------------------------------------
// LayerNorm over last dim (256), out-of-place. One block per row.
// ---------------------------------------------------------------------------
__global__ void ln_rows_k(const float* __restrict__ Xi, float* __restrict__ Xo,
                          const float* __restrict__ g, const float* __restrict__ b){
  long long row = blockIdx.x;
  int t = threadIdx.x;
  float v = Xi[row*HH + t];
  float s = v, q = v*v;
  #pragma unroll
  for (int o=32;o>0;o>>=1){ s += __shfl_down(s,o); q += __shfl_down(q,o); }
  __shared__ float ssm[4], qqm[4];
  int w = t >> 6;
  if ((t & 63) == 0){ ssm[w] = s; qqm[w] = q; }
  __syncthreads();
  if (t == 0){ ssm[0] = ssm[0]+ssm[1]+ssm[2]+ssm[3]; qqm[0] = qqm[0]+qqm[1]+qqm[2]+qqm[3]; }
  __syncthreads();
  s = ssm[0]; q = qqm[0];
  float mu  = s * (1.f/HH);
  float var = q * (1.f/HH) - mu*mu;
  float rs  = rsqrtf(var + EPSF);
  Xo[row*HH + t] = (v - mu)*rs*g[t] + b[t];
}

// ---------------------------------------------------------------------------
// FUSED dual-GRU gate scan (proven R5 structure). Even blocks: GRU1(c);
// odd blocks: GRU2(c-1). Parity interleave keeps 16 CUs per weight image
// per XCD (R1: 32 CUs on ONE image thrashes L2). Body = proven 128x4
// k-split scan (unroll 4; R3 unroll-8 regressed; R4 rotation null).
// ---------------------------------------------------------------------------
#define DOT4(hv,A0,A1,A2,A3) \
  A0=fmaf(hv.x,w0.x,A0); A0=fmaf(hv.y,w1.x,A0); A0=fmaf(hv.z,w2.x,A0); A0=fmaf(hv.w,w3.x,A0); \
  A1=fmaf(hv.x,w0.y,A1); A1=fmaf(hv.y,w1.y,A1); A1=fmaf(hv.z,w2.y,A1); A1=fmaf(hv.w,w3.y,A1); \
  A2=fmaf(hv.x,w0.z,A2); A2=fmaf(hv.y,w1.z,A2); A2=fmaf(hv.z,w2.z,A2); A2=fmaf(hv.w,w3.z,A2); \
  A3=fmaf(hv.x,w0.w,A3); A3=fmaf(hv.y,w1.w,A3); A3=fmaf(hv.z,w2.w,A3); A3=fmaf(hv.w,w3.w,A3);

__global__ __launch_bounds__(768) void gru_scan_fused_k(
  const float* __restrict__ gi1, const float* __restrict__ w1T,
  const float* __restrict__ b1v, const float* __restrict__ m1v,
  float* __restrict__ hc1, float* __restrict__ Hh1o, int nst1,
  const float* __restrict__ gi2, const float* __restrict__ w2T,
  const float* __restrict__ b2v, const float* __restrict__ m2v,
  float* __restrict__ hc2, float* __restrict__ Hh2o, int nst2)
{
  const int gsel = blockIdx.x & 1;
  const int blk  = blockIdx.x >> 1;
  const float* gi    = gsel ? gi2 : gi1;
  const float* whhT  = gsel ? w2T : w1T;
  const float* bhh   = gsel ? b2v : b1v;
  const float* mask0 = gsel ? m2v : m1v;
  float* hcar        = gsel ? hc2 : hc1;
  float* Hh          = gsel ? Hh2o : Hh1o;
  const int nst      = gsel ? nst2 : nst1;
  if (nst <= 0) return;

  const int t  = threadIdx.x;
  const int b0 = blk*4;
  const int cg = t % 192;            // column group (4 cols)
  const int ks = t / 192;            // k-slice (64 k)
  const int c0 = cg*4;
  const int k0 = ks*64;
  __shared__ __align__(16) float h[4][260];
  __shared__ __align__(16) float part[4][4][776];
  __shared__ float mkz[4];

  const int uj = t & 255;            // update col (t < 512)
  const int ur = t >> 8;             // update rows ur, ur+2
  if (t < 512){
    h[ur  ][uj] = hcar[(size_t)(b0+ur  )*HH + uj];
    h[ur+2][uj] = hcar[(size_t)(b0+ur+2)*HH + uj];
  }
  float br=0.f, bz=0.f, bn_=0.f;
  if (t < 512){ br = bhh[uj]; bz = bhh[uj+HH]; bn_ = bhh[uj+2*HH]; }
  __syncthreads();

  const float* wbase = whhT + (size_t)k0*G3 + c0;

  for (int st=0; st<nst; ++st){
    float i0r=0,i0z=0,i0n=0, i1r=0,i1z=0,i1n=0;
    if (t < 512){
      const size_t ga = ((size_t)st*BB + b0 + ur  )*G3 + uj;
      const size_t gb = ((size_t)st*BB + b0 + ur+2)*G3 + uj;
      i0r=gi[ga]; i0z=gi[ga+HH]; i0n=gi[ga+2*HH];
      i1r=gi[gb]; i1z=gi[gb+HH]; i1n=gi[gb+2*HH];
    }
    if (t < 4) mkz[t] = mask0[(size_t)st*BB + b0 + t];

    float a00=0,a01=0,a02=0,a03=0;
    float a10=0,a11=0,a12=0,a13=0;
    float a20=0,a21=0,a22=0,a23=0;
    float a30=0,a31=0,a32=0,a33=0;
    #pragma unroll 4
    for (int kk=0; kk<64; kk+=4){
      const float4 w0 = *(const float4*)(wbase + (size_t)(kk  )*G3);
      const float4 w1 = *(const float4*)(wbase + (size_t)(kk+1)*G3);
      const float4 w2 = *(const float4*)(wbase + (size_t)(kk+2)*G3);
      const float4 w3 = *(const float4*)(wbase + (size_t)(kk+3)*G3);
      const float4 h0 = *(const float4*)&h[0][k0+kk];
      const float4 h1 = *(const float4*)&h[1][k0+kk];
      const float4 h2 = *(const float4*)&h[2][k0+kk];
      const float4 h3 = *(const float4*)&h[3][k0+kk];
      DOT4(h0,a00,a01,a02,a03);
      DOT4(h1,a10,a11,a12,a13);
      DOT4(h2,a20,a21,a22,a23);
      DOT4(h3,a30,a31,a32,a33);
    }
    *(float4*)&part[ks][0][c0] = make_float4(a00,a01,a02,a03);
    *(float4*)&part[ks][1][c0] = make_float4(a10,a11,a12,a13);
    *(float4*)&part[ks][2][c0] = make_float4(a20,a21,a22,a23);
    *(float4*)&part[ks][3][c0] = make_float4(a30,a31,a32,a33);
    __syncthreads();

    if (t < 512){
      {
        const int r_ = ur;
        const float ar = part[0][r_][uj]+part[1][r_][uj]+part[2][r_][uj]+part[3][r_][uj] + br;
        const float az = part[0][r_][uj+HH]+part[1][r_][uj+HH]+part[2][r_][uj+HH]+part[3][r_][uj+HH] + bz;
        const float an = part[0][r_][uj+2*HH]+part[1][r_][uj+2*HH]+part[2][r_][uj+2*HH]+part[3][r_][uj+2*HH] + bn_;
        const float rr = 1.f/(1.f + __expf(-(i0r + ar)));
        const float zz = 1.f/(1.f + __expf(-(i0z + az)));
        const float nn = tanhf(fmaf(rr, an, i0n));
        const float hold = h[r_][uj];
        const float m = mkz[r_];
        const float hnew = (1.f - zz)*nn + zz*hold;
        const float hv = hnew*m + hold*(1.f - m);
        h[r_][uj] = hv;
        Hh[((size_t)st*BB + b0 + r_)*HH + uj] = hv;
      }
      {
        const int r_ = ur + 2;
        const float ar = part[0][r_][uj]+part[1][r_][uj]+part[2][r_][uj]+part[3][r_][uj] + br;
        const float az = part[0][r_][uj+HH]+part[1][r_][uj+HH]+part[2][r_][uj+HH]+part[3][r_][uj+HH] + bz;
        const float an = part[0][r_][uj+2*HH]+part[1][r_][uj+2*HH]+part[2][r_][uj+2*HH]+part[3][r_][uj+2*HH] + bn_;
        const float rr = 1.f/(1.f + __expf(-(i1r + ar)));
        const float zz = 1.f/(1.f + __expf(-(i1z + az)));
        const float nn = tanhf(fmaf(rr, an, i1n));
        const float hold = h[r_][uj];
        const float m = mkz[r_];
        const float hnew = (1.f - zz)*nn + zz*hold;
        const float hv = hnew*m + hold*(1.f - m);
        h[r_][uj] = hv;
        Hh[((size_t)st*BB + b0 + r_)*HH + uj] = hv;
      }
    }
    __syncthreads();
  }
  if (t < 512){
    hcar[(size_t)(b0+ur  )*HH + uj] = h[ur  ][uj];
    hcar[(size_t)(b0+ur+2)*HH + uj] = h[ur+2][uj];
  }
}

// ---------------------------------------------------------------------------
// Head (fused LN2): x=LN2(row); relu(x@nn1.T+b1) -> LN(8) -> @nn2.T+b2.
// ---------------------------------------------------------------------------
__global__ void head_ln_k(const float* __restrict__ hx,
                          const float* __restrict__ g2, const float* __restrict__ b2,
                          const float* __restrict__ w1, const float* __restrict__ b1,
                          const float* __restrict__ g3, const float* __restrict__ b3,
                          const float* __restrict__ w2, const float* __restrict__ b2h,
                          float* __restrict__ outp, long long r0){
  long long row = blockIdx.x;
  int t = threadIdx.x;
  float v = hx[row*HH + t];
  float s = v, q = v*v;
  #pragma unroll
  for (int o=32;o>0;o>>=1){ s += __shfl_down(s,o); q += __shfl_down(q,o); }
  __shared__ float ssm[4], qqm[4];
  int w = t >> 6;
  if ((t & 63) == 0){ ssm[w] = s; qqm[w] = q; }
  __syncthreads();
  if (t == 0){ ssm[0] = ssm[0]+ssm[1]+ssm[2]+ssm[3]; qqm[0] = qqm[0]+qqm[1]+qqm[2]+qqm[3]; }
  __syncthreads();
  s = ssm[0]; q = qqm[0];
  float mu  = s * (1.f/HH);
  float var = q * (1.f/HH) - mu*mu;
  float rs  = rsqrtf(var + EPSF);
  __shared__ float xs[HH];
  xs[t] = (v - mu)*rs*g2[t] + b2[t];
  __syncthreads();
  int o = t >> 5, l = t & 31;
  const float* wv = w1 + o*HH;
  float acc = 0.f;
  for (int k=l;k<HH;k+=32) acc = fmaf(xs[k], wv[k], acc);
  #pragma unroll
  for (int d=16;d>0;d>>=1) acc += __shfl_down(acc, d, 32);
  __shared__ float a8[8];
  if (l == 0) a8[o] = fmaxf(acc + b1[o], 0.f);
  __syncthreads();
  if (t == 0){
    float ss = 0.f;
    #pragma unroll
    for (int i=0;i<8;i++) ss += a8[i];
    float m8 = ss*0.125f;
    float qq = 0.f;
    #pragma unroll
    for (int i=0;i<8;i++){ float d = a8[i]-m8; qq = fmaf(d,d,qq); }
    float r8 = rsqrtf(qq*0.125f + EPSF);
    float y0 = b2h[0], y1 = b2h[1];
    #pragma unroll
    for (int i=0;i<8;i++){
      float vv = (a8[i]-m8)*r8*g3[i] + b3[i];
      y0 = fmaf(vv, w2[i],   y0);
      y1 = fmaf(vv, w2[8+i], y1);
    }
    outp[(r0+row)*2+0] = y0; outp[(r0+row)*2+1] = y1;
  }
}

// ---------------------------------------------------------------------------
// Host launcher. R7: passes A/B use LARGE sweeps (1 + 2 chunks) with the
// pass-C per-chunk region as scratch (dead at that point) — cuts ~40 small
// dispatches; S1's down+out1r fused into one dual-output GEMM.
// ---------------------------------------------------------------------------
extern "C" void kernel_launch(void* const* d_in, const int* in_sizes, int n_in,
                              void* d_out, int out_size, void* d_ws, size_t ws_size,
                              hipStream_t stream) {
  const float* X      = (const float*)d_in[0];
  const float* Mi     = (const float*)d_in[1];
  const float* mask   = (const float*)d_in[2];
  const float* i2h_w  = (const float*)d_in[3];
  const float* i2h_b  = (const float*)d_in[4];
  const float* comb_w = (const float*)d_in[5];
  const float* comb_b = (const float*)d_in[6];
  const float* down_w = (const float*)d_in[7];
  const float* down_b = (const float*)d_in[8];
  const float* conv1_w= (const float*)d_in[9];
  const float* conv1_b= (const float*)d_in[10];
  const float* conv2_w= (const float*)d_in[11];
  const float* conv2_b= (const float*)d_in[12];
  const float* bn1_g  = (const float*)d_in[13];
  const float* bn1_b  = (const float*)d_in[14];
  const float* bn2_g  = (const float*)d_in[15];
  const float* bn2_b  = (const float*)d_in[16];
  const float* r1_wih = (const float*)d_in[17];
  const float* r1_whh = (const float*)d_in[18];
  const float* r1_bih = (const float*)d_in[19];
  const float* r1_bhh = (const float*)d_in[20];
  const float* r1_cw  = (const float*)d_in[21];
  const float* r1_cb  = (const float*)d_in[22];
  const float* r2_wih = (const float*)d_in[23];
  const float* r2_whh = (const float*)d_in[24];
  const float* r2_bih = (const float*)d_in[25];
  const float* r2_bhh = (const float*)d_in[26];
  const float* r2_cw  = (const float*)d_in[27];
  const float* r2_cb  = (const float*)d_in[28];
  const float* ln1_g  = (const float*)d_in[29];
  const float* ln1_b  = (const float*)d_in[30];
  const float* ln2_g  = (const float*)d_in[31];
  const float* ln2_b  = (const float*)d_in[32];
  const float* ln3_g  = (const float*)d_in[33];
  const float* ln3_b  = (const float*)d_in[34];
  const float* nn1_w  = (const float*)d_in[35];
  const float* nn1_b  = (const float*)d_in[36];
  const float* nn2_w  = (const float*)d_in[37];
  const float* nn2_b  = (const float*)d_in[38];
  float* outp = (float*)d_out;

  const size_t us_elems = 2*((size_t)HH*HH + (size_t)HH*HH + (size_t)G3*HH
                           + (size_t)G3*HH + (size_t)HH*2*HH + (size_t)HH*2*HH);
  const size_t tail_floats = 2*(size_t)BB*HH + 2*(size_t)NPART*HH + 2*HH
                           + (size_t)256*40 + 256 + (size_t)HH*HH + 256
                           + 2*(size_t)G3*HH + (size_t)SB*CC
                           + (us_elems + 1)/2;
  // per-chunk rows: A(256) + GI1(768, Cxp aliased) + GI2(768) + Ee(256)
  //               + Hh2(256) + Hx1(256) = 2560 floats/row
  int cands[6] = {256,128,64,32,16,8};
  int sc_chunk = 0;
  for (int ci=0; ci<6; ci++){
    size_t R = (size_t)512*cands[ci];
    size_t need = (R*2560 + tail_floats)*sizeof(float);
    // passes A/B also need SB*HH scratch inside the per-chunk region
    if (need <= ws_size && R*2560 >= (size_t)SB*HH){ sc_chunk = cands[ci]; break; }
  }
  if (!sc_chunk) return;

  const size_t R = (size_t)512*sc_chunk;     // rows per chunk
  const int Ri = (int)R;
  const int nchunks = SB / Ri;

  float* wsf = (float*)d_ws;
  float* A   = wsf;                    // R*256  (res -> hx)
  float* GI1 = A + R*HH;               // R*768  gi for GRU1(c)
  float* Cxp = GI1;                    // ALIAS: GI1 dead after scan; Cxp lives after
  float* GI2 = GI1 + R*G3;             // R*768  gi for GRU2(c)
  float* Ee  = GI2 + R*G3;             // R*256  out1r -> Hh1
  float* Hh2 = Ee + R*HH;              // R*256  Hh of GRU2(c-1)
  float* Hx1 = Hh2 + R*HH;             // R*256  hx1(c) = LN1 out
  float* tl  = Hx1 + R*HH;
  float* H1C = tl;                     // BB*HH
  float* H2C = H1C + (size_t)BB*HH;
  float* PS  = H2C + (size_t)BB*HH;    // NPART*HH
  float* PQ  = PS  + (size_t)NPART*HH;
  float* SCv = PQ  + (size_t)NPART*HH; // HH
  float* SHv = SCv + HH;
  float* W1F = SHv + HH;               // 256*40
  float* B1F = W1F + (size_t)256*40;   // 256
  float* W2F = B1F + HH;               // 256*256
  float* B2F = W2F + (size_t)HH*HH;    // 256
  float* W1T = B2F + HH;               // 256*768 whhT (GRU1)
  float* W2T = W1T + (size_t)HH*G3;    // 256*768 whhT (GRU2)
  float* XcF = W2T + (size_t)HH*G3;    // SB*40 persisted comb output
  unsigned short* usb = (unsigned short*)(XcF + (size_t)SB*CC);
  unsigned short* C2H  = usb;                       // conv2_w raw split (HH*HH)
  unsigned short* C2L  = C2H  + (size_t)HH*HH;
  unsigned short* W2FH = C2L  + (size_t)HH*HH;      // folded conv2 (HH*HH)
  unsigned short* W2FL = W2FH + (size_t)HH*HH;
  unsigned short* WI1H = W2FL + (size_t)HH*HH;      // r1_wih (G3*HH)
  unsigned short* WI1L = WI1H + (size_t)G3*HH;
  unsigned short* WI2H = WI1L + (size_t)G3*HH;      // r2_wih (G3*HH)
  unsigned short* WI2L = WI2H + (size_t)G3*HH;
  unsigned short* CW1H = WI2L + (size_t)G3*HH;      // r1_cw (HH*2HH)
  unsigned short* CW1L = CW1H + (size_t)HH*2*HH;
  unsigned short* CW2H = CW1L + (size_t)HH*2*HH;    // r2_cw (HH*2HH)
  unsigned short* CW2L = CW2H + (size_t)HH*2*HH;

  // one-time transposes + static weight splits
  whht_k<<<(G3*HH + 255)/256, 256, 0, stream>>>(r1_whh, W1T);
  whht_k<<<(G3*HH + 255)/256, 256, 0, stream>>>(r2_whh, W2T);
  split_w_k<<<(HH*HH + 255)/256, 256, 0, stream>>>(conv2_w, C2H, C2L, HH*HH);
  split_w_k<<<(G3*HH + 255)/256, 256, 0, stream>>>(r1_wih, WI1H, WI1L, G3*HH);
  split_w_k<<<(G3*HH + 255)/256, 256, 0, stream>>>(r2_wih, WI2H, WI2L, G3*HH);
  split_w_k<<<(HH*2*HH + 255)/256, 256, 0, stream>>>(r1_cw, CW1H, CW1L, HH*2*HH);
  split_w_k<<<(HH*2*HH + 255)/256, 256, 0, stream>>>(r2_cw, CW2H, CW2L, HH*2*HH);

  const int MB = Ri/128;

  // ---------- pass A: ONE sweep over all SB rows (scratch = per-chunk region) ----------
  {
    float* SA = wsf;                          // SB*HH scratch (33.5M <= R*2560)
    gemm_tn<0,1><<<dim3(SB/128,1), 256, 0, stream>>>(X, II, comb_w, 80, comb_b, XcF, CC, SB, CC, 80, Mi, 0);
    gemm_tn<0,0><<<dim3(SB/128,2), 256, 0, stream>>>(XcF, CC, conv1_w, CC, conv1_b, SA, HH, SB, HH, CC, nullptr, 0);
    bn_partial_k<<<SB/64, 256, 0, stream>>>(SA, PS, PQ, 0);
  }
  bn_final_k<<<1, 256, 0, stream>>>(PS, PQ, bn1_g, bn1_b, SCv, SHv);
  fold_k<<<(256*40 + 255)/256, 256, 0, stream>>>(conv1_w, conv1_b, SCv, SHv, W1F, B1F, 40);

  // ---------- pass B: TWO half-sweeps (needs 2x SB/2*HH scratch) ----------
  {
    float* SA2 = wsf;                         // SB/2*HH
    float* SB2 = wsf + (size_t)(SB/2)*HH;     // SB/2*HH
    for (int hlf=0; hlf<2; hlf++){
      long long r0 = (long long)hlf*(SB/2);
      gemm_tn<1,0><<<dim3(SB/256,2), 256, 0, stream>>>(XcF + r0*CC, CC, W1F, CC, B1F, SA2, HH, SB/2, HH, CC, nullptr, 0);
      gemm_mfp<0><<<dim3(SB/256,2), 256, 0, stream>>>(SA2, HH, C2H, C2L, HH, conv2_b, SB2, HH, HH, HH);
      bn_partial_k<<<(SB/2)/64, 256, 0, stream>>>(SB2, PS, PQ, (int)(r0/64));
    }
  }
  bn_final_k<<<1, 256, 0, stream>>>(PS, PQ, bn2_g, bn2_b, SCv, SHv);
  fold_k<<<(256*256 + 255)/256, 256, 0, stream>>>(conv2_w, conv2_b, SCv, SHv, W2F, B2F, 256);
  split_w_k<<<(HH*HH + 255)/256, 256, 0, stream>>>(W2F, W2FH, W2FL, HH*HH);

  // ---------- h0 -> carries ----------
  h0_k<<<BB, HH, 0, stream>>>(X, i2h_w, i2h_b, H1C, H2C);

  // ---------- pass C: pipelined main loop ----------
  for (int c=0;c<nchunks;c++){
    long long r0 = (long long)c*R;
    long long rp = r0 - (long long)R;   // previous chunk base (valid for c>0)
    // ---- S1(c): {res, out1r} fused, then hx, gi1
    gemm_tn_dual2<<<dim3(MB,2), 256, 0, stream>>>(X, r0, down_w, down_b, A,
                                                  XcF + r0*CC, W1F, B1F, Ee, Ri);
    gemm_mfp<2><<<dim3(MB,2), 256, 0, stream>>>(Ee, HH, W2FH, W2FL, HH, B2F, A, HH, HH, HH);     // hx
    gemm_mfp<0><<<dim3(MB,6), 256, 0, stream>>>(A, HH, WI1H, WI1L, HH, r1_bih, GI1, G3, G3, HH); // gi1
    // ---- fused scan: GRU1(c) || GRU2(c-1)
    gru_scan_fused_k<<<2*(BB/4), 768, 0, stream>>>(
        GI1, W1T, r1_bhh, mask + r0, H1C, Ee, sc_chunk,
        GI2, W2T, r2_bhh, (c > 0) ? (mask + rp) : mask, H2C, Hh2, (c > 0) ? sc_chunk : 0);
    // ---- S3(c-1): finish previous chunk (Cxp = GI1 region, dead after scan)
    if (c > 0){
      gemm_mfp_dual<<<dim3(MB,2), 256, 0, stream>>>(Hx1, Hh2, CW2H, CW2L, r2_cb, Cxp, HH, HH);   // outs2
      head_ln_k<<<Ri, 256, 0, stream>>>(Cxp, ln2_g, ln2_b, nn1_w, nn1_b, ln3_g, ln3_b, nn2_w, nn2_b, outp, rp);
    }
    // ---- S2(c): GRU1 out-projection, LN1, gi2(c)
    gemm_mfp_dual<<<dim3(MB,2), 256, 0, stream>>>(A, Ee, CW1H, CW1L, r1_cb, Cxp, HH, HH);        // outs1
    ln_rows_k<<<Ri, 256, 0, stream>>>(Cxp, Hx1, ln1_g, ln1_b);                                    // hx1(c)
    gemm_mfp<0><<<dim3(MB,6), 256, 0, stream>>>(Hx1, HH, WI2H, WI2L, HH, r2_bih, GI2, G3, G3, HH); // gi2(c)
  }
  // ---------- drain: GRU2(last chunk) ----------
  {
    long long rl = (long long)(nchunks-1)*R;
    gru_scan_fused_k<<<2*(BB/4), 768, 0, stream>>>(
        GI1, W1T, r1_bhh, mask, H1C, Ee, 0,
        GI2, W2T, r2_bhh, mask + rl, H2C, Hh2, sc_chunk);
    gemm_mfp_dual<<<dim3(MB,2), 256, 0, stream>>>(Hx1, Hh2, CW2H, CW2L, r2_cb, Cxp, HH, HH);
    head_ln_k<<<Ri, 256, 0, stream>>>(Cxp, ln2_g, ln2_b, nn1_w, nn1_b, ln3_g, ln3_b, nn2_w, nn2_b, outp, rl);
  }
}

// Round 8
// 6455.747 us; speedup vs baseline: 1.0437x; 1.0182x over previous
//
#include <hip/hip_runtime.h>
#include <hip/hip_bf16.h>

// Problem dims
#define SS 256
#define BB 512
#define II 46
#define HH 256
#define CC 40
#define SB (SS*BB)        // 131072 rows
#define G3 (3*HH)         // 768
#define EPSF 1e-5f
#define NPART (SB/64)     // 2048 bn partials

typedef __attribute__((ext_vector_type(8))) short bf16x8;
typedef __attribute__((ext_vector_type(4))) float f32x4;

// ---------------------------------------------------------------------------
// helpers
// ---------------------------------------------------------------------------
__device__ __forceinline__ unsigned short f2bf_rne(float f){
  unsigned u = __float_as_uint(f);
  unsigned r = (u + 0x7FFFu + ((u >> 16) & 1u)) >> 16;
  return (unsigned short)r;
}
__device__ __forceinline__ float bf2f(unsigned short b){
  return __uint_as_float(((unsigned)b) << 16);
}
__device__ __forceinline__ void cvt8(const float* v, bf16x8& hi, bf16x8& lo){
  #pragma unroll
  for (int e=0;e<8;e++){
    unsigned short hb = f2bf_rne(v[e]);
    hi[e] = (short)hb;
    lo[e] = (short)f2bf_rne(v[e] - bf2f(hb));
  }
}

// ---------------------------------------------------------------------------
// split f32 weight array -> bf16 {hi, lo}
// ---------------------------------------------------------------------------
__global__ void split_w_k(const float* __restrict__ w, unsigned short* __restrict__ wh,
                          unsigned short* __restrict__ wl, int n){
  int i = blockIdx.x*256 + threadIdx.x;
  if (i >= n) return;
  float v = w[i];
  unsigned short hb = f2bf_rne(v);
  wh[i] = hb;
  wl[i] = f2bf_rne(v - bf2f(hb));
}

// ---------------------------------------------------------------------------
// h0[b,j] = sum_{c<6} X[0,b,40+c] * i2h_w[j,c] + i2h_b[j]  -> both carries
// ---------------------------------------------------------------------------
__global__ void h0_k(const float* __restrict__ X, const float* __restrict__ w,
                     const float* __restrict__ bias, float* __restrict__ h1c,
                     float* __restrict__ h2c){
  int b = blockIdx.x, jj = threadIdx.x;
  const float* p = X + (long long)b*II + (II - 6);
  float acc = bias[jj];
  #pragma unroll
  for (int c2=0;c2<6;c2++) acc = fmaf(p[c2], w[jj*6 + c2], acc);
  h1c[(long long)b*HH + jj] = acc;
  h2c[(long long)b*HH + jj] = acc;
}

// ---------------------------------------------------------------------------
// transpose + bf16-convert whh (768x256) -> whhTb (256x768 bf16), once.
// R8: scan weights stored bf16 (RNE) — halves the per-step weight stream
// (786 -> 393 KB/CU), which is the scan's delivery-bound bottleneck.
// ---------------------------------------------------------------------------
__global__ void whht_bf_k(const float* __restrict__ w, unsigned short* __restrict__ wt){
  int idx = blockIdx.x*blockDim.x + threadIdx.x;
  if (idx >= G3*HH) return;
  int u = idx / HH, k = idx - u*HH;      // w[u][k]
  wt[(size_t)k*G3 + u] = f2bf_rne(w[idx]);
}

// ---------------------------------------------------------------------------
// Generic f32 GEMM (small-K ops: comb K=80, conv1 K=40).
// MODE 0: store; 1: store relu; 2: accumulate.
// XM 1: A is implicit [X | Mi] with row stride II; A=X base, A2=Mi base, +r0.
// ---------------------------------------------------------------------------
template<int MODE, int XM>
__global__ void gemm_tn(const float* __restrict__ A, int lda,
                        const float* __restrict__ W, int ldw,
                        const float* __restrict__ bias,
                        float* __restrict__ Co, int ldc,
                        int Mrows, int N, int K,
                        const float* __restrict__ A2, long long r0)
{
  __shared__ __align__(16) float As[32][132];
  __shared__ __align__(16) float Ws[32][132];
  const int m0 = blockIdx.x*128, n0 = blockIdx.y*128;
  const int t  = threadIdx.x;
  const int tm = t >> 4, tn = t & 15;
  float acc[8][8];
  #pragma unroll
  for (int i=0;i<8;i++)
    #pragma unroll
    for (int j2=0;j2<8;j2++) acc[i][j2] = 0.f;

  for (int k0=0;k0<K;k0+=32){
    #pragma unroll
    for (int u=0;u<16;u++){
      int idx = u*256 + t;
      int r = idx >> 5, c = idx & 31;
      int gk = k0 + c;
      float av = 0.f, wv = 0.f;
      if (gk < K){
        int gm = m0 + r;
        if (gm < Mrows){
          if (XM){
            long long gr = r0 + gm;
            av = (gk < CC) ? A[gr*II + gk] : A2[gr*II + (gk - CC)];
          } else {
            av = A[(long long)gm*lda + gk];
          }
        }
        int gn = n0 + r;
        if (gn < N)     wv = W[(long long)gn*ldw + gk];
      }
      As[c][r] = av;
      Ws[c][r] = wv;
    }
    __syncthreads();
    #pragma unroll
    for (int kk=0;kk<32;kk++){
      const float4 a0 = *(const float4*)&As[kk][tm*8];
      const float4 a1 = *(const float4*)&As[kk][tm*8+4];
      const float4 b0 = *(const float4*)&Ws[kk][tn*8];
      const float4 b1 = *(const float4*)&Ws[kk][tn*8+4];
      const float av[8] = {a0.x,a0.y,a0.z,a0.w,a1.x,a1.y,a1.z,a1.w};
      const float bv[8] = {b0.x,b0.y,b0.z,b0.w,b1.x,b1.y,b1.z,b1.w};
      #pragma unroll
      for (int i=0;i<8;i++)
        #pragma unroll
        for (int j2=0;j2<8;j2++) acc[i][j2] = fmaf(av[i], bv[j2], acc[i][j2]);
    }
    __syncthreads();
  }
  #pragma unroll
  for (int i=0;i<8;i++){
    int gm = m0 + tm*8 + i;
    if (gm < Mrows){
      #pragma unroll
      for (int j2=0;j2<8;j2++){
        int gn = n0 + tn*8 + j2;
        if (gn < N){
          long long oi = (long long)gm*ldc + gn;
          float val = acc[i][j2] + bias[gn];
          if (MODE == 1) val = fmaxf(val, 0.f);
          if (MODE == 2) val += Co[oi];
          Co[oi] = val;
        }
      }
    }
  }
}

// ---------------------------------------------------------------------------
// Dual-output small-K GEMM (S1 fusion): res + relu(out1) in one dispatch.
// ---------------------------------------------------------------------------
__global__ void gemm_tn_dual2(const float* __restrict__ Xb, long long r0,
                              const float* __restrict__ W1, const float* __restrict__ b1,
                              float* __restrict__ Co1,
                              const float* __restrict__ A2, const float* __restrict__ W2,
                              const float* __restrict__ b2, float* __restrict__ Co2,
                              int Mrows)
{
  __shared__ __align__(16) float As1[32][132];
  __shared__ __align__(16) float As2[32][132];
  __shared__ __align__(16) float Ws1[32][132];
  __shared__ __align__(16) float Ws2[32][132];
  const int m0 = blockIdx.x*128, n0 = blockIdx.y*128;
  const int t  = threadIdx.x;
  const int tm = t >> 4, tn = t & 15;
  float acc1[8][8], acc2[8][8];
  #pragma unroll
  for (int i=0;i<8;i++)
    #pragma unroll
    for (int j2=0;j2<8;j2++){ acc1[i][j2] = 0.f; acc2[i][j2] = 0.f; }

  for (int k0=0;k0<CC;k0+=32){
    #pragma unroll
    for (int u=0;u<16;u++){
      int idx = u*256 + t;
      int r = idx >> 5, c = idx & 31;
      int gk = k0 + c;
      float a1=0.f, a2=0.f, w1=0.f, w2=0.f;
      if (gk < CC){
        int gm = m0 + r;
        if (gm < Mrows){
          long long gr = r0 + gm;
          a1 = Xb[gr*II + gk];
          a2 = A2[(long long)gm*CC + gk];
        }
        int gn = n0 + r;
        w1 = W1[(long long)gn*CC + gk];
        w2 = W2[(long long)gn*CC + gk];
      }
      As1[c][r] = a1; As2[c][r] = a2;
      Ws1[c][r] = w1; Ws2[c][r] = w2;
    }
    __syncthreads();
    #pragma unroll
    for (int kk=0;kk<32;kk++){
      const float4 p0 = *(const float4*)&As1[kk][tm*8];
      const float4 p1 = *(const float4*)&As1[kk][tm*8+4];
      const float4 q0 = *(const float4*)&As2[kk][tm*8];
      const float4 q1 = *(const float4*)&As2[kk][tm*8+4];
      const float4 u0 = *(const float4*)&Ws1[kk][tn*8];
      const float4 u1 = *(const float4*)&Ws1[kk][tn*8+4];
      const float4 v0 = *(const float4*)&Ws2[kk][tn*8];
      const float4 v1 = *(const float4*)&Ws2[kk][tn*8+4];
      const float a1v[8] = {p0.x,p0.y,p0.z,p0.w,p1.x,p1.y,p1.z,p1.w};
      const float a2v[8] = {q0.x,q0.y,q0.z,q0.w,q1.x,q1.y,q1.z,q1.w};
      const float w1v[8] = {u0.x,u0.y,u0.z,u0.w,u1.x,u1.y,u1.z,u1.w};
      const float w2v[8] = {v0.x,v0.y,v0.z,v0.w,v1.x,v1.y,v1.z,v1.w};
      #pragma unroll
      for (int i=0;i<8;i++)
        #pragma unroll
        for (int j2=0;j2<8;j2++){
          acc1[i][j2] = fmaf(a1v[i], w1v[j2], acc1[i][j2]);
          acc2[i][j2] = fmaf(a2v[i], w2v[j2], acc2[i][j2]);
        }
    }
    __syncthreads();
  }
  #pragma unroll
  for (int i=0;i<8;i++){
    int gm = m0 + tm*8 + i;
    if (gm < Mrows){
      #pragma unroll
      for (int j2=0;j2<8;j2++){
        int gn = n0 + tn*8 + j2;
        long long oi = (long long)gm*HH + gn;
        Co1[oi] = acc1[i][j2] + b1[gn];
        Co2[oi] = fmaxf(acc2[i][j2] + b2[gn], 0.f);
      }
    }
  }
}

// ---------------------------------------------------------------------------
// Split-bf16 MFMA GEMM with PRE-SPLIT B. MODE 0: store; 2: accumulate.
// ---------------------------------------------------------------------------
template<int MODE>
__global__ __launch_bounds__(256) void gemm_mfp(
    const float* __restrict__ A, int lda,
    const unsigned short* __restrict__ Wh, const unsigned short* __restrict__ Wl, int ldw,
    const float* __restrict__ bias,
    float* __restrict__ Co, int ldc,
    int N, int K)
{
  __shared__ __align__(16) unsigned short Ah[128*32];
  __shared__ __align__(16) unsigned short Al[128*32];
  __shared__ __align__(16) unsigned short Bh[128*32];
  __shared__ __align__(16) unsigned short Bl[128*32];
  const int t = threadIdx.x;
  const int m0 = blockIdx.x*128, n0 = blockIdx.y*128;
  const int lane = t & 63, w = t >> 6;
  const int wm = (w & 1)*64, wn = (w >> 1)*64;
  const int fr = lane & 15, fg = lane >> 4;

  f32x4 acc[4][4];
  #pragma unroll
  for (int i=0;i<4;i++)
    #pragma unroll
    for (int j=0;j<4;j++){ f32x4 z; z[0]=0;z[1]=0;z[2]=0;z[3]=0; acc[i][j]=z; }

  for (int k0=0; k0<K; k0+=32){
    #pragma unroll
    for (int cc=0; cc<2; cc++){
      const int c   = t + cc*256;
      const int row = c >> 2, kg = c & 3;
      const int byte = row*64 + ((kg*16) ^ (((row>>1)&3)<<4));
      {
        const float* ap = A + (size_t)(m0+row)*lda + k0 + kg*8;
        float v[8];
        *(float4*)&v[0] = *(const float4*)ap;
        *(float4*)&v[4] = *(const float4*)(ap+4);
        bf16x8 hi, lo; cvt8(v, hi, lo);
        *(bf16x8*)((char*)Ah + byte) = hi;
        *(bf16x8*)((char*)Al + byte) = lo;
      }
      {
        const size_t off = (size_t)(n0+row)*ldw + k0 + kg*8;
        *(bf16x8*)((char*)Bh + byte) = *(const bf16x8*)&Wh[off];
        *(bf16x8*)((char*)Bl + byte) = *(const bf16x8*)&Wl[off];
      }
    }
    __syncthreads();
    bf16x8 ahi[4], alo[4], bhi[4], blo[4];
    #pragma unroll
    for (int mt=0; mt<4; mt++){
      const int r = wm + mt*16 + fr;
      const int byte = r*64 + ((fg*16) ^ (((r>>1)&3)<<4));
      ahi[mt] = *(const bf16x8*)((const char*)Ah + byte);
      alo[mt] = *(const bf16x8*)((const char*)Al + byte);
    }
    #pragma unroll
    for (int nt=0; nt<4; nt++){
      const int r = wn + nt*16 + fr;
      const int byte = r*64 + ((fg*16) ^ (((r>>1)&3)<<4));
      bhi[nt] = *(const bf16x8*)((const char*)Bh + byte);
      blo[nt] = *(const bf16x8*)((const char*)Bl + byte);
    }
    #pragma unroll
    for (int mt=0; mt<4; mt++)
      #pragma unroll
      for (int nt=0; nt<4; nt++){
        acc[mt][nt] = __builtin_amdgcn_mfma_f32_16x16x32_bf16(alo[mt], bhi[nt], acc[mt][nt], 0,0,0);
        acc[mt][nt] = __builtin_amdgcn_mfma_f32_16x16x32_bf16(ahi[mt], blo[nt], acc[mt][nt], 0,0,0);
        acc[mt][nt] = __builtin_amdgcn_mfma_f32_16x16x32_bf16(ahi[mt], bhi[nt], acc[mt][nt], 0,0,0);
      }
    __syncthreads();
  }

  #pragma unroll
  for (int mt=0; mt<4; mt++){
    #pragma unroll
    for (int nt=0; nt<4; nt++){
      const int col = n0 + wn + nt*16 + fr;
      const float bv = bias[col];
      #pragma unroll
      for (int i=0;i<4;i++){
        const int row = m0 + wm + mt*16 + fg*4 + i;
        const size_t oi = (size_t)row*ldc + col;
        float val = acc[mt][nt][i] + bv;
        if (MODE == 2) val += Co[oi];
        Co[oi] = val;
      }
    }
  }
}

// ---------------------------------------------------------------------------
// Dual-A fused out-projection GEMM with pre-split B (cw).
// ---------------------------------------------------------------------------
__global__ __launch_bounds__(256) void gemm_mfp_dual(
    const float* __restrict__ A1, const float* __restrict__ A2,
    const unsigned short* __restrict__ Wh, const unsigned short* __restrict__ Wl,
    const float* __restrict__ bias,
    float* __restrict__ Co, int ldc, int N)
{
  __shared__ __align__(16) unsigned short Ah[128*32];
  __shared__ __align__(16) unsigned short Al[128*32];
  __shared__ __align__(16) unsigned short Bh[128*32];
  __shared__ __align__(16) unsigned short Bl[128*32];
  const int t = threadIdx.x;
  const int m0 = blockIdx.x*128, n0 = blockIdx.y*128;
  const int lane = t & 63, w = t >> 6;
  const int wm = (w & 1)*64, wn = (w >> 1)*64;
  const int fr = lane & 15, fg = lane >> 4;

  f32x4 acc[4][4];
  #pragma unroll
  for (int i=0;i<4;i++)
    #pragma unroll
    for (int j=0;j<4;j++){ f32x4 z; z[0]=0;z[1]=0;z[2]=0;z[3]=0; acc[i][j]=z; }

  for (int k0=0; k0<2*HH; k0+=32){
    const float* Abase = (k0 < HH) ? A1 : A2;
    const int    kofs  = (k0 < HH) ? k0 : (k0 - HH);
    #pragma unroll
    for (int cc=0; cc<2; cc++){
      const int c   = t + cc*256;
      const int row = c >> 2, kg = c & 3;
      const int byte = row*64 + ((kg*16) ^ (((row>>1)&3)<<4));
      {
        const float* ap = Abase + (size_t)(m0+row)*HH + kofs + kg*8;
        float v[8];
        *(float4*)&v[0] = *(const float4*)ap;
        *(float4*)&v[4] = *(const float4*)(ap+4);
        bf16x8 hi, lo; cvt8(v, hi, lo);
        *(bf16x8*)((char*)Ah + byte) = hi;
        *(bf16x8*)((char*)Al + byte) = lo;
      }
      {
        const size_t off = (size_t)(n0+row)*(2*HH) + k0 + kg*8;
        *(bf16x8*)((char*)Bh + byte) = *(const bf16x8*)&Wh[off];
        *(bf16x8*)((char*)Bl + byte) = *(const bf16x8*)&Wl[off];
      }
    }
    __syncthreads();
    bf16x8 ahi[4], alo[4], bhi[4], blo[4];
    #pragma unroll
    for (int mt=0; mt<4; mt++){
      const int r = wm + mt*16 + fr;
      const int byte = r*64 + ((fg*16) ^ (((r>>1)&3)<<4));
      ahi[mt] = *(const bf16x8*)((const char*)Ah + byte);
      alo[mt] = *(const bf16x8*)((const char*)Al + byte);
    }
    #pragma unroll
    for (int nt=0; nt<4; nt++){
      const int r = wn + nt*16 + fr;
      const int byte = r*64 + ((fg*16) ^ (((r>>1)&3)<<4));
      bhi[nt] = *(const bf16x8*)((const char*)Bh + byte);
      blo[nt] = *(const bf16x8*)((const char*)Bl + byte);
    }
    #pragma unroll
    for (int mt=0; mt<4; mt++)
      #pragma unroll
      for (int nt=0; nt<4; nt++){
        acc[mt][nt] = __builtin_amdgcn_mfma_f32_16x16x32_bf16(alo[mt], bhi[nt], acc[mt][nt], 0,0,0);
        acc[mt][nt] = __builtin_amdgcn_mfma_f32_16x16x32_bf16(ahi[mt], blo[nt], acc[mt][nt], 0,0,0);
        acc[mt][nt] = __builtin_amdgcn_mfma_f32_16x16x32_bf16(ahi[mt], bhi[nt], acc[mt][nt], 0,0,0);
      }
    __syncthreads();
  }

  #pragma unroll
  for (int mt=0; mt<4; mt++){
    #pragma unroll
    for (int nt=0; nt<4; nt++){
      const int col = n0 + wn + nt*16 + fr;
      const float bv = bias[col];
      #pragma unroll
      for (int i=0;i<4;i++){
        const int row = m0 + wm + mt*16 + fg*4 + i;
        const size_t oi = (size_t)row*ldc + col;
        Co[oi] = acc[mt][nt][i] + bv;
      }
    }
  }
}

// ---------------------------------------------------------------------------
// BatchNorm stats (64 rows/block) + fold
// ---------------------------------------------------------------------------
__global__ void bn_partial_k(const float* __restrict__ Xc, float* __restrict__ ps,
                             float* __restrict__ pq, int pblk0){
  int blk = blockIdx.x, t = threadIdx.x;
  long long base = (long long)blk*64*HH;
  float s = 0.f, q = 0.f;
  for (int r=0;r<64;r++){
    float v = Xc[base + (long long)r*HH + t];
    s += v; q = fmaf(v, v, q);
  }
  ps[(size_t)(pblk0+blk)*HH + t] = s;
  pq[(size_t)(pblk0+blk)*HH + t] = q;
}

__global__ void bn_final_k(const float* __restrict__ ps, const float* __restrict__ pq,
                           const float* __restrict__ g, const float* __restrict__ b,
                           float* __restrict__ sc, float* __restrict__ sh){
  int t = threadIdx.x;
  double s = 0.0, q = 0.0;
  for (int i=0;i<NPART;i++){ s += (double)ps[(size_t)i*HH + t]; q += (double)pq[(size_t)i*HH + t]; }
  double mu  = s / (double)SB;
  double var = q / (double)SB - mu*mu;
  float scv = (float)((double)g[t] / sqrt(var + 1e-5));
  sc[t] = scv;
  sh[t] = (float)((double)b[t] - mu*(double)scv);
}

__global__ void fold_k(const float* __restrict__ w, const float* __restrict__ b,
                       const float* __restrict__ sc, const float* __restrict__ sh,
                       float* __restrict__ wf, float* __restrict__ bf, int K){
  int idx = blockIdx.x*blockDim.x + threadIdx.x;
  if (idx < 256*K){ int o = idx / K; wf[idx] = w[idx]*sc[o]; }
  if (idx < 256)  bf[idx] = b[idx]*sc[idx] + sh[idx];
}

// ---------------------------------------------------------------------------
// LayerNorm over last dim (256), out-of-place. One block per row.
// ---------------------------------------------------------------------------
__global__ void ln_rows_k(const float* __restrict__ Xi, float* __restrict__ Xo,
                          const float* __restrict__ g, const float* __restrict__ b){
  long long row = blockIdx.x;
  int t = threadIdx.x;
  float v = Xi[row*HH + t];
  float s = v, q = v*v;
  #pragma unroll
  for (int o=32;o>0;o>>=1){ s += __shfl_down(s,o); q += __shfl_down(q,o); }
  __shared__ float ssm[4], qqm[4];
  int w = t >> 6;
  if ((t & 63) == 0){ ssm[w] = s; qqm[w] = q; }
  __syncthreads();
  if (t == 0){ ssm[0] = ssm[0]+ssm[1]+ssm[2]+ssm[3]; qqm[0] = qqm[0]+qqm[1]+qqm[2]+qqm[3]; }
  __syncthreads();
  s = ssm[0]; q = qqm[0];
  float mu  = s * (1.f/HH);
  float var = q * (1.f/HH) - mu*mu;
  float rs  = rsqrtf(var + EPSF);
  Xo[row*HH + t] = (v - mu)*rs*g[t] + b[t];
}

// ---------------------------------------------------------------------------
// FUSED dual-GRU gate scan with BF16 WEIGHTS (R8).
// Even blocks: GRU1(c); odd: GRU2(c-1). Parity interleave keeps 16 CUs per
// weight image per XCD. Weights loaded as packed bf16 (uint2 = 4 weights),
// unpacked with shift/mask — halves the delivery-bound weight stream.
// Body otherwise = proven 128x4 k-split scan (unroll 4).
// ---------------------------------------------------------------------------
#define DOT4(hv,A0,A1,A2,A3) \
  A0=fmaf(hv.x,w0.x,A0); A0=fmaf(hv.y,w1.x,A0); A0=fmaf(hv.z,w2.x,A0); A0=fmaf(hv.w,w3.x,A0); \
  A1=fmaf(hv.x,w0.y,A1); A1=fmaf(hv.y,w1.y,A1); A1=fmaf(hv.z,w2.y,A1); A1=fmaf(hv.w,w3.y,A1); \
  A2=fmaf(hv.x,w0.z,A2); A2=fmaf(hv.y,w1.z,A2); A2=fmaf(hv.z,w2.z,A2); A2=fmaf(hv.w,w3.z,A2); \
  A3=fmaf(hv.x,w0.w,A3); A3=fmaf(hv.y,w1.w,A3); A3=fmaf(hv.z,w2.w,A3); A3=fmaf(hv.w,w3.w,A3);

#define LDW_BF(dst, ofs) { \
  const uint2 u_ = *(const uint2*)(wbase + (size_t)(ofs)*G3); \
  dst.x = __uint_as_float(u_.x << 16); \
  dst.y = __uint_as_float(u_.x & 0xffff0000u); \
  dst.z = __uint_as_float(u_.y << 16); \
  dst.w = __uint_as_float(u_.y & 0xffff0000u); }

__global__ __launch_bounds__(768) void gru_scan_fused_k(
  const float* __restrict__ gi1, const unsigned short* __restrict__ w1T,
  const float* __restrict__ b1v, const float* __restrict__ m1v,
  float* __restrict__ hc1, float* __restrict__ Hh1o, int nst1,
  const float* __restrict__ gi2, const unsigned short* __restrict__ w2T,
  const float* __restrict__ b2v, const float* __restrict__ m2v,
  float* __restrict__ hc2, float* __restrict__ Hh2o, int nst2)
{
  const int gsel = blockIdx.x & 1;
  const int blk  = blockIdx.x >> 1;
  const float* gi    = gsel ? gi2 : gi1;
  const unsigned short* whhT = gsel ? w2T : w1T;
  const float* bhh   = gsel ? b2v : b1v;
  const float* mask0 = gsel ? m2v : m1v;
  float* hcar        = gsel ? hc2 : hc1;
  float* Hh          = gsel ? Hh2o : Hh1o;
  const int nst      = gsel ? nst2 : nst1;
  if (nst <= 0) return;

  const int t  = threadIdx.x;
  const int b0 = blk*4;
  const int cg = t % 192;            // column group (4 cols)
  const int ks = t / 192;            // k-slice (64 k)
  const int c0 = cg*4;
  const int k0 = ks*64;
  __shared__ __align__(16) float h[4][260];
  __shared__ __align__(16) float part[4][4][776];
  __shared__ float mkz[4];

  const int uj = t & 255;            // update col (t < 512)
  const int ur = t >> 8;             // update rows ur, ur+2
  if (t < 512){
    h[ur  ][uj] = hcar[(size_t)(b0+ur  )*HH + uj];
    h[ur+2][uj] = hcar[(size_t)(b0+ur+2)*HH + uj];
  }
  float br=0.f, bz=0.f, bn_=0.f;
  if (t < 512){ br = bhh[uj]; bz = bhh[uj+HH]; bn_ = bhh[uj+2*HH]; }
  __syncthreads();

  const unsigned short* wbase = whhT + (size_t)k0*G3 + c0;

  for (int st=0; st<nst; ++st){
    float i0r=0,i0z=0,i0n=0, i1r=0,i1z=0,i1n=0;
    if (t < 512){
      const size_t ga = ((size_t)st*BB + b0 + ur  )*G3 + uj;
      const size_t gb = ((size_t)st*BB + b0 + ur+2)*G3 + uj;
      i0r=gi[ga]; i0z=gi[ga+HH]; i0n=gi[ga+2*HH];
      i1r=gi[gb]; i1z=gi[gb+HH]; i1n=gi[gb+2*HH];
    }
    if (t < 4) mkz[t] = mask0[(size_t)st*BB + b0 + t];

    float a00=0,a01=0,a02=0,a03=0;
    float a10=0,a11=0,a12=0,a13=0;
    float a20=0,a21=0,a22=0,a23=0;
    float a30=0,a31=0,a32=0,a33=0;
    #pragma unroll 4
    for (int kk=0; kk<64; kk+=4){
      float4 w0, w1, w2, w3;
      LDW_BF(w0, kk  );
      LDW_BF(w1, kk+1);
      LDW_BF(w2, kk+2);
      LDW_BF(w3, kk+3);
      const float4 h0 = *(const float4*)&h[0][k0+kk];
      const float4 h1 = *(const float4*)&h[1][k0+kk];
      const float4 h2 = *(const float4*)&h[2][k0+kk];
      const float4 h3 = *(const float4*)&h[3][k0+kk];
      DOT4(h0,a00,a01,a02,a03);
      DOT4(h1,a10,a11,a12,a13);
      DOT4(h2,a20,a21,a22,a23);
      DOT4(h3,a30,a31,a32,a33);
    }
    *(float4*)&part[ks][0][c0] = make_float4(a00,a01,a02,a03);
    *(float4*)&part[ks][1][c0] = make_float4(a10,a11,a12,a13);
    *(float4*)&part[ks][2][c0] = make_float4(a20,a21,a22,a23);
    *(float4*)&part[ks][3][c0] = make_float4(a30,a31,a32,a33);
    __syncthreads();

    if (t < 512){
      {
        const int r_ = ur;
        const float ar = part[0][r_][uj]+part[1][r_][uj]+part[2][r_][uj]+part[3][r_][uj] + br;
        const float az = part[0][r_][uj+HH]+part[1][r_][uj+HH]+part[2][r_][uj+HH]+part[3][r_][uj+HH] + bz;
        const float an = part[0][r_][uj+2*HH]+part[1][r_][uj+2*HH]+part[2][r_][uj+2*HH]+part[3][r_][uj+2*HH] + bn_;
        const float rr = 1.f/(1.f + __expf(-(i0r + ar)));
        const float zz = 1.f/(1.f + __expf(-(i0z + az)));
        const float nn = tanhf(fmaf(rr, an, i0n));
        const float hold = h[r_][uj];
        const float m = mkz[r_];
        const float hnew = (1.f - zz)*nn + zz*hold;
        const float hv = hnew*m + hold*(1.f - m);
        h[r_][uj] = hv;
        Hh[((size_t)st*BB + b0 + r_)*HH + uj] = hv;
      }
      {
        const int r_ = ur + 2;
        const float ar = part[0][r_][uj]+part[1][r_][uj]+part[2][r_][uj]+part[3][r_][uj] + br;
        const float az = part[0][r_][uj+HH]+part[1][r_][uj+HH]+part[2][r_][uj+HH]+part[3][r_][uj+HH] + bz;
        const float an = part[0][r_][uj+2*HH]+part[1][r_][uj+2*HH]+part[2][r_][uj+2*HH]+part[3][r_][uj+2*HH] + bn_;
        const float rr = 1.f/(1.f + __expf(-(i1r + ar)));
        const float zz = 1.f/(1.f + __expf(-(i1z + az)));
        const float nn = tanhf(fmaf(rr, an, i1n));
        const float hold = h[r_][uj];
        const float m = mkz[r_];
        const float hnew = (1.f - zz)*nn + zz*hold;
        const float hv = hnew*m + hold*(1.f - m);
        h[r_][uj] = hv;
        Hh[((size_t)st*BB + b0 + r_)*HH + uj] = hv;
      }
    }
    __syncthreads();
  }
  if (t < 512){
    hcar[(size_t)(b0+ur  )*HH + uj] = h[ur  ][uj];
    hcar[(size_t)(b0+ur+2)*HH + uj] = h[ur+2][uj];
  }
}

// ---------------------------------------------------------------------------
// Head (fused LN2): x=LN2(row); relu(x@nn1.T+b1) -> LN(8) -> @nn2.T+b2.
// ---------------------------------------------------------------------------
__global__ void head_ln_k(const float* __restrict__ hx,
                          const float* __restrict__ g2, const float* __restrict__ b2,
                          const float* __restrict__ w1, const float* __restrict__ b1,
                          const float* __restrict__ g3, const float* __restrict__ b3,
                          const float* __restrict__ w2, const float* __restrict__ b2h,
                          float* __restrict__ outp, long long r0){
  long long row = blockIdx.x;
  int t = threadIdx.x;
  float v = hx[row*HH + t];
  float s = v, q = v*v;
  #pragma unroll
  for (int o=32;o>0;o>>=1){ s += __shfl_down(s,o); q += __shfl_down(q,o); }
  __shared__ float ssm[4], qqm[4];
  int w = t >> 6;
  if ((t & 63) == 0){ ssm[w] = s; qqm[w] = q; }
  __syncthreads();
  if (t == 0){ ssm[0] = ssm[0]+ssm[1]+ssm[2]+ssm[3]; qqm[0] = qqm[0]+qqm[1]+qqm[2]+qqm[3]; }
  __syncthreads();
  s = ssm[0]; q = qqm[0];
  float mu  = s * (1.f/HH);
  float var = q * (1.f/HH) - mu*mu;
  float rs  = rsqrtf(var + EPSF);
  __shared__ float xs[HH];
  xs[t] = (v - mu)*rs*g2[t] + b2[t];
  __syncthreads();
  int o = t >> 5, l = t & 31;
  const float* wv = w1 + o*HH;
  float acc = 0.f;
  for (int k=l;k<HH;k+=32) acc = fmaf(xs[k], wv[k], acc);
  #pragma unroll
  for (int d=16;d>0;d>>=1) acc += __shfl_down(acc, d, 32);
  __shared__ float a8[8];
  if (l == 0) a8[o] = fmaxf(acc + b1[o], 0.f);
  __syncthreads();
  if (t == 0){
    float ss = 0.f;
    #pragma unroll
    for (int i=0;i<8;i++) ss += a8[i];
    float m8 = ss*0.125f;
    float qq = 0.f;
    #pragma unroll
    for (int i=0;i<8;i++){ float d = a8[i]-m8; qq = fmaf(d,d,qq); }
    float r8 = rsqrtf(qq*0.125f + EPSF);
    float y0 = b2h[0], y1 = b2h[1];
    #pragma unroll
    for (int i=0;i<8;i++){
      float vv = (a8[i]-m8)*r8*g3[i] + b3[i];
      y0 = fmaf(vv, w2[i],   y0);
      y1 = fmaf(vv, w2[8+i], y1);
    }
    outp[(r0+row)*2+0] = y0; outp[(r0+row)*2+1] = y1;
  }
}

// ---------------------------------------------------------------------------
// Host launcher. R8 = R7 + bf16 scan weights (whhTb). Structure frozen.
// ---------------------------------------------------------------------------
extern "C" void kernel_launch(void* const* d_in, const int* in_sizes, int n_in,
                              void* d_out, int out_size, void* d_ws, size_t ws_size,
                              hipStream_t stream) {
  const float* X      = (const float*)d_in[0];
  const float* Mi     = (const float*)d_in[1];
  const float* mask   = (const float*)d_in[2];
  const float* i2h_w  = (const float*)d_in[3];
  const float* i2h_b  = (const float*)d_in[4];
  const float* comb_w = (const float*)d_in[5];
  const float* comb_b = (const float*)d_in[6];
  const float* down_w = (const float*)d_in[7];
  const float* down_b = (const float*)d_in[8];
  const float* conv1_w= (const float*)d_in[9];
  const float* conv1_b= (const float*)d_in[10];
  const float* conv2_w= (const float*)d_in[11];
  const float* conv2_b= (const float*)d_in[12];
  const float* bn1_g  = (const float*)d_in[13];
  const float* bn1_b  = (const float*)d_in[14];
  const float* bn2_g  = (const float*)d_in[15];
  const float* bn2_b  = (const float*)d_in[16];
  const float* r1_wih = (const float*)d_in[17];
  const float* r1_whh = (const float*)d_in[18];
  const float* r1_bih = (const float*)d_in[19];
  const float* r1_bhh = (const float*)d_in[20];
  const float* r1_cw  = (const float*)d_in[21];
  const float* r1_cb  = (const float*)d_in[22];
  const float* r2_wih = (const float*)d_in[23];
  const float* r2_whh = (const float*)d_in[24];
  const float* r2_bih = (const float*)d_in[25];
  const float* r2_bhh = (const float*)d_in[26];
  const float* r2_cw  = (const float*)d_in[27];
  const float* r2_cb  = (const float*)d_in[28];
  const float* ln1_g  = (const float*)d_in[29];
  const float* ln1_b  = (const float*)d_in[30];
  const float* ln2_g  = (const float*)d_in[31];
  const float* ln2_b  = (const float*)d_in[32];
  const float* ln3_g  = (const float*)d_in[33];
  const float* ln3_b  = (const float*)d_in[34];
  const float* nn1_w  = (const float*)d_in[35];
  const float* nn1_b  = (const float*)d_in[36];
  const float* nn2_w  = (const float*)d_in[37];
  const float* nn2_b  = (const float*)d_in[38];
  float* outp = (float*)d_out;

  // ushort region: C2{h,l} W2F{h,l} WI1{h,l} WI2{h,l} CW1{h,l} CW2{h,l} + W1Tb + W2Tb
  const size_t us_elems = 2*((size_t)HH*HH + (size_t)HH*HH + (size_t)G3*HH
                           + (size_t)G3*HH + (size_t)HH*2*HH + (size_t)HH*2*HH)
                        + 2*(size_t)G3*HH;
  const size_t tail_floats = 2*(size_t)BB*HH + 2*(size_t)NPART*HH + 2*HH
                           + (size_t)256*40 + 256 + (size_t)HH*HH + 256
                           + (size_t)SB*CC
                           + (us_elems + 1)/2;
  // per-chunk rows: A(256) + GI1(768, Cxp aliased) + GI2(768) + Ee(256)
  //               + Hh2(256) + Hx1(256) = 2560 floats/row
  int cands[6] = {256,128,64,32,16,8};
  int sc_chunk = 0;
  for (int ci=0; ci<6; ci++){
    size_t R = (size_t)512*cands[ci];
    size_t need = (R*2560 + tail_floats)*sizeof(float);
    if (need <= ws_size && R*2560 >= (size_t)SB*HH){ sc_chunk = cands[ci]; break; }
  }
  if (!sc_chunk) return;

  const size_t R = (size_t)512*sc_chunk;     // rows per chunk
  const int Ri = (int)R;
  const int nchunks = SB / Ri;

  float* wsf = (float*)d_ws;
  float* A   = wsf;                    // R*256  (res -> hx)
  float* GI1 = A + R*HH;               // R*768  gi for GRU1(c)
  float* Cxp = GI1;                    // ALIAS: GI1 dead after scan; Cxp lives after
  float* GI2 = GI1 + R*G3;             // R*768  gi for GRU2(c)
  float* Ee  = GI2 + R*G3;             // R*256  out1r -> Hh1
  float* Hh2 = Ee + R*HH;              // R*256  Hh of GRU2(c-1)
  float* Hx1 = Hh2 + R*HH;             // R*256  hx1(c) = LN1 out
  float* tl  = Hx1 + R*HH;
  float* H1C = tl;                     // BB*HH
  float* H2C = H1C + (size_t)BB*HH;
  float* PS  = H2C + (size_t)BB*HH;    // NPART*HH
  float* PQ  = PS  + (size_t)NPART*HH;
  float* SCv = PQ  + (size_t)NPART*HH; // HH
  float* SHv = SCv + HH;
  float* W1F = SHv + HH;               // 256*40
  float* B1F = W1F + (size_t)256*40;   // 256
  float* W2F = B1F + HH;               // 256*256
  float* B2F = W2F + (size_t)HH*HH;    // 256
  float* XcF = B2F + HH;               // SB*40 persisted comb output
  unsigned short* usb = (unsigned short*)(XcF + (size_t)SB*CC);
  unsigned short* C2H  = usb;                       // conv2_w raw split (HH*HH)
  unsigned short* C2L  = C2H  + (size_t)HH*HH;
  unsigned short* W2FH = C2L  + (size_t)HH*HH;      // folded conv2 (HH*HH)
  unsigned short* W2FL = W2FH + (size_t)HH*HH;
  unsigned short* WI1H = W2FL + (size_t)HH*HH;      // r1_wih (G3*HH)
  unsigned short* WI1L = WI1H + (size_t)G3*HH;
  unsigned short* WI2H = WI1L + (size_t)G3*HH;      // r2_wih (G3*HH)
  unsigned short* WI2L = WI2H + (size_t)G3*HH;
  unsigned short* CW1H = WI2L + (size_t)G3*HH;      // r1_cw (HH*2HH)
  unsigned short* CW1L = CW1H + (size_t)HH*2*HH;
  unsigned short* CW2H = CW1L + (size_t)HH*2*HH;    // r2_cw (HH*2HH)
  unsigned short* CW2L = CW2H + (size_t)HH*2*HH;
  unsigned short* W1Tb = CW2L + (size_t)HH*2*HH;    // whhT bf16 (256x768) GRU1
  unsigned short* W2Tb = W1Tb + (size_t)HH*G3;      // whhT bf16 (256x768) GRU2

  // one-time transposes + static weight splits
  whht_bf_k<<<(G3*HH + 255)/256, 256, 0, stream>>>(r1_whh, W1Tb);
  whht_bf_k<<<(G3*HH + 255)/256, 256, 0, stream>>>(r2_whh, W2Tb);
  split_w_k<<<(HH*HH + 255)/256, 256, 0, stream>>>(conv2_w, C2H, C2L, HH*HH);
  split_w_k<<<(G3*HH + 255)/256, 256, 0, stream>>>(r1_wih, WI1H, WI1L, G3*HH);
  split_w_k<<<(G3*HH + 255)/256, 256, 0, stream>>>(r2_wih, WI2H, WI2L, G3*HH);
  split_w_k<<<(HH*2*HH + 255)/256, 256, 0, stream>>>(r1_cw, CW1H, CW1L, HH*2*HH);
  split_w_k<<<(HH*2*HH + 255)/256, 256, 0, stream>>>(r2_cw, CW2H, CW2L, HH*2*HH);

  const int MB = Ri/128;

  // ---------- pass A: ONE sweep over all SB rows (scratch = per-chunk region) ----------
  {
    float* SA = wsf;                          // SB*HH scratch (33.5M <= R*2560)
    gemm_tn<0,1><<<dim3(SB/128,1), 256, 0, stream>>>(X, II, comb_w, 80, comb_b, XcF, CC, SB, CC, 80, Mi, 0);
    gemm_tn<0,0><<<dim3(SB/128,2), 256, 0, stream>>>(XcF, CC, conv1_w, CC, conv1_b, SA, HH, SB, HH, CC, nullptr, 0);
    bn_partial_k<<<SB/64, 256, 0, stream>>>(SA, PS, PQ, 0);
  }
  bn_final_k<<<1, 256, 0, stream>>>(PS, PQ, bn1_g, bn1_b, SCv, SHv);
  fold_k<<<(256*40 + 255)/256, 256, 0, stream>>>(conv1_w, conv1_b, SCv, SHv, W1F, B1F, 40);

  // ---------- pass B: TWO half-sweeps (needs 2x SB/2*HH scratch) ----------
  {
    float* SA2 = wsf;                         // SB/2*HH
    float* SB2 = wsf + (size_t)(SB/2)*HH;     // SB/2*HH
    for (int hlf=0; hlf<2; hlf++){
      long long r0 = (long long)hlf*(SB/2);
      gemm_tn<1,0><<<dim3(SB/256,2), 256, 0, stream>>>(XcF + r0*CC, CC, W1F, CC, B1F, SA2, HH, SB/2, HH, CC, nullptr, 0);
      gemm_mfp<0><<<dim3(SB/256,2), 256, 0, stream>>>(SA2, HH, C2H, C2L, HH, conv2_b, SB2, HH, HH, HH);
      bn_partial_k<<<(SB/2)/64, 256, 0, stream>>>(SB2, PS, PQ, (int)(r0/64));
    }
  }
  bn_final_k<<<1, 256, 0, stream>>>(PS, PQ, bn2_g, bn2_b, SCv, SHv);
  fold_k<<<(256*256 + 255)/256, 256, 0, stream>>>(conv2_w, conv2_b, SCv, SHv, W2F, B2F, 256);
  split_w_k<<<(HH*HH + 255)/256, 256, 0, stream>>>(W2F, W2FH, W2FL, HH*HH);

  // ---------- h0 -> carries ----------
  h0_k<<<BB, HH, 0, stream>>>(X, i2h_w, i2h_b, H1C, H2C);

  // ---------- pass C: pipelined main loop ----------
  for (int c=0;c<nchunks;c++){
    long long r0 = (long long)c*R;
    long long rp = r0 - (long long)R;   // previous chunk base (valid for c>0)
    // ---- S1(c): {res, out1r} fused, then hx, gi1
    gemm_tn_dual2<<<dim3(MB,2), 256, 0, stream>>>(X, r0, down_w, down_b, A,
                                                  XcF + r0*CC, W1F, B1F, Ee, Ri);
    gemm_mfp<2><<<dim3(MB,2), 256, 0, stream>>>(Ee, HH, W2FH, W2FL, HH, B2F, A, HH, HH, HH);     // hx
    gemm_mfp<0><<<dim3(MB,6), 256, 0, stream>>>(A, HH, WI1H, WI1L, HH, r1_bih, GI1, G3, G3, HH); // gi1
    // ---- fused scan: GRU1(c) || GRU2(c-1)
    gru_scan_fused_k<<<2*(BB/4), 768, 0, stream>>>(
        GI1, W1Tb, r1_bhh, mask + r0, H1C, Ee, sc_chunk,
        GI2, W2Tb, r2_bhh, (c > 0) ? (mask + rp) : mask, H2C, Hh2, (c > 0) ? sc_chunk : 0);
    // ---- S3(c-1): finish previous chunk (Cxp = GI1 region, dead after scan)
    if (c > 0){
      gemm_mfp_dual<<<dim3(MB,2), 256, 0, stream>>>(Hx1, Hh2, CW2H, CW2L, r2_cb, Cxp, HH, HH);   // outs2
      head_ln_k<<<Ri, 256, 0, stream>>>(Cxp, ln2_g, ln2_b, nn1_w, nn1_b, ln3_g, ln3_b, nn2_w, nn2_b, outp, rp);
    }
    // ---- S2(c): GRU1 out-projection, LN1, gi2(c)
    gemm_mfp_dual<<<dim3(MB,2), 256, 0, stream>>>(A, Ee, CW1H, CW1L, r1_cb, Cxp, HH, HH);        // outs1
    ln_rows_k<<<Ri, 256, 0, stream>>>(Cxp, Hx1, ln1_g, ln1_b);                                    // hx1(c)
    gemm_mfp<0><<<dim3(MB,6), 256, 0, stream>>>(Hx1, HH, WI2H, WI2L, HH, r2_bih, GI2, G3, G3, HH); // gi2(c)
  }
  // ---------- drain: GRU2(last chunk) ----------
  {
    long long rl = (long long)(nchunks-1)*R;
    gru_scan_fused_k<<<2*(BB/4), 768, 0, stream>>>(
        GI1, W1Tb, r1_bhh, mask, H1C, Ee, 0,
        GI2, W2Tb, r2_bhh, mask + rl, H2C, Hh2, sc_chunk);
    gemm_mfp_dual<<<dim3(MB,2), 256, 0, stream>>>(Hx1, Hh2, CW2H, CW2L, r2_cb, Cxp, HH, HH);
    head_ln_k<<<Ri, 256, 0, stream>>>(Cxp, ln2_g, ln2_b, nn1_w, nn1_b, ln3_g, ln3_b, nn2_w, nn2_b, outp, rl);
  }
}

// Round 9
// 6434.431 us; speedup vs baseline: 1.0472x; 1.0033x over previous
//
#include <hip/hip_runtime.h>
#include <hip/hip_bf16.h>

// Problem dims
#define SS 256
#define BB 512
#define II 46
#define HH 256
#define CC 40
#define SB (SS*BB)        // 131072 rows
#define G3 (3*HH)         // 768
#define EPSF 1e-5f
#define NPART (SB/64)     // 2048 bn partials

typedef __attribute__((ext_vector_type(8))) short bf16x8;
typedef __attribute__((ext_vector_type(4))) float f32x4;
typedef __attribute__((ext_vector_type(2))) float f32x2;

// ---------------------------------------------------------------------------
// helpers
// ---------------------------------------------------------------------------
__device__ __forceinline__ unsigned short f2bf_rne(float f){
  unsigned u = __float_as_uint(f);
  unsigned r = (u + 0x7FFFu + ((u >> 16) & 1u)) >> 16;
  return (unsigned short)r;
}
__device__ __forceinline__ float bf2f(unsigned short b){
  return __uint_as_float(((unsigned)b) << 16);
}
__device__ __forceinline__ void cvt8(const float* v, bf16x8& hi, bf16x8& lo){
  #pragma unroll
  for (int e=0;e<8;e++){
    unsigned short hb = f2bf_rne(v[e]);
    hi[e] = (short)hb;
    lo[e] = (short)f2bf_rne(v[e] - bf2f(hb));
  }
}

// ---------------------------------------------------------------------------
// split f32 weight array -> bf16 {hi, lo}
// ---------------------------------------------------------------------------
__global__ void split_w_k(const float* __restrict__ w, unsigned short* __restrict__ wh,
                          unsigned short* __restrict__ wl, int n){
  int i = blockIdx.x*256 + threadIdx.x;
  if (i >= n) return;
  float v = w[i];
  unsigned short hb = f2bf_rne(v);
  wh[i] = hb;
  wl[i] = f2bf_rne(v - bf2f(hb));
}

// ---------------------------------------------------------------------------
// h0[b,j] = sum_{c<6} X[0,b,40+c] * i2h_w[j,c] + i2h_b[j]  -> both carries
// ---------------------------------------------------------------------------
__global__ void h0_k(const float* __restrict__ X, const float* __restrict__ w,
                     const float* __restrict__ bias, float* __restrict__ h1c,
                     float* __restrict__ h2c){
  int b = blockIdx.x, jj = threadIdx.x;
  const float* p = X + (long long)b*II + (II - 6);
  float acc = bias[jj];
  #pragma unroll
  for (int c2=0;c2<6;c2++) acc = fmaf(p[c2], w[jj*6 + c2], acc);
  h1c[(long long)b*HH + jj] = acc;
  h2c[(long long)b*HH + jj] = acc;
}

// ---------------------------------------------------------------------------
// transpose + bf16-convert whh (768x256) -> whhTb (256x768 bf16), once.
// ---------------------------------------------------------------------------
__global__ void whht_bf_k(const float* __restrict__ w, unsigned short* __restrict__ wt){
  int idx = blockIdx.x*blockDim.x + threadIdx.x;
  if (idx >= G3*HH) return;
  int u = idx / HH, k = idx - u*HH;      // w[u][k]
  wt[(size_t)k*G3 + u] = f2bf_rne(w[idx]);
}

// ---------------------------------------------------------------------------
// Generic f32 GEMM (small-K ops: comb K=80, conv1 K=40).
// MODE 0: store; 1: store relu; 2: accumulate.
// XM 1: A is implicit [X | Mi] with row stride II; A=X base, A2=Mi base, +r0.
// ---------------------------------------------------------------------------
template<int MODE, int XM>
__global__ void gemm_tn(const float* __restrict__ A, int lda,
                        const float* __restrict__ W, int ldw,
                        const float* __restrict__ bias,
                        float* __restrict__ Co, int ldc,
                        int Mrows, int N, int K,
                        const float* __restrict__ A2, long long r0)
{
  __shared__ __align__(16) float As[32][132];
  __shared__ __align__(16) float Ws[32][132];
  const int m0 = blockIdx.x*128, n0 = blockIdx.y*128;
  const int t  = threadIdx.x;
  const int tm = t >> 4, tn = t & 15;
  float acc[8][8];
  #pragma unroll
  for (int i=0;i<8;i++)
    #pragma unroll
    for (int j2=0;j2<8;j2++) acc[i][j2] = 0.f;

  for (int k0=0;k0<K;k0+=32){
    #pragma unroll
    for (int u=0;u<16;u++){
      int idx = u*256 + t;
      int r = idx >> 5, c = idx & 31;
      int gk = k0 + c;
      float av = 0.f, wv = 0.f;
      if (gk < K){
        int gm = m0 + r;
        if (gm < Mrows){
          if (XM){
            long long gr = r0 + gm;
            av = (gk < CC) ? A[gr*II + gk] : A2[gr*II + (gk - CC)];
          } else {
            av = A[(long long)gm*lda + gk];
          }
        }
        int gn = n0 + r;
        if (gn < N)     wv = W[(long long)gn*ldw + gk];
      }
      As[c][r] = av;
      Ws[c][r] = wv;
    }
    __syncthreads();
    #pragma unroll
    for (int kk=0;kk<32;kk++){
      const float4 a0 = *(const float4*)&As[kk][tm*8];
      const float4 a1 = *(const float4*)&As[kk][tm*8+4];
      const float4 b0 = *(const float4*)&Ws[kk][tn*8];
      const float4 b1 = *(const float4*)&Ws[kk][tn*8+4];
      const float av[8] = {a0.x,a0.y,a0.z,a0.w,a1.x,a1.y,a1.z,a1.w};
      const float bv[8] = {b0.x,b0.y,b0.z,b0.w,b1.x,b1.y,b1.z,b1.w};
      #pragma unroll
      for (int i=0;i<8;i++)
        #pragma unroll
        for (int j2=0;j2<8;j2++) acc[i][j2] = fmaf(av[i], bv[j2], acc[i][j2]);
    }
    __syncthreads();
  }
  #pragma unroll
  for (int i=0;i<8;i++){
    int gm = m0 + tm*8 + i;
    if (gm < Mrows){
      #pragma unroll
      for (int j2=0;j2<8;j2++){
        int gn = n0 + tn*8 + j2;
        if (gn < N){
          long long oi = (long long)gm*ldc + gn;
          float val = acc[i][j2] + bias[gn];
          if (MODE == 1) val = fmaxf(val, 0.f);
          if (MODE == 2) val += Co[oi];
          Co[oi] = val;
        }
      }
    }
  }
}

// ---------------------------------------------------------------------------
// Dual-output small-K GEMM (S1 fusion): res + relu(out1) in one dispatch.
// ---------------------------------------------------------------------------
__global__ void gemm_tn_dual2(const float* __restrict__ Xb, long long r0,
                              const float* __restrict__ W1, const float* __restrict__ b1,
                              float* __restrict__ Co1,
                              const float* __restrict__ A2, const float* __restrict__ W2,
                              const float* __restrict__ b2, float* __restrict__ Co2,
                              int Mrows)
{
  __shared__ __align__(16) float As1[32][132];
  __shared__ __align__(16) float As2[32][132];
  __shared__ __align__(16) float Ws1[32][132];
  __shared__ __align__(16) float Ws2[32][132];
  const int m0 = blockIdx.x*128, n0 = blockIdx.y*128;
  const int t  = threadIdx.x;
  const int tm = t >> 4, tn = t & 15;
  float acc1[8][8], acc2[8][8];
  #pragma unroll
  for (int i=0;i<8;i++)
    #pragma unroll
    for (int j2=0;j2<8;j2++){ acc1[i][j2] = 0.f; acc2[i][j2] = 0.f; }

  for (int k0=0;k0<CC;k0+=32){
    #pragma unroll
    for (int u=0;u<16;u++){
      int idx = u*256 + t;
      int r = idx >> 5, c = idx & 31;
      int gk = k0 + c;
      float a1=0.f, a2=0.f, w1=0.f, w2=0.f;
      if (gk < CC){
        int gm = m0 + r;
        if (gm < Mrows){
          long long gr = r0 + gm;
          a1 = Xb[gr*II + gk];
          a2 = A2[(long long)gm*CC + gk];
        }
        int gn = n0 + r;
        w1 = W1[(long long)gn*CC + gk];
        w2 = W2[(long long)gn*CC + gk];
      }
      As1[c][r] = a1; As2[c][r] = a2;
      Ws1[c][r] = w1; Ws2[c][r] = w2;
    }
    __syncthreads();
    #pragma unroll
    for (int kk=0;kk<32;kk++){
      const float4 p0 = *(const float4*)&As1[kk][tm*8];
      const float4 p1 = *(const float4*)&As1[kk][tm*8+4];
      const float4 q0 = *(const float4*)&As2[kk][tm*8];
      const float4 q1 = *(const float4*)&As2[kk][tm*8+4];
      const float4 u0 = *(const float4*)&Ws1[kk][tn*8];
      const float4 u1 = *(const float4*)&Ws1[kk][tn*8+4];
      const float4 v0 = *(const float4*)&Ws2[kk][tn*8];
      const float4 v1 = *(const float4*)&Ws2[kk][tn*8+4];
      const float a1v[8] = {p0.x,p0.y,p0.z,p0.w,p1.x,p1.y,p1.z,p1.w};
      const float a2v[8] = {q0.x,q0.y,q0.z,q0.w,q1.x,q1.y,q1.z,q1.w};
      const float w1v[8] = {u0.x,u0.y,u0.z,u0.w,u1.x,u1.y,u1.z,u1.w};
      const float w2v[8] = {v0.x,v0.y,v0.z,v0.w,v1.x,v1.y,v1.z,v1.w};
      #pragma unroll
      for (int i=0;i<8;i++)
        #pragma unroll
        for (int j2=0;j2<8;j2++){
          acc1[i][j2] = fmaf(a1v[i], w1v[j2], acc1[i][j2]);
          acc2[i][j2] = fmaf(a2v[i], w2v[j2], acc2[i][j2]);
        }
    }
    __syncthreads();
  }
  #pragma unroll
  for (int i=0;i<8;i++){
    int gm = m0 + tm*8 + i;
    if (gm < Mrows){
      #pragma unroll
      for (int j2=0;j2<8;j2++){
        int gn = n0 + tn*8 + j2;
        long long oi = (long long)gm*HH + gn;
        Co1[oi] = acc1[i][j2] + b1[gn];
        Co2[oi] = fmaxf(acc2[i][j2] + b2[gn], 0.f);
      }
    }
  }
}

// ---------------------------------------------------------------------------
// Split-bf16 MFMA GEMM with PRE-SPLIT B. MODE 0: store; 2: accumulate.
// ---------------------------------------------------------------------------
template<int MODE>
__global__ __launch_bounds__(256) void gemm_mfp(
    const float* __restrict__ A, int lda,
    const unsigned short* __restrict__ Wh, const unsigned short* __restrict__ Wl, int ldw,
    const float* __restrict__ bias,
    float* __restrict__ Co, int ldc,
    int N, int K)
{
  __shared__ __align__(16) unsigned short Ah[128*32];
  __shared__ __align__(16) unsigned short Al[128*32];
  __shared__ __align__(16) unsigned short Bh[128*32];
  __shared__ __align__(16) unsigned short Bl[128*32];
  const int t = threadIdx.x;
  const int m0 = blockIdx.x*128, n0 = blockIdx.y*128;
  const int lane = t & 63, w = t >> 6;
  const int wm = (w & 1)*64, wn = (w >> 1)*64;
  const int fr = lane & 15, fg = lane >> 4;

  f32x4 acc[4][4];
  #pragma unroll
  for (int i=0;i<4;i++)
    #pragma unroll
    for (int j=0;j<4;j++){ f32x4 z; z[0]=0;z[1]=0;z[2]=0;z[3]=0; acc[i][j]=z; }

  for (int k0=0; k0<K; k0+=32){
    #pragma unroll
    for (int cc=0; cc<2; cc++){
      const int c   = t + cc*256;
      const int row = c >> 2, kg = c & 3;
      const int byte = row*64 + ((kg*16) ^ (((row>>1)&3)<<4));
      {
        const float* ap = A + (size_t)(m0+row)*lda + k0 + kg*8;
        float v[8];
        *(float4*)&v[0] = *(const float4*)ap;
        *(float4*)&v[4] = *(const float4*)(ap+4);
        bf16x8 hi, lo; cvt8(v, hi, lo);
        *(bf16x8*)((char*)Ah + byte) = hi;
        *(bf16x8*)((char*)Al + byte) = lo;
      }
      {
        const size_t off = (size_t)(n0+row)*ldw + k0 + kg*8;
        *(bf16x8*)((char*)Bh + byte) = *(const bf16x8*)&Wh[off];
        *(bf16x8*)((char*)Bl + byte) = *(const bf16x8*)&Wl[off];
      }
    }
    __syncthreads();
    bf16x8 ahi[4], alo[4], bhi[4], blo[4];
    #pragma unroll
    for (int mt=0; mt<4; mt++){
      const int r = wm + mt*16 + fr;
      const int byte = r*64 + ((fg*16) ^ (((r>>1)&3)<<4));
      ahi[mt] = *(const bf16x8*)((const char*)Ah + byte);
      alo[mt] = *(const bf16x8*)((const char*)Al + byte);
    }
    #pragma unroll
    for (int nt=0; nt<4; nt++){
      const int r = wn + nt*16 + fr;
      const int byte = r*64 + ((fg*16) ^ (((r>>1)&3)<<4));
      bhi[nt] = *(const bf16x8*)((const char*)Bh + byte);
      blo[nt] = *(const bf16x8*)((const char*)Bl + byte);
    }
    #pragma unroll
    for (int mt=0; mt<4; mt++)
      #pragma unroll
      for (int nt=0; nt<4; nt++){
        acc[mt][nt] = __builtin_amdgcn_mfma_f32_16x16x32_bf16(alo[mt], bhi[nt], acc[mt][nt], 0,0,0);
        acc[mt][nt] = __builtin_amdgcn_mfma_f32_16x16x32_bf16(ahi[mt], blo[nt], acc[mt][nt], 0,0,0);
        acc[mt][nt] = __builtin_amdgcn_mfma_f32_16x16x32_bf16(ahi[mt], bhi[nt], acc[mt][nt], 0,0,0);
      }
    __syncthreads();
  }

  #pragma unroll
  for (int mt=0; mt<4; mt++){
    #pragma unroll
    for (int nt=0; nt<4; nt++){
      const int col = n0 + wn + nt*16 + fr;
      const float bv = bias[col];
      #pragma unroll
      for (int i=0;i<4;i++){
        const int row = m0 + wm + mt*16 + fg*4 + i;
        const size_t oi = (size_t)row*ldc + col;
        float val = acc[mt][nt][i] + bv;
        if (MODE == 2) val += Co[oi];
        Co[oi] = val;
      }
    }
  }
}

// ---------------------------------------------------------------------------
// Dual-A fused out-projection GEMM with pre-split B (cw).
// ---------------------------------------------------------------------------
__global__ __launch_bounds__(256) void gemm_mfp_dual(
    const float* __restrict__ A1, const float* __restrict__ A2,
    const unsigned short* __restrict__ Wh, const unsigned short* __restrict__ Wl,
    const float* __restrict__ bias,
    float* __restrict__ Co, int ldc, int N)
{
  __shared__ __align__(16) unsigned short Ah[128*32];
  __shared__ __align__(16) unsigned short Al[128*32];
  __shared__ __align__(16) unsigned short Bh[128*32];
  __shared__ __align__(16) unsigned short Bl[128*32];
  const int t = threadIdx.x;
  const int m0 = blockIdx.x*128, n0 = blockIdx.y*128;
  const int lane = t & 63, w = t >> 6;
  const int wm = (w & 1)*64, wn = (w >> 1)*64;
  const int fr = lane & 15, fg = lane >> 4;

  f32x4 acc[4][4];
  #pragma unroll
  for (int i=0;i<4;i++)
    #pragma unroll
    for (int j=0;j<4;j++){ f32x4 z; z[0]=0;z[1]=0;z[2]=0;z[3]=0; acc[i][j]=z; }

  for (int k0=0; k0<2*HH; k0+=32){
    const float* Abase = (k0 < HH) ? A1 : A2;
    const int    kofs  = (k0 < HH) ? k0 : (k0 - HH);
    #pragma unroll
    for (int cc=0; cc<2; cc++){
      const int c   = t + cc*256;
      const int row = c >> 2, kg = c & 3;
      const int byte = row*64 + ((kg*16) ^ (((row>>1)&3)<<4));
      {
        const float* ap = Abase + (size_t)(m0+row)*HH + kofs + kg*8;
        float v[8];
        *(float4*)&v[0] = *(const float4*)ap;
        *(float4*)&v[4] = *(const float4*)(ap+4);
        bf16x8 hi, lo; cvt8(v, hi, lo);
        *(bf16x8*)((char*)Ah + byte) = hi;
        *(bf16x8*)((char*)Al + byte) = lo;
      }
      {
        const size_t off = (size_t)(n0+row)*(2*HH) + k0 + kg*8;
        *(bf16x8*)((char*)Bh + byte) = *(const bf16x8*)&Wh[off];
        *(bf16x8*)((char*)Bl + byte) = *(const bf16x8*)&Wl[off];
      }
    }
    __syncthreads();
    bf16x8 ahi[4], alo[4], bhi[4], blo[4];
    #pragma unroll
    for (int mt=0; mt<4; mt++){
      const int r = wm + mt*16 + fr;
      const int byte = r*64 + ((fg*16) ^ (((r>>1)&3)<<4));
      ahi[mt] = *(const bf16x8*)((const char*)Ah + byte);
      alo[mt] = *(const bf16x8*)((const char*)Al + byte);
    }
    #pragma unroll
    for (int nt=0; nt<4; nt++){
      const int r = wn + nt*16 + fr;
      const int byte = r*64 + ((fg*16) ^ (((r>>1)&3)<<4));
      bhi[nt] = *(const bf16x8*)((const char*)Bh + byte);
      blo[nt] = *(const bf16x8*)((const char*)Bl + byte);
    }
    #pragma unroll
    for (int mt=0; mt<4; mt++)
      #pragma unroll
      for (int nt=0; nt<4; nt++){
        acc[mt][nt] = __builtin_amdgcn_mfma_f32_16x16x32_bf16(alo[mt], bhi[nt], acc[mt][nt], 0,0,0);
        acc[mt][nt] = __builtin_amdgcn_mfma_f32_16x16x32_bf16(ahi[mt], blo[nt], acc[mt][nt], 0,0,0);
        acc[mt][nt] = __builtin_amdgcn_mfma_f32_16x16x32_bf16(ahi[mt], bhi[nt], acc[mt][nt], 0,0,0);
      }
    __syncthreads();
  }

  #pragma unroll
  for (int mt=0; mt<4; mt++){
    #pragma unroll
    for (int nt=0; nt<4; nt++){
      const int col = n0 + wn + nt*16 + fr;
      const float bv = bias[col];
      #pragma unroll
      for (int i=0;i<4;i++){
        const int row = m0 + wm + mt*16 + fg*4 + i;
        const size_t oi = (size_t)row*ldc + col;
        Co[oi] = acc[mt][nt][i] + bv;
      }
    }
  }
}

// ---------------------------------------------------------------------------
// BatchNorm stats (64 rows/block) + fold
// ---------------------------------------------------------------------------
__global__ void bn_partial_k(const float* __restrict__ Xc, float* __restrict__ ps,
                             float* __restrict__ pq, int pblk0){
  int blk = blockIdx.x, t = threadIdx.x;
  long long base = (long long)blk*64*HH;
  float s = 0.f, q = 0.f;
  for (int r=0;r<64;r++){
    float v = Xc[base + (long long)r*HH + t];
    s += v; q = fmaf(v, v, q);
  }
  ps[(size_t)(pblk0+blk)*HH + t] = s;
  pq[(size_t)(pblk0+blk)*HH + t] = q;
}

__global__ void bn_final_k(const float* __restrict__ ps, const float* __restrict__ pq,
                           const float* __restrict__ g, const float* __restrict__ b,
                           float* __restrict__ sc, float* __restrict__ sh){
  int t = threadIdx.x;
  double s = 0.0, q = 0.0;
  for (int i=0;i<NPART;i++){ s += (double)ps[(size_t)i*HH + t]; q += (double)pq[(size_t)i*HH + t]; }
  double mu  = s / (double)SB;
  double var = q / (double)SB - mu*mu;
  float scv = (float)((double)g[t] / sqrt(var + 1e-5));
  sc[t] = scv;
  sh[t] = (float)((double)b[t] - mu*(double)scv);
}

__global__ void fold_k(const float* __restrict__ w, const float* __restrict__ b,
                       const float* __restrict__ sc, const float* __restrict__ sh,
                       float* __restrict__ wf, float* __restrict__ bf, int K){
  int idx = blockIdx.x*blockDim.x + threadIdx.x;
  if (idx < 256*K){ int o = idx / K; wf[idx] = w[idx]*sc[o]; }
  if (idx < 256)  bf[idx] = b[idx]*sc[idx] + sh[idx];
}

// ---------------------------------------------------------------------------
// LayerNorm over last dim (256), out-of-place. One block per row.
// ---------------------------------------------------------------------------
__global__ void ln_rows_k(const float* __restrict__ Xi, float* __restrict__ Xo,
                          const float* __restrict__ g, const float* __restrict__ b){
  long long row = blockIdx.x;
  int t = threadIdx.x;
  float v = Xi[row*HH + t];
  float s = v, q = v*v;
  #pragma unroll
  for (int o=32;o>0;o>>=1){ s += __shfl_down(s,o); q += __shfl_down(q,o); }
  __shared__ float ssm[4], qqm[4];
  int w = t >> 6;
  if ((t & 63) == 0){ ssm[w] = s; qqm[w] = q; }
  __syncthreads();
  if (t == 0){ ssm[0] = ssm[0]+ssm[1]+ssm[2]+ssm[3]; qqm[0] = qqm[0]+qqm[1]+qqm[2]+qqm[3]; }
  __syncthreads();
  s = ssm[0]; q = qqm[0];
  float mu  = s * (1.f/HH);
  float var = q * (1.f/HH) - mu*mu;
  float rs  = rsqrtf(var + EPSF);
  Xo[row*HH + t] = (v - mu)*rs*g[t] + b[t];
}

// ---------------------------------------------------------------------------
// FUSED dual-GRU gate scan, bf16 weights + PACKED-F32 FMA (R9).
// Column pairs (c0,c0+1) share the same h scalar and their bf16 weights sit
// in one u32 -> f32x2 accumulators with __builtin_elementwise_fma lower to
// v_pk_fma_f32 (2 FMA/inst), halving the scan's VALU issue count (the
// measured limiter: 61% VALUBusy, R8). Same per-element fma order ->
// bit-identical to R8 (absmax canary 0.00757).
// ---------------------------------------------------------------------------
__global__ __launch_bounds__(768) void gru_scan_fused_k(
  const float* __restrict__ gi1, const unsigned short* __restrict__ w1T,
  const float* __restrict__ b1v, const float* __restrict__ m1v,
  float* __restrict__ hc1, float* __restrict__ Hh1o, int nst1,
  const float* __restrict__ gi2, const unsigned short* __restrict__ w2T,
  const float* __restrict__ b2v, const float* __restrict__ m2v,
  float* __restrict__ hc2, float* __restrict__ Hh2o, int nst2)
{
  const int gsel = blockIdx.x & 1;
  const int blk  = blockIdx.x >> 1;
  const float* gi    = gsel ? gi2 : gi1;
  const unsigned short* whhT = gsel ? w2T : w1T;
  const float* bhh   = gsel ? b2v : b1v;
  const float* mask0 = gsel ? m2v : m1v;
  float* hcar        = gsel ? hc2 : hc1;
  float* Hh          = gsel ? Hh2o : Hh1o;
  const int nst      = gsel ? nst2 : nst1;
  if (nst <= 0) return;

  const int t  = threadIdx.x;
  const int b0 = blk*4;
  const int cg = t % 192;            // column group (4 cols)
  const int ks = t / 192;            // k-slice (64 k)
  const int c0 = cg*4;
  const int k0 = ks*64;
  __shared__ __align__(16) float h[4][260];
  __shared__ __align__(16) float part[4][4][776];
  __shared__ float mkz[4];

  const int uj = t & 255;            // update col (t < 512)
  const int ur = t >> 8;             // update rows ur, ur+2
  if (t < 512){
    h[ur  ][uj] = hcar[(size_t)(b0+ur  )*HH + uj];
    h[ur+2][uj] = hcar[(size_t)(b0+ur+2)*HH + uj];
  }
  float br=0.f, bz=0.f, bn_=0.f;
  if (t < 512){ br = bhh[uj]; bz = bhh[uj+HH]; bn_ = bhh[uj+2*HH]; }
  __syncthreads();

  const unsigned short* wbase = whhT + (size_t)k0*G3 + c0;

  for (int st=0; st<nst; ++st){
    float i0r=0,i0z=0,i0n=0, i1r=0,i1z=0,i1n=0;
    if (t < 512){
      const size_t ga = ((size_t)st*BB + b0 + ur  )*G3 + uj;
      const size_t gb = ((size_t)st*BB + b0 + ur+2)*G3 + uj;
      i0r=gi[ga]; i0z=gi[ga+HH]; i0n=gi[ga+2*HH];
      i1r=gi[gb]; i1z=gi[gb+HH]; i1n=gi[gb+2*HH];
    }
    if (t < 4) mkz[t] = mask0[(size_t)st*BB + b0 + t];

    // packed accumulators: row r, col-pair p (cols c0+2p, c0+2p+1)
    f32x2 a0p0={0,0}, a0p1={0,0};
    f32x2 a1p0={0,0}, a1p1={0,0};
    f32x2 a2p0={0,0}, a2p1={0,0};
    f32x2 a3p0={0,0}, a3p1={0,0};
    #pragma unroll 4
    for (int kk=0; kk<64; kk+=4){
      const float4 h0 = *(const float4*)&h[0][k0+kk];
      const float4 h1 = *(const float4*)&h[1][k0+kk];
      const float4 h2 = *(const float4*)&h[2][k0+kk];
      const float4 h3 = *(const float4*)&h[3][k0+kk];
      #pragma unroll
      for (int j=0;j<4;j++){
        const uint2 u_ = *(const uint2*)(wbase + (size_t)(kk+j)*G3);
        f32x2 wA, wB;
        wA.x = __uint_as_float(u_.x << 16);
        wA.y = __uint_as_float(u_.x & 0xffff0000u);
        wB.x = __uint_as_float(u_.y << 16);
        wB.y = __uint_as_float(u_.y & 0xffff0000u);
        const float h0j = (j==0)?h0.x:(j==1)?h0.y:(j==2)?h0.z:h0.w;
        const float h1j = (j==0)?h1.x:(j==1)?h1.y:(j==2)?h1.z:h1.w;
        const float h2j = (j==0)?h2.x:(j==1)?h2.y:(j==2)?h2.z:h2.w;
        const float h3j = (j==0)?h3.x:(j==1)?h3.y:(j==2)?h3.z:h3.w;
        const f32x2 s0 = {h0j, h0j};
        const f32x2 s1 = {h1j, h1j};
        const f32x2 s2 = {h2j, h2j};
        const f32x2 s3 = {h3j, h3j};
        a0p0 = __builtin_elementwise_fma(s0, wA, a0p0);
        a0p1 = __builtin_elementwise_fma(s0, wB, a0p1);
        a1p0 = __builtin_elementwise_fma(s1, wA, a1p0);
        a1p1 = __builtin_elementwise_fma(s1, wB, a1p1);
        a2p0 = __builtin_elementwise_fma(s2, wA, a2p0);
        a2p1 = __builtin_elementwise_fma(s2, wB, a2p1);
        a3p0 = __builtin_elementwise_fma(s3, wA, a3p0);
        a3p1 = __builtin_elementwise_fma(s3, wB, a3p1);
      }
    }
    *(float4*)&part[ks][0][c0] = make_float4(a0p0.x,a0p0.y,a0p1.x,a0p1.y);
    *(float4*)&part[ks][1][c0] = make_float4(a1p0.x,a1p0.y,a1p1.x,a1p1.y);
    *(float4*)&part[ks][2][c0] = make_float4(a2p0.x,a2p0.y,a2p1.x,a2p1.y);
    *(float4*)&part[ks][3][c0] = make_float4(a3p0.x,a3p0.y,a3p1.x,a3p1.y);
    __syncthreads();

    if (t < 512){
      {
        const int r_ = ur;
        const float ar = part[0][r_][uj]+part[1][r_][uj]+part[2][r_][uj]+part[3][r_][uj] + br;
        const float az = part[0][r_][uj+HH]+part[1][r_][uj+HH]+part[2][r_][uj+HH]+part[3][r_][uj+HH] + bz;
        const float an = part[0][r_][uj+2*HH]+part[1][r_][uj+2*HH]+part[2][r_][uj+2*HH]+part[3][r_][uj+2*HH] + bn_;
        const float rr = 1.f/(1.f + __expf(-(i0r + ar)));
        const float zz = 1.f/(1.f + __expf(-(i0z + az)));
        const float nn = tanhf(fmaf(rr, an, i0n));
        const float hold = h[r_][uj];
        const float m = mkz[r_];
        const float hnew = (1.f - zz)*nn + zz*hold;
        const float hv = hnew*m + hold*(1.f - m);
        h[r_][uj] = hv;
        Hh[((size_t)st*BB + b0 + r_)*HH + uj] = hv;
      }
      {
        const int r_ = ur + 2;
        const float ar = part[0][r_][uj]+part[1][r_][uj]+part[2][r_][uj]+part[3][r_][uj] + br;
        const float az = part[0][r_][uj+HH]+part[1][r_][uj+HH]+part[2][r_][uj+HH]+part[3][r_][uj+HH] + bz;
        const float an = part[0][r_][uj+2*HH]+part[1][r_][uj+2*HH]+part[2][r_][uj+2*HH]+part[3][r_][uj+2*HH] + bn_;
        const float rr = 1.f/(1.f + __expf(-(i1r + ar)));
        const float zz = 1.f/(1.f + __expf(-(i1z + az)));
        const float nn = tanhf(fmaf(rr, an, i1n));
        const float hold = h[r_][uj];
        const float m = mkz[r_];
        const float hnew = (1.f - zz)*nn + zz*hold;
        const float hv = hnew*m + hold*(1.f - m);
        h[r_][uj] = hv;
        Hh[((size_t)st*BB + b0 + r_)*HH + uj] = hv;
      }
    }
    __syncthreads();
  }
  if (t < 512){
    hcar[(size_t)(b0+ur  )*HH + uj] = h[ur  ][uj];
    hcar[(size_t)(b0+ur+2)*HH + uj] = h[ur+2][uj];
  }
}

// ---------------------------------------------------------------------------
// Head (fused LN2): x=LN2(row); relu(x@nn1.T+b1) -> LN(8) -> @nn2.T+b2.
// ---------------------------------------------------------------------------
__global__ void head_ln_k(const float* __restrict__ hx,
                          const float* __restrict__ g2, const float* __restrict__ b2,
                          const float* __restrict__ w1, const float* __restrict__ b1,
                          const float* __restrict__ g3, const float* __restrict__ b3,
                          const float* __restrict__ w2, const float* __restrict__ b2h,
                          float* __restrict__ outp, long long r0){
  long long row = blockIdx.x;
  int t = threadIdx.x;
  float v = hx[row*HH + t];
  float s = v, q = v*v;
  #pragma unroll
  for (int o=32;o>0;o>>=1){ s += __shfl_down(s,o); q += __shfl_down(q,o); }
  __shared__ float ssm[4], qqm[4];
  int w = t >> 6;
  if ((t & 63) == 0){ ssm[w] = s; qqm[w] = q; }
  __syncthreads();
  if (t == 0){ ssm[0] = ssm[0]+ssm[1]+ssm[2]+ssm[3]; qqm[0] = qqm[0]+qqm[1]+qqm[2]+qqm[3]; }
  __syncthreads();
  s = ssm[0]; q = qqm[0];
  float mu  = s * (1.f/HH);
  float var = q * (1.f/HH) - mu*mu;
  float rs  = rsqrtf(var + EPSF);
  __shared__ float xs[HH];
  xs[t] = (v - mu)*rs*g2[t] + b2[t];
  __syncthreads();
  int o = t >> 5, l = t & 31;
  const float* wv = w1 + o*HH;
  float acc = 0.f;
  for (int k=l;k<HH;k+=32) acc = fmaf(xs[k], wv[k], acc);
  #pragma unroll
  for (int d=16;d>0;d>>=1) acc += __shfl_down(acc, d, 32);
  __shared__ float a8[8];
  if (l == 0) a8[o] = fmaxf(acc + b1[o], 0.f);
  __syncthreads();
  if (t == 0){
    float ss = 0.f;
    #pragma unroll
    for (int i=0;i<8;i++) ss += a8[i];
    float m8 = ss*0.125f;
    float qq = 0.f;
    #pragma unroll
    for (int i=0;i<8;i++){ float d = a8[i]-m8; qq = fmaf(d,d,qq); }
    float r8 = rsqrtf(qq*0.125f + EPSF);
    float y0 = b2h[0], y1 = b2h[1];
    #pragma unroll
    for (int i=0;i<8;i++){
      float vv = (a8[i]-m8)*r8*g3[i] + b3[i];
      y0 = fmaf(vv, w2[i],   y0);
      y1 = fmaf(vv, w2[8+i], y1);
    }
    outp[(r0+row)*2+0] = y0; outp[(r0+row)*2+1] = y1;
  }
}

// ---------------------------------------------------------------------------
// Host launcher. R9 = R8 + packed-f32 FMA in the scan. Structure frozen.
// ---------------------------------------------------------------------------
extern "C" void kernel_launch(void* const* d_in, const int* in_sizes, int n_in,
                              void* d_out, int out_size, void* d_ws, size_t ws_size,
                              hipStream_t stream) {
  const float* X      = (const float*)d_in[0];
  const float* Mi     = (const float*)d_in[1];
  const float* mask   = (const float*)d_in[2];
  const float* i2h_w  = (const float*)d_in[3];
  const float* i2h_b  = (const float*)d_in[4];
  const float* comb_w = (const float*)d_in[5];
  const float* comb_b = (const float*)d_in[6];
  const float* down_w = (const float*)d_in[7];
  const float* down_b = (const float*)d_in[8];
  const float* conv1_w= (const float*)d_in[9];
  const float* conv1_b= (const float*)d_in[10];
  const float* conv2_w= (const float*)d_in[11];
  const float* conv2_b= (const float*)d_in[12];
  const float* bn1_g  = (const float*)d_in[13];
  const float* bn1_b  = (const float*)d_in[14];
  const float* bn2_g  = (const float*)d_in[15];
  const float* bn2_b  = (const float*)d_in[16];
  const float* r1_wih = (const float*)d_in[17];
  const float* r1_whh = (const float*)d_in[18];
  const float* r1_bih = (const float*)d_in[19];
  const float* r1_bhh = (const float*)d_in[20];
  const float* r1_cw  = (const float*)d_in[21];
  const float* r1_cb  = (const float*)d_in[22];
  const float* r2_wih = (const float*)d_in[23];
  const float* r2_whh = (const float*)d_in[24];
  const float* r2_bih = (const float*)d_in[25];
  const float* r2_bhh = (const float*)d_in[26];
  const float* r2_cw  = (const float*)d_in[27];
  const float* r2_cb  = (const float*)d_in[28];
  const float* ln1_g  = (const float*)d_in[29];
  const float* ln1_b  = (const float*)d_in[30];
  const float* ln2_g  = (const float*)d_in[31];
  const float* ln2_b  = (const float*)d_in[32];
  const float* ln3_g  = (const float*)d_in[33];
  const float* ln3_b  = (const float*)d_in[34];
  const float* nn1_w  = (const float*)d_in[35];
  const float* nn1_b  = (const float*)d_in[36];
  const float* nn2_w  = (const float*)d_in[37];
  const float* nn2_b  = (const float*)d_in[38];
  float* outp = (float*)d_out;

  // ushort region: C2{h,l} W2F{h,l} WI1{h,l} WI2{h,l} CW1{h,l} CW2{h,l} + W1Tb + W2Tb
  const size_t us_elems = 2*((size_t)HH*HH + (size_t)HH*HH + (size_t)G3*HH
                           + (size_t)G3*HH + (size_t)HH*2*HH + (size_t)HH*2*HH)
                        + 2*(size_t)G3*HH;
  const size_t tail_floats = 2*(size_t)BB*HH + 2*(size_t)NPART*HH + 2*HH
                           + (size_t)256*40 + 256 + (size_t)HH*HH + 256
                           + (size_t)SB*CC
                           + (us_elems + 1)/2;
  // per-chunk rows: A(256) + GI1(768, Cxp aliased) + GI2(768) + Ee(256)
  //               + Hh2(256) + Hx1(256) = 2560 floats/row
  int cands[6] = {256,128,64,32,16,8};
  int sc_chunk = 0;
  for (int ci=0; ci<6; ci++){
    size_t R = (size_t)512*cands[ci];
    size_t need = (R*2560 + tail_floats)*sizeof(float);
    if (need <= ws_size && R*2560 >= (size_t)SB*HH){ sc_chunk = cands[ci]; break; }
  }
  if (!sc_chunk) return;

  const size_t R = (size_t)512*sc_chunk;     // rows per chunk
  const int Ri = (int)R;
  const int nchunks = SB / Ri;

  float* wsf = (float*)d_ws;
  float* A   = wsf;                    // R*256  (res -> hx)
  float* GI1 = A + R*HH;               // R*768  gi for GRU1(c)
  float* Cxp = GI1;                    // ALIAS: GI1 dead after scan; Cxp lives after
  float* GI2 = GI1 + R*G3;             // R*768  gi for GRU2(c)
  float* Ee  = GI2 + R*G3;             // R*256  out1r -> Hh1
  float* Hh2 = Ee + R*HH;              // R*256  Hh of GRU2(c-1)
  float* Hx1 = Hh2 + R*HH;             // R*256  hx1(c) = LN1 out
  float* tl  = Hx1 + R*HH;
  float* H1C = tl;                     // BB*HH
  float* H2C = H1C + (size_t)BB*HH;
  float* PS  = H2C + (size_t)BB*HH;    // NPART*HH
  float* PQ  = PS  + (size_t)NPART*HH;
  float* SCv = PQ  + (size_t)NPART*HH; // HH
  float* SHv = SCv + HH;
  float* W1F = SHv + HH;               // 256*40
  float* B1F = W1F + (size_t)256*40;   // 256
  float* W2F = B1F + HH;               // 256*256
  float* B2F = W2F + (size_t)HH*HH;    // 256
  float* XcF = B2F + HH;               // SB*40 persisted comb output
  unsigned short* usb = (unsigned short*)(XcF + (size_t)SB*CC);
  unsigned short* C2H  = usb;                       // conv2_w raw split (HH*HH)
  unsigned short* C2L  = C2H  + (size_t)HH*HH;
  unsigned short* W2FH = C2L  + (size_t)HH*HH;      // folded conv2 (HH*HH)
  unsigned short* W2FL = W2FH + (size_t)HH*HH;
  unsigned short* WI1H = W2FL + (size_t)HH*HH;      // r1_wih (G3*HH)
  unsigned short* WI1L = WI1H + (size_t)G3*HH;
  unsigned short* WI2H = WI1L + (size_t)G3*HH;      // r2_wih (G3*HH)
  unsigned short* WI2L = WI2H + (size_t)G3*HH;
  unsigned short* CW1H = WI2L + (size_t)G3*HH;      // r1_cw (HH*2HH)
  unsigned short* CW1L = CW1H + (size_t)HH*2*HH;
  unsigned short* CW2H = CW1L + (size_t)HH*2*HH;    // r2_cw (HH*2HH)
  unsigned short* CW2L = CW2H + (size_t)HH*2*HH;
  unsigned short* W1Tb = CW2L + (size_t)HH*2*HH;    // whhT bf16 (256x768) GRU1
  unsigned short* W2Tb = W1Tb + (size_t)HH*G3;      // whhT bf16 (256x768) GRU2

  // one-time transposes + static weight splits
  whht_bf_k<<<(G3*HH + 255)/256, 256, 0, stream>>>(r1_whh, W1Tb);
  whht_bf_k<<<(G3*HH + 255)/256, 256, 0, stream>>>(r2_whh, W2Tb);
  split_w_k<<<(HH*HH + 255)/256, 256, 0, stream>>>(conv2_w, C2H, C2L, HH*HH);
  split_w_k<<<(G3*HH + 255)/256, 256, 0, stream>>>(r1_wih, WI1H, WI1L, G3*HH);
  split_w_k<<<(G3*HH + 255)/256, 256, 0, stream>>>(r2_wih, WI2H, WI2L, G3*HH);
  split_w_k<<<(HH*2*HH + 255)/256, 256, 0, stream>>>(r1_cw, CW1H, CW1L, HH*2*HH);
  split_w_k<<<(HH*2*HH + 255)/256, 256, 0, stream>>>(r2_cw, CW2H, CW2L, HH*2*HH);

  const int MB = Ri/128;

  // ---------- pass A: ONE sweep over all SB rows (scratch = per-chunk region) ----------
  {
    float* SA = wsf;                          // SB*HH scratch (33.5M <= R*2560)
    gemm_tn<0,1><<<dim3(SB/128,1), 256, 0, stream>>>(X, II, comb_w, 80, comb_b, XcF, CC, SB, CC, 80, Mi, 0);
    gemm_tn<0,0><<<dim3(SB/128,2), 256, 0, stream>>>(XcF, CC, conv1_w, CC, conv1_b, SA, HH, SB, HH, CC, nullptr, 0);
    bn_partial_k<<<SB/64, 256, 0, stream>>>(SA, PS, PQ, 0);
  }
  bn_final_k<<<1, 256, 0, stream>>>(PS, PQ, bn1_g, bn1_b, SCv, SHv);
  fold_k<<<(256*40 + 255)/256, 256, 0, stream>>>(conv1_w, conv1_b, SCv, SHv, W1F, B1F, 40);

  // ---------- pass B: TWO half-sweeps (needs 2x SB/2*HH scratch) ----------
  {
    float* SA2 = wsf;                         // SB/2*HH
    float* SB2 = wsf + (size_t)(SB/2)*HH;     // SB/2*HH
    for (int hlf=0; hlf<2; hlf++){
      long long r0 = (long long)hlf*(SB/2);
      gemm_tn<1,0><<<dim3(SB/256,2), 256, 0, stream>>>(XcF + r0*CC, CC, W1F, CC, B1F, SA2, HH, SB/2, HH, CC, nullptr, 0);
      gemm_mfp<0><<<dim3(SB/256,2), 256, 0, stream>>>(SA2, HH, C2H, C2L, HH, conv2_b, SB2, HH, HH, HH);
      bn_partial_k<<<(SB/2)/64, 256, 0, stream>>>(SB2, PS, PQ, (int)(r0/64));
    }
  }
  bn_final_k<<<1, 256, 0, stream>>>(PS, PQ, bn2_g, bn2_b, SCv, SHv);
  fold_k<<<(256*256 + 255)/256, 256, 0, stream>>>(conv2_w, conv2_b, SCv, SHv, W2F, B2F, 256);
  split_w_k<<<(HH*HH + 255)/256, 256, 0, stream>>>(W2F, W2FH, W2FL, HH*HH);

  // ---------- h0 -> carries ----------
  h0_k<<<BB, HH, 0, stream>>>(X, i2h_w, i2h_b, H1C, H2C);

  // ---------- pass C: pipelined main loop ----------
  for (int c=0;c<nchunks;c++){
    long long r0 = (long long)c*R;
    long long rp = r0 - (long long)R;   // previous chunk base (valid for c>0)
    // ---- S1(c): {res, out1r} fused, then hx, gi1
    gemm_tn_dual2<<<dim3(MB,2), 256, 0, stream>>>(X, r0, down_w, down_b, A,
                                                  XcF + r0*CC, W1F, B1F, Ee, Ri);
    gemm_mfp<2><<<dim3(MB,2), 256, 0, stream>>>(Ee, HH, W2FH, W2FL, HH, B2F, A, HH, HH, HH);     // hx
    gemm_mfp<0><<<dim3(MB,6), 256, 0, stream>>>(A, HH, WI1H, WI1L, HH, r1_bih, GI1, G3, G3, HH); // gi1
    // ---- fused scan: GRU1(c) || GRU2(c-1)
    gru_scan_fused_k<<<2*(BB/4), 768, 0, stream>>>(
        GI1, W1Tb, r1_bhh, mask + r0, H1C, Ee, sc_chunk,
        GI2, W2Tb, r2_bhh, (c > 0) ? (mask + rp) : mask, H2C, Hh2, (c > 0) ? sc_chunk : 0);
    // ---- S3(c-1): finish previous chunk (Cxp = GI1 region, dead after scan)
    if (c > 0){
      gemm_mfp_dual<<<dim3(MB,2), 256, 0, stream>>>(Hx1, Hh2, CW2H, CW2L, r2_cb, Cxp, HH, HH);   // outs2
      head_ln_k<<<Ri, 256, 0, stream>>>(Cxp, ln2_g, ln2_b, nn1_w, nn1_b, ln3_g, ln3_b, nn2_w, nn2_b, outp, rp);
    }
    // ---- S2(c): GRU1 out-projection, LN1, gi2(c)
    gemm_mfp_dual<<<dim3(MB,2), 256, 0, stream>>>(A, Ee, CW1H, CW1L, r1_cb, Cxp, HH, HH);        // outs1
    ln_rows_k<<<Ri, 256, 0, stream>>>(Cxp, Hx1, ln1_g, ln1_b);                                    // hx1(c)
    gemm_mfp<0><<<dim3(MB,6), 256, 0, stream>>>(Hx1, HH, WI2H, WI2L, HH, r2_bih, GI2, G3, G3, HH); // gi2(c)
  }
  // ---------- drain: GRU2(last chunk) ----------
  {
    long long rl = (long long)(nchunks-1)*R;
    gru_scan_fused_k<<<2*(BB/4), 768, 0, stream>>>(
        GI1, W1Tb, r1_bhh, mask, H1C, Ee, 0,
        GI2, W2Tb, r2_bhh, mask + rl, H2C, Hh2, sc_chunk);
    gemm_mfp_dual<<<dim3(MB,2), 256, 0, stream>>>(Hx1, Hh2, CW2H, CW2L, r2_cb, Cxp, HH, HH);
    head_ln_k<<<Ri, 256, 0, stream>>>(Cxp, ln2_g, ln2_b, nn1_w, nn1_b, ln3_g, ln3_b, nn2_w, nn2_b, outp, rl);
  }
}

// Round 10
// 5902.750 us; speedup vs baseline: 1.1415x; 1.0901x over previous
//
#include <hip/hip_runtime.h>
#include <hip/hip_bf16.h>

// Problem dims
#define SS 256
#define BB 512
#define II 46
#define HH 256
#define CC 40
#define SB (SS*BB)        // 131072 rows
#define G3 (3*HH)         // 768
#define EPSF 1e-5f
#define NPART (SB/64)     // 2048 bn partials

typedef __attribute__((ext_vector_type(8))) short bf16x8;
typedef __attribute__((ext_vector_type(4))) float f32x4;

// ---------------------------------------------------------------------------
// helpers
// ---------------------------------------------------------------------------
__device__ __forceinline__ unsigned short f2bf_rne(float f){
  unsigned u = __float_as_uint(f);
  unsigned r = (u + 0x7FFFu + ((u >> 16) & 1u)) >> 16;
  return (unsigned short)r;
}
__device__ __forceinline__ float bf2f(unsigned short b){
  return __uint_as_float(((unsigned)b) << 16);
}
__device__ __forceinline__ void cvt8(const float* v, bf16x8& hi, bf16x8& lo){
  #pragma unroll
  for (int e=0;e<8;e++){
    unsigned short hb = f2bf_rne(v[e]);
    hi[e] = (short)hb;
    lo[e] = (short)f2bf_rne(v[e] - bf2f(hb));
  }
}

// ---------------------------------------------------------------------------
// split f32 weight array -> bf16 {hi, lo}
// ---------------------------------------------------------------------------
__global__ void split_w_k(const float* __restrict__ w, unsigned short* __restrict__ wh,
                          unsigned short* __restrict__ wl, int n){
  int i = blockIdx.x*256 + threadIdx.x;
  if (i >= n) return;
  float v = w[i];
  unsigned short hb = f2bf_rne(v);
  wh[i] = hb;
  wl[i] = f2bf_rne(v - bf2f(hb));
}

// ---------------------------------------------------------------------------
// h0[b,j] = sum_{c<6} X[0,b,40+c] * i2h_w[j,c] + i2h_b[j]  -> both carries
// ---------------------------------------------------------------------------
__global__ void h0_k(const float* __restrict__ X, const float* __restrict__ w,
                     const float* __restrict__ bias, float* __restrict__ h1c,
                     float* __restrict__ h2c){
  int b = blockIdx.x, jj = threadIdx.x;
  const float* p = X + (long long)b*II + (II - 6);
  float acc = bias[jj];
  #pragma unroll
  for (int c2=0;c2<6;c2++) acc = fmaf(p[c2], w[jj*6 + c2], acc);
  h1c[(long long)b*HH + jj] = acc;
  h2c[(long long)b*HH + jj] = acc;
}

// ---------------------------------------------------------------------------
// Pre-format whh (768x256) into MFMA B-fragment order, bf16 (R10).
// Fragment (ntile, kt): lane l, elem e holds B[k][n] = whh[n][k] with
// n = ntile*16 + (l&15), k = kt*32 + (l>>4)*8 + e  — the exact layout the
// proven gemm_mf kernel reads. 48 ntiles x 8 kt = 384 frags x 64 lanes x 8.
// ---------------------------------------------------------------------------
__global__ void wfrag_k(const float* __restrict__ whh, unsigned short* __restrict__ wf){
  int tid = blockIdx.x*256 + threadIdx.x;       // 384*64 = 24576 total
  if (tid >= 384*64) return;
  int f = tid >> 6, l = tid & 63;
  int ntile = f >> 3, kt = f & 7;
  int col = ntile*16 + (l & 15);
  int k0  = kt*32 + (l >> 4)*8;
  unsigned short* dst = wf + (((size_t)f)*64 + l)*8;
  #pragma unroll
  for (int e=0;e<8;e++) dst[e] = f2bf_rne(whh[(size_t)col*HH + k0 + e]);
}

// ---------------------------------------------------------------------------
// Generic f32 GEMM (small-K ops: comb K=80, conv1 K=40).
// MODE 0: store; 1: store relu; 2: accumulate.
// XM 1: A is implicit [X | Mi] with row stride II; A=X base, A2=Mi base, +r0.
// ---------------------------------------------------------------------------
template<int MODE, int XM>
__global__ void gemm_tn(const float* __restrict__ A, int lda,
                        const float* __restrict__ W, int ldw,
                        const float* __restrict__ bias,
                        float* __restrict__ Co, int ldc,
                        int Mrows, int N, int K,
                        const float* __restrict__ A2, long long r0)
{
  __shared__ __align__(16) float As[32][132];
  __shared__ __align__(16) float Ws[32][132];
  const int m0 = blockIdx.x*128, n0 = blockIdx.y*128;
  const int t  = threadIdx.x;
  const int tm = t >> 4, tn = t & 15;
  float acc[8][8];
  #pragma unroll
  for (int i=0;i<8;i++)
    #pragma unroll
    for (int j2=0;j2<8;j2++) acc[i][j2] = 0.f;

  for (int k0=0;k0<K;k0+=32){
    #pragma unroll
    for (int u=0;u<16;u++){
      int idx = u*256 + t;
      int r = idx >> 5, c = idx & 31;
      int gk = k0 + c;
      float av = 0.f, wv = 0.f;
      if (gk < K){
        int gm = m0 + r;
        if (gm < Mrows){
          if (XM){
            long long gr = r0 + gm;
            av = (gk < CC) ? A[gr*II + gk] : A2[gr*II + (gk - CC)];
          } else {
            av = A[(long long)gm*lda + gk];
          }
        }
        int gn = n0 + r;
        if (gn < N)     wv = W[(long long)gn*ldw + gk];
      }
      As[c][r] = av;
      Ws[c][r] = wv;
    }
    __syncthreads();
    #pragma unroll
    for (int kk=0;kk<32;kk++){
      const float4 a0 = *(const float4*)&As[kk][tm*8];
      const float4 a1 = *(const float4*)&As[kk][tm*8+4];
      const float4 b0 = *(const float4*)&Ws[kk][tn*8];
      const float4 b1 = *(const float4*)&Ws[kk][tn*8+4];
      const float av[8] = {a0.x,a0.y,a0.z,a0.w,a1.x,a1.y,a1.z,a1.w};
      const float bv[8] = {b0.x,b0.y,b0.z,b0.w,b1.x,b1.y,b1.z,b1.w};
      #pragma unroll
      for (int i=0;i<8;i++)
        #pragma unroll
        for (int j2=0;j2<8;j2++) acc[i][j2] = fmaf(av[i], bv[j2], acc[i][j2]);
    }
    __syncthreads();
  }
  #pragma unroll
  for (int i=0;i<8;i++){
    int gm = m0 + tm*8 + i;
    if (gm < Mrows){
      #pragma unroll
      for (int j2=0;j2<8;j2++){
        int gn = n0 + tn*8 + j2;
        if (gn < N){
          long long oi = (long long)gm*ldc + gn;
          float val = acc[i][j2] + bias[gn];
          if (MODE == 1) val = fmaxf(val, 0.f);
          if (MODE == 2) val += Co[oi];
          Co[oi] = val;
        }
      }
    }
  }
}

// ---------------------------------------------------------------------------
// Dual-output small-K GEMM (S1 fusion): res + relu(out1) in one dispatch.
// ---------------------------------------------------------------------------
__global__ void gemm_tn_dual2(const float* __restrict__ Xb, long long r0,
                              const float* __restrict__ W1, const float* __restrict__ b1,
                              float* __restrict__ Co1,
                              const float* __restrict__ A2, const float* __restrict__ W2,
                              const float* __restrict__ b2, float* __restrict__ Co2,
                              int Mrows)
{
  __shared__ __align__(16) float As1[32][132];
  __shared__ __align__(16) float As2[32][132];
  __shared__ __align__(16) float Ws1[32][132];
  __shared__ __align__(16) float Ws2[32][132];
  const int m0 = blockIdx.x*128, n0 = blockIdx.y*128;
  const int t  = threadIdx.x;
  const int tm = t >> 4, tn = t & 15;
  float acc1[8][8], acc2[8][8];
  #pragma unroll
  for (int i=0;i<8;i++)
    #pragma unroll
    for (int j2=0;j2<8;j2++){ acc1[i][j2] = 0.f; acc2[i][j2] = 0.f; }

  for (int k0=0;k0<CC;k0+=32){
    #pragma unroll
    for (int u=0;u<16;u++){
      int idx = u*256 + t;
      int r = idx >> 5, c = idx & 31;
      int gk = k0 + c;
      float a1=0.f, a2=0.f, w1=0.f, w2=0.f;
      if (gk < CC){
        int gm = m0 + r;
        if (gm < Mrows){
          long long gr = r0 + gm;
          a1 = Xb[gr*II + gk];
          a2 = A2[(long long)gm*CC + gk];
        }
        int gn = n0 + r;
        w1 = W1[(long long)gn*CC + gk];
        w2 = W2[(long long)gn*CC + gk];
      }
      As1[c][r] = a1; As2[c][r] = a2;
      Ws1[c][r] = w1; Ws2[c][r] = w2;
    }
    __syncthreads();
    #pragma unroll
    for (int kk=0;kk<32;kk++){
      const float4 p0 = *(const float4*)&As1[kk][tm*8];
      const float4 p1 = *(const float4*)&As1[kk][tm*8+4];
      const float4 q0 = *(const float4*)&As2[kk][tm*8];
      const float4 q1 = *(const float4*)&As2[kk][tm*8+4];
      const float4 u0 = *(const float4*)&Ws1[kk][tn*8];
      const float4 u1 = *(const float4*)&Ws1[kk][tn*8+4];
      const float4 v0 = *(const float4*)&Ws2[kk][tn*8];
      const float4 v1 = *(const float4*)&Ws2[kk][tn*8+4];
      const float a1v[8] = {p0.x,p0.y,p0.z,p0.w,p1.x,p1.y,p1.z,p1.w};
      const float a2v[8] = {q0.x,q0.y,q0.z,q0.w,q1.x,q1.y,q1.z,q1.w};
      const float w1v[8] = {u0.x,u0.y,u0.z,u0.w,u1.x,u1.y,u1.z,u1.w};
      const float w2v[8] = {v0.x,v0.y,v0.z,v0.w,v1.x,v1.y,v1.z,v1.w};
      #pragma unroll
      for (int i=0;i<8;i++)
        #pragma unroll
        for (int j2=0;j2<8;j2++){
          acc1[i][j2] = fmaf(a1v[i], w1v[j2], acc1[i][j2]);
          acc2[i][j2] = fmaf(a2v[i], w2v[j2], acc2[i][j2]);
        }
    }
    __syncthreads();
  }
  #pragma unroll
  for (int i=0;i<8;i++){
    int gm = m0 + tm*8 + i;
    if (gm < Mrows){
      #pragma unroll
      for (int j2=0;j2<8;j2++){
        int gn = n0 + tn*8 + j2;
        long long oi = (long long)gm*HH + gn;
        Co1[oi] = acc1[i][j2] + b1[gn];
        Co2[oi] = fmaxf(acc2[i][j2] + b2[gn], 0.f);
      }
    }
  }
}

// ---------------------------------------------------------------------------
// Split-bf16 MFMA GEMM with PRE-SPLIT B. MODE 0: store; 2: accumulate.
// ---------------------------------------------------------------------------
template<int MODE>
__global__ __launch_bounds__(256) void gemm_mfp(
    const float* __restrict__ A, int lda,
    const unsigned short* __restrict__ Wh, const unsigned short* __restrict__ Wl, int ldw,
    const float* __restrict__ bias,
    float* __restrict__ Co, int ldc,
    int N, int K)
{
  __shared__ __align__(16) unsigned short Ah[128*32];
  __shared__ __align__(16) unsigned short Al[128*32];
  __shared__ __align__(16) unsigned short Bh[128*32];
  __shared__ __align__(16) unsigned short Bl[128*32];
  const int t = threadIdx.x;
  const int m0 = blockIdx.x*128, n0 = blockIdx.y*128;
  const int lane = t & 63, w = t >> 6;
  const int wm = (w & 1)*64, wn = (w >> 1)*64;
  const int fr = lane & 15, fg = lane >> 4;

  f32x4 acc[4][4];
  #pragma unroll
  for (int i=0;i<4;i++)
    #pragma unroll
    for (int j=0;j<4;j++){ f32x4 z; z[0]=0;z[1]=0;z[2]=0;z[3]=0; acc[i][j]=z; }

  for (int k0=0; k0<K; k0+=32){
    #pragma unroll
    for (int cc=0; cc<2; cc++){
      const int c   = t + cc*256;
      const int row = c >> 2, kg = c & 3;
      const int byte = row*64 + ((kg*16) ^ (((row>>1)&3)<<4));
      {
        const float* ap = A + (size_t)(m0+row)*lda + k0 + kg*8;
        float v[8];
        *(float4*)&v[0] = *(const float4*)ap;
        *(float4*)&v[4] = *(const float4*)(ap+4);
        bf16x8 hi, lo; cvt8(v, hi, lo);
        *(bf16x8*)((char*)Ah + byte) = hi;
        *(bf16x8*)((char*)Al + byte) = lo;
      }
      {
        const size_t off = (size_t)(n0+row)*ldw + k0 + kg*8;
        *(bf16x8*)((char*)Bh + byte) = *(const bf16x8*)&Wh[off];
        *(bf16x8*)((char*)Bl + byte) = *(const bf16x8*)&Wl[off];
      }
    }
    __syncthreads();
    bf16x8 ahi[4], alo[4], bhi[4], blo[4];
    #pragma unroll
    for (int mt=0; mt<4; mt++){
      const int r = wm + mt*16 + fr;
      const int byte = r*64 + ((fg*16) ^ (((r>>1)&3)<<4));
      ahi[mt] = *(const bf16x8*)((const char*)Ah + byte);
      alo[mt] = *(const bf16x8*)((const char*)Al + byte);
    }
    #pragma unroll
    for (int nt=0; nt<4; nt++){
      const int r = wn + nt*16 + fr;
      const int byte = r*64 + ((fg*16) ^ (((r>>1)&3)<<4));
      bhi[nt] = *(const bf16x8*)((const char*)Bh + byte);
      blo[nt] = *(const bf16x8*)((const char*)Bl + byte);
    }
    #pragma unroll
    for (int mt=0; mt<4; mt++)
      #pragma unroll
      for (int nt=0; nt<4; nt++){
        acc[mt][nt] = __builtin_amdgcn_mfma_f32_16x16x32_bf16(alo[mt], bhi[nt], acc[mt][nt], 0,0,0);
        acc[mt][nt] = __builtin_amdgcn_mfma_f32_16x16x32_bf16(ahi[mt], blo[nt], acc[mt][nt], 0,0,0);
        acc[mt][nt] = __builtin_amdgcn_mfma_f32_16x16x32_bf16(ahi[mt], bhi[nt], acc[mt][nt], 0,0,0);
      }
    __syncthreads();
  }

  #pragma unroll
  for (int mt=0; mt<4; mt++){
    #pragma unroll
    for (int nt=0; nt<4; nt++){
      const int col = n0 + wn + nt*16 + fr;
      const float bv = bias[col];
      #pragma unroll
      for (int i=0;i<4;i++){
        const int row = m0 + wm + mt*16 + fg*4 + i;
        const size_t oi = (size_t)row*ldc + col;
        float val = acc[mt][nt][i] + bv;
        if (MODE == 2) val += Co[oi];
        Co[oi] = val;
      }
    }
  }
}

// ---------------------------------------------------------------------------
// Dual-A fused out-projection GEMM with pre-split B (cw).
// ---------------------------------------------------------------------------
__global__ __launch_bounds__(256) void gemm_mfp_dual(
    const float* __restrict__ A1, const float* __restrict__ A2,
    const unsigned short* __restrict__ Wh, const unsigned short* __restrict__ Wl,
    const float* __restrict__ bias,
    float* __restrict__ Co, int ldc, int N)
{
  __shared__ __align__(16) unsigned short Ah[128*32];
  __shared__ __align__(16) unsigned short Al[128*32];
  __shared__ __align__(16) unsigned short Bh[128*32];
  __shared__ __align__(16) unsigned short Bl[128*32];
  const int t = threadIdx.x;
  const int m0 = blockIdx.x*128, n0 = blockIdx.y*128;
  const int lane = t & 63, w = t >> 6;
  const int wm = (w & 1)*64, wn = (w >> 1)*64;
  const int fr = lane & 15, fg = lane >> 4;

  f32x4 acc[4][4];
  #pragma unroll
  for (int i=0;i<4;i++)
    #pragma unroll
    for (int j=0;j<4;j++){ f32x4 z; z[0]=0;z[1]=0;z[2]=0;z[3]=0; acc[i][j]=z; }

  for (int k0=0; k0<2*HH; k0+=32){
    const float* Abase = (k0 < HH) ? A1 : A2;
    const int    kofs  = (k0 < HH) ? k0 : (k0 - HH);
    #pragma unroll
    for (int cc=0; cc<2; cc++){
      const int c   = t + cc*256;
      const int row = c >> 2, kg = c & 3;
      const int byte = row*64 + ((kg*16) ^ (((row>>1)&3)<<4));
      {
        const float* ap = Abase + (size_t)(m0+row)*HH + kofs + kg*8;
        float v[8];
        *(float4*)&v[0] = *(const float4*)ap;
        *(float4*)&v[4] = *(const float4*)(ap+4);
        bf16x8 hi, lo; cvt8(v, hi, lo);
        *(bf16x8*)((char*)Ah + byte) = hi;
        *(bf16x8*)((char*)Al + byte) = lo;
      }
      {
        const size_t off = (size_t)(n0+row)*(2*HH) + k0 + kg*8;
        *(bf16x8*)((char*)Bh + byte) = *(const bf16x8*)&Wh[off];
        *(bf16x8*)((char*)Bl + byte) = *(const bf16x8*)&Wl[off];
      }
    }
    __syncthreads();
    bf16x8 ahi[4], alo[4], bhi[4], blo[4];
    #pragma unroll
    for (int mt=0; mt<4; mt++){
      const int r = wm + mt*16 + fr;
      const int byte = r*64 + ((fg*16) ^ (((r>>1)&3)<<4));
      ahi[mt] = *(const bf16x8*)((const char*)Ah + byte);
      alo[mt] = *(const bf16x8*)((const char*)Al + byte);
    }
    #pragma unroll
    for (int nt=0; nt<4; nt++){
      const int r = wn + nt*16 + fr;
      const int byte = r*64 + ((fg*16) ^ (((r>>1)&3)<<4));
      bhi[nt] = *(const bf16x8*)((const char*)Bh + byte);
      blo[nt] = *(const bf16x8*)((const char*)Bl + byte);
    }
    #pragma unroll
    for (int mt=0; mt<4; mt++)
      #pragma unroll
      for (int nt=0; nt<4; nt++){
        acc[mt][nt] = __builtin_amdgcn_mfma_f32_16x16x32_bf16(alo[mt], bhi[nt], acc[mt][nt], 0,0,0);
        acc[mt][nt] = __builtin_amdgcn_mfma_f32_16x16x32_bf16(ahi[mt], blo[nt], acc[mt][nt], 0,0,0);
        acc[mt][nt] = __builtin_amdgcn_mfma_f32_16x16x32_bf16(ahi[mt], bhi[nt], acc[mt][nt], 0,0,0);
      }
    __syncthreads();
  }

  #pragma unroll
  for (int mt=0; mt<4; mt++){
    #pragma unroll
    for (int nt=0; nt<4; nt++){
      const int col = n0 + wn + nt*16 + fr;
      const float bv = bias[col];
      #pragma unroll
      for (int i=0;i<4;i++){
        const int row = m0 + wm + mt*16 + fg*4 + i;
        const size_t oi = (size_t)row*ldc + col;
        Co[oi] = acc[mt][nt][i] + bv;
      }
    }
  }
}

// ---------------------------------------------------------------------------
// BatchNorm stats (64 rows/block) + fold
// ---------------------------------------------------------------------------
__global__ void bn_partial_k(const float* __restrict__ Xc, float* __restrict__ ps,
                             float* __restrict__ pq, int pblk0){
  int blk = blockIdx.x, t = threadIdx.x;
  long long base = (long long)blk*64*HH;
  float s = 0.f, q = 0.f;
  for (int r=0;r<64;r++){
    float v = Xc[base + (long long)r*HH + t];
    s += v; q = fmaf(v, v, q);
  }
  ps[(size_t)(pblk0+blk)*HH + t] = s;
  pq[(size_t)(pblk0+blk)*HH + t] = q;
}

__global__ void bn_final_k(const float* __restrict__ ps, const float* __restrict__ pq,
                           const float* __restrict__ g, const float* __restrict__ b,
                           float* __restrict__ sc, float* __restrict__ sh){
  int t = threadIdx.x;
  double s = 0.0, q = 0.0;
  for (int i=0;i<NPART;i++){ s += (double)ps[(size_t)i*HH + t]; q += (double)pq[(size_t)i*HH + t]; }
  double mu  = s / (double)SB;
  double var = q / (double)SB - mu*mu;
  float scv = (float)((double)g[t] / sqrt(var + 1e-5));
  sc[t] = scv;
  sh[t] = (float)((double)b[t] - mu*(double)scv);
}

__global__ void fold_k(const float* __restrict__ w, const float* __restrict__ b,
                       const float* __restrict__ sc, const float* __restrict__ sh,
                       float* __restrict__ wf, float* __restrict__ bf, int K){
  int idx = blockIdx.x*blockDim.x + threadIdx.x;
  if (idx < 256*K){ int o = idx / K; wf[idx] = w[idx]*sc[o]; }
  if (idx < 256)  bf[idx] = b[idx]*sc[idx] + sh[idx];
}

// ---------------------------------------------------------------------------
// LayerNorm over last dim (256), out-of-place. One block per row.
// ---------------------------------------------------------------------------
__global__ void ln_rows_k(const float* __restrict__ Xi, float* __restrict__ Xo,
                          const float* __restrict__ g, const float* __restrict__ b){
  long long row = blockIdx.x;
  int t = threadIdx.x;
  float v = Xi[row*HH + t];
  float s = v, q = v*v;
  #pragma unroll
  for (int o=32;o>0;o>>=1){ s += __shfl_down(s,o); q += __shfl_down(q,o); }
  __shared__ float ssm[4], qqm[4];
  int w = t >> 6;
  if ((t & 63) == 0){ ssm[w] = s; qqm[w] = q; }
  __syncthreads();
  if (t == 0){ ssm[0] = ssm[0]+ssm[1]+ssm[2]+ssm[3]; qqm[0] = qqm[0]+qqm[1]+qqm[2]+qqm[3]; }
  __syncthreads();
  s = ssm[0]; q = qqm[0];
  float mu  = s * (1.f/HH);
  float var = q * (1.f/HH) - mu*mu;
  float rs  = rsqrtf(var + EPSF);
  Xo[row*HH + t] = (v - mu)*rs*g[t] + b[t];
}

// ---------------------------------------------------------------------------
// FUSED dual-GRU gate scan — MFMA edition (R10).
// Even blocks: GRU1(c); odd: GRU2(c-1). 512 threads = 8 waves; each wave owns
// 6 N-tiles of the (4x256)@(256x768) per-step matvec via mfma 16x16x32 bf16
// (A = h split hi/lo -> f32-grade, B = bf16 weights = R8/R9 numerics).
// h lives in registers; gate writes bf16 hi/lo A-staging for the next step;
// gh accumulated over full K (no k-split part sums). Weights read as
// pre-formatted fragments (wfrag_k) — layout identical to gemm_mf's B.
// ---------------------------------------------------------------------------
__global__ __launch_bounds__(512) void gru_scan_mfma_k(
  const float* __restrict__ gi1, const unsigned short* __restrict__ wf1,
  const float* __restrict__ b1v, const float* __restrict__ m1v,
  float* __restrict__ hc1, float* __restrict__ Hh1o, int nst1,
  const float* __restrict__ gi2, const unsigned short* __restrict__ wf2,
  const float* __restrict__ b2v, const float* __restrict__ m2v,
  float* __restrict__ hc2, float* __restrict__ Hh2o, int nst2)
{
  const int gsel = blockIdx.x & 1;
  const int blk  = blockIdx.x >> 1;
  const float* gi    = gsel ? gi2 : gi1;
  const unsigned short* wfr = gsel ? wf2 : wf1;
  const float* bhh   = gsel ? b2v : b1v;
  const float* mask0 = gsel ? m2v : m1v;
  float* hcar        = gsel ? hc2 : hc1;
  float* Hh          = gsel ? Hh2o : Hh1o;
  const int nst      = gsel ? nst2 : nst1;
  if (nst <= 0) return;

  const int t    = threadIdx.x;
  const int b0   = blk*4;
  const int lane = t & 63, wid = t >> 6;      // 8 waves
  const int arow = lane & 15, kg = lane >> 4; // A-fragment coords
  const bool act = (arow < 4);
  const int uj = t & 255, ur = t >> 8;        // gate coords: rows ur, ur+2

  __shared__ __align__(16) unsigned short AhS[4][256];
  __shared__ __align__(16) unsigned short AlS[4][256];
  __shared__ __align__(16) float ghS[4][768];
  __shared__ float mkz[4];

  // persistent h in registers (rows ur and ur+2 of this thread's column uj)
  float hold0 = hcar[(size_t)(b0+ur  )*HH + uj];
  float hold1 = hcar[(size_t)(b0+ur+2)*HH + uj];
  const float br = bhh[uj], bz = bhh[uj+HH], bn_ = bhh[uj+2*HH];

  // init A staging from carries
  {
    unsigned short hb0 = f2bf_rne(hold0);
    AhS[ur  ][uj] = hb0;  AlS[ur  ][uj] = f2bf_rne(hold0 - bf2f(hb0));
    unsigned short hb1 = f2bf_rne(hold1);
    AhS[ur+2][uj] = hb1;  AlS[ur+2][uj] = f2bf_rne(hold1 - bf2f(hb1));
  }
  __syncthreads();

  // wave's fragment base: ntiles wid*6 .. wid*6+5; frag stride = 64*8 ushorts
  const unsigned short* wfbase = wfr + (((size_t)(wid*6)*8)*64 + lane)*8;

  for (int st=0; st<nst; ++st){
    // gi prefetch for the gate phase
    const size_t ga = ((size_t)st*BB + b0 + ur  )*G3 + uj;
    const size_t gb = ((size_t)st*BB + b0 + ur+2)*G3 + uj;
    const float i0r=gi[ga], i0z=gi[ga+HH], i0n=gi[ga+2*HH];
    const float i1r=gi[gb], i1z=gi[gb+HH], i1n=gi[gb+2*HH];
    if (t < 4) mkz[t] = mask0[(size_t)st*BB + b0 + t];

    // ---- A fragments for all 8 K-steps (rows>=4 are zero) ----
    bf16x8 AH[8], AL[8];
    #pragma unroll
    for (int kt=0; kt<8; kt++){
      if (act){
        AH[kt] = *(const bf16x8*)&AhS[arow][kt*32 + kg*8];
        AL[kt] = *(const bf16x8*)&AlS[arow][kt*32 + kg*8];
      } else {
        bf16x8 z = {0,0,0,0,0,0,0,0};
        AH[kt] = z; AL[kt] = z;
      }
    }
    // ---- MFMA over this wave's 6 N-tiles ----
    #pragma unroll
    for (int nt=0; nt<6; nt++){
      const unsigned short* wp = wfbase + (size_t)nt*8*64*8;
      f32x4 acc = {0.f,0.f,0.f,0.f};
      #pragma unroll
      for (int kt=0; kt<8; kt++){
        const bf16x8 b = *(const bf16x8*)(wp + (size_t)kt*64*8);
        acc = __builtin_amdgcn_mfma_f32_16x16x32_bf16(AL[kt], b, acc, 0,0,0);
        acc = __builtin_amdgcn_mfma_f32_16x16x32_bf16(AH[kt], b, acc, 0,0,0);
      }
      if (lane < 16){
        const int col = (wid*6 + nt)*16 + lane;   // C: col=lane&15, row=i (fg==0)
        ghS[0][col] = acc[0];
        ghS[1][col] = acc[1];
        ghS[2][col] = acc[2];
        ghS[3][col] = acc[3];
      }
    }
    __syncthreads();

    // ---- gate phase: rows ur, ur+2 at column uj ----
    {
      const float ar = ghS[ur][uj]       + br;
      const float az = ghS[ur][uj+HH]    + bz;
      const float an = ghS[ur][uj+2*HH]  + bn_;
      const float rr = 1.f/(1.f + __expf(-(i0r + ar)));
      const float zz = 1.f/(1.f + __expf(-(i0z + az)));
      const float nn = tanhf(fmaf(rr, an, i0n));
      const float m  = mkz[ur];
      const float hnew = (1.f - zz)*nn + zz*hold0;
      const float hv = hnew*m + hold0*(1.f - m);
      hold0 = hv;
      unsigned short hb = f2bf_rne(hv);
      AhS[ur][uj] = hb; AlS[ur][uj] = f2bf_rne(hv - bf2f(hb));
      Hh[((size_t)st*BB + b0 + ur)*HH + uj] = hv;
    }
    {
      const int r_ = ur + 2;
      const float ar = ghS[r_][uj]       + br;
      const float az = ghS[r_][uj+HH]    + bz;
      const float an = ghS[r_][uj+2*HH]  + bn_;
      const float rr = 1.f/(1.f + __expf(-(i1r + ar)));
      const float zz = 1.f/(1.f + __expf(-(i1z + az)));
      const float nn = tanhf(fmaf(rr, an, i1n));
      const float m  = mkz[r_];
      const float hnew = (1.f - zz)*nn + zz*hold1;
      const float hv = hnew*m + hold1*(1.f - m);
      hold1 = hv;
      unsigned short hb = f2bf_rne(hv);
      AhS[r_][uj] = hb; AlS[r_][uj] = f2bf_rne(hv - bf2f(hb));
      Hh[((size_t)st*BB + b0 + r_)*HH + uj] = hv;
    }
    __syncthreads();
  }
  hcar[(size_t)(b0+ur  )*HH + uj] = hold0;
  hcar[(size_t)(b0+ur+2)*HH + uj] = hold1;
}

// ---------------------------------------------------------------------------
// Head (fused LN2): x=LN2(row); relu(x@nn1.T+b1) -> LN(8) -> @nn2.T+b2.
// ---------------------------------------------------------------------------
__global__ void head_ln_k(const float* __restrict__ hx,
                          const float* __restrict__ g2, const float* __restrict__ b2,
                          const float* __restrict__ w1, const float* __restrict__ b1,
                          const float* __restrict__ g3, const float* __restrict__ b3,
                          const float* __restrict__ w2, const float* __restrict__ b2h,
                          float* __restrict__ outp, long long r0){
  long long row = blockIdx.x;
  int t = threadIdx.x;
  float v = hx[row*HH + t];
  float s = v, q = v*v;
  #pragma unroll
  for (int o=32;o>0;o>>=1){ s += __shfl_down(s,o); q += __shfl_down(q,o); }
  __shared__ float ssm[4], qqm[4];
  int w = t >> 6;
  if ((t & 63) == 0){ ssm[w] = s; qqm[w] = q; }
  __syncthreads();
  if (t == 0){ ssm[0] = ssm[0]+ssm[1]+ssm[2]+ssm[3]; qqm[0] = qqm[0]+qqm[1]+qqm[2]+qqm[3]; }
  __syncthreads();
  s = ssm[0]; q = qqm[0];
  float mu  = s * (1.f/HH);
  float var = q * (1.f/HH) - mu*mu;
  float rs  = rsqrtf(var + EPSF);
  __shared__ float xs[HH];
  xs[t] = (v - mu)*rs*g2[t] + b2[t];
  __syncthreads();
  int o = t >> 5, l = t & 31;
  const float* wv = w1 + o*HH;
  float acc = 0.f;
  for (int k=l;k<HH;k+=32) acc = fmaf(xs[k], wv[k], acc);
  #pragma unroll
  for (int d=16;d>0;d>>=1) acc += __shfl_down(acc, d, 32);
  __shared__ float a8[8];
  if (l == 0) a8[o] = fmaxf(acc + b1[o], 0.f);
  __syncthreads();
  if (t == 0){
    float ss = 0.f;
    #pragma unroll
    for (int i=0;i<8;i++) ss += a8[i];
    float m8 = ss*0.125f;
    float qq = 0.f;
    #pragma unroll
    for (int i=0;i<8;i++){ float d = a8[i]-m8; qq = fmaf(d,d,qq); }
    float r8 = rsqrtf(qq*0.125f + EPSF);
    float y0 = b2h[0], y1 = b2h[1];
    #pragma unroll
    for (int i=0;i<8;i++){
      float vv = (a8[i]-m8)*r8*g3[i] + b3[i];
      y0 = fmaf(vv, w2[i],   y0);
      y1 = fmaf(vv, w2[8+i], y1);
    }
    outp[(r0+row)*2+0] = y0; outp[(r0+row)*2+1] = y1;
  }
}

// ---------------------------------------------------------------------------
// Host launcher. R10 = R9 structure + MFMA scan (wfrag weights).
// ---------------------------------------------------------------------------
extern "C" void kernel_launch(void* const* d_in, const int* in_sizes, int n_in,
                              void* d_out, int out_size, void* d_ws, size_t ws_size,
                              hipStream_t stream) {
  const float* X      = (const float*)d_in[0];
  const float* Mi     = (const float*)d_in[1];
  const float* mask   = (const float*)d_in[2];
  const float* i2h_w  = (const float*)d_in[3];
  const float* i2h_b  = (const float*)d_in[4];
  const float* comb_w = (const float*)d_in[5];
  const float* comb_b = (const float*)d_in[6];
  const float* down_w = (const float*)d_in[7];
  const float* down_b = (const float*)d_in[8];
  const float* conv1_w= (const float*)d_in[9];
  const float* conv1_b= (const float*)d_in[10];
  const float* conv2_w= (const float*)d_in[11];
  const float* conv2_b= (const float*)d_in[12];
  const float* bn1_g  = (const float*)d_in[13];
  const float* bn1_b  = (const float*)d_in[14];
  const float* bn2_g  = (const float*)d_in[15];
  const float* bn2_b  = (const float*)d_in[16];
  const float* r1_wih = (const float*)d_in[17];
  const float* r1_whh = (const float*)d_in[18];
  const float* r1_bih = (const float*)d_in[19];
  const float* r1_bhh = (const float*)d_in[20];
  const float* r1_cw  = (const float*)d_in[21];
  const float* r1_cb  = (const float*)d_in[22];
  const float* r2_wih = (const float*)d_in[23];
  const float* r2_whh = (const float*)d_in[24];
  const float* r2_bih = (const float*)d_in[25];
  const float* r2_bhh = (const float*)d_in[26];
  const float* r2_cw  = (const float*)d_in[27];
  const float* r2_cb  = (const float*)d_in[28];
  const float* ln1_g  = (const float*)d_in[29];
  const float* ln1_b  = (const float*)d_in[30];
  const float* ln2_g  = (const float*)d_in[31];
  const float* ln2_b  = (const float*)d_in[32];
  const float* ln3_g  = (const float*)d_in[33];
  const float* ln3_b  = (const float*)d_in[34];
  const float* nn1_w  = (const float*)d_in[35];
  const float* nn1_b  = (const float*)d_in[36];
  const float* nn2_w  = (const float*)d_in[37];
  const float* nn2_b  = (const float*)d_in[38];
  float* outp = (float*)d_out;

  // ushort region: C2{h,l} W2F{h,l} WI1{h,l} WI2{h,l} CW1{h,l} CW2{h,l} + WF1 + WF2
  const size_t us_elems = 2*((size_t)HH*HH + (size_t)HH*HH + (size_t)G3*HH
                           + (size_t)G3*HH + (size_t)HH*2*HH + (size_t)HH*2*HH)
                        + 2*(size_t)G3*HH;   // WF1/WF2: 384*64*8 = G3*HH each
  const size_t tail_floats = 2*(size_t)BB*HH + 2*(size_t)NPART*HH + 2*HH
                           + (size_t)256*40 + 256 + (size_t)HH*HH + 256
                           + (size_t)SB*CC
                           + (us_elems + 1)/2;
  // per-chunk rows: A(256) + GI1(768, Cxp aliased) + GI2(768) + Ee(256)
  //               + Hh2(256) + Hx1(256) = 2560 floats/row
  int cands[6] = {256,128,64,32,16,8};
  int sc_chunk = 0;
  for (int ci=0; ci<6; ci++){
    size_t R = (size_t)512*cands[ci];
    size_t need = (R*2560 + tail_floats)*sizeof(float);
    if (need <= ws_size && R*2560 >= (size_t)SB*HH){ sc_chunk = cands[ci]; break; }
  }
  if (!sc_chunk) return;

  const size_t R = (size_t)512*sc_chunk;     // rows per chunk
  const int Ri = (int)R;
  const int nchunks = SB / Ri;

  float* wsf = (float*)d_ws;
  float* A   = wsf;                    // R*256  (res -> hx)
  float* GI1 = A + R*HH;               // R*768  gi for GRU1(c)
  float* Cxp = GI1;                    // ALIAS: GI1 dead after scan; Cxp lives after
  float* GI2 = GI1 + R*G3;             // R*768  gi for GRU2(c)
  float* Ee  = GI2 + R*G3;             // R*256  out1r -> Hh1
  float* Hh2 = Ee + R*HH;              // R*256  Hh of GRU2(c-1)
  float* Hx1 = Hh2 + R*HH;             // R*256  hx1(c) = LN1 out
  float* tl  = Hx1 + R*HH;
  float* H1C = tl;                     // BB*HH
  float* H2C = H1C + (size_t)BB*HH;
  float* PS  = H2C + (size_t)BB*HH;    // NPART*HH
  float* PQ  = PS  + (size_t)NPART*HH;
  float* SCv = PQ  + (size_t)NPART*HH; // HH
  float* SHv = SCv + HH;
  float* W1F = SHv + HH;               // 256*40
  float* B1F = W1F + (size_t)256*40;   // 256
  float* W2F = B1F + HH;               // 256*256
  float* B2F = W2F + (size_t)HH*HH;    // 256
  float* XcF = B2F + HH;               // SB*40 persisted comb output
  unsigned short* usb = (unsigned short*)(XcF + (size_t)SB*CC);
  unsigned short* C2H  = usb;                       // conv2_w raw split (HH*HH)
  unsigned short* C2L  = C2H  + (size_t)HH*HH;
  unsigned short* W2FH = C2L  + (size_t)HH*HH;      // folded conv2 (HH*HH)
  unsigned short* W2FL = W2FH + (size_t)HH*HH;
  unsigned short* WI1H = W2FL + (size_t)HH*HH;      // r1_wih (G3*HH)
  unsigned short* WI1L = WI1H + (size_t)G3*HH;
  unsigned short* WI2H = WI1L + (size_t)G3*HH;      // r2_wih (G3*HH)
  unsigned short* WI2L = WI2H + (size_t)G3*HH;
  unsigned short* CW1H = WI2L + (size_t)G3*HH;      // r1_cw (HH*2HH)
  unsigned short* CW1L = CW1H + (size_t)HH*2*HH;
  unsigned short* CW2H = CW1L + (size_t)HH*2*HH;    // r2_cw (HH*2HH)
  unsigned short* CW2L = CW2H + (size_t)HH*2*HH;
  unsigned short* WF1  = CW2L + (size_t)HH*2*HH;    // whh MFMA frags (GRU1)
  unsigned short* WF2  = WF1 + (size_t)G3*HH;       // whh MFMA frags (GRU2)

  // one-time weight prep
  wfrag_k<<<(384*64 + 255)/256, 256, 0, stream>>>(r1_whh, WF1);
  wfrag_k<<<(384*64 + 255)/256, 256, 0, stream>>>(r2_whh, WF2);
  split_w_k<<<(HH*HH + 255)/256, 256, 0, stream>>>(conv2_w, C2H, C2L, HH*HH);
  split_w_k<<<(G3*HH + 255)/256, 256, 0, stream>>>(r1_wih, WI1H, WI1L, G3*HH);
  split_w_k<<<(G3*HH + 255)/256, 256, 0, stream>>>(r2_wih, WI2H, WI2L, G3*HH);
  split_w_k<<<(HH*2*HH + 255)/256, 256, 0, stream>>>(r1_cw, CW1H, CW1L, HH*2*HH);
  split_w_k<<<(HH*2*HH + 255)/256, 256, 0, stream>>>(r2_cw, CW2H, CW2L, HH*2*HH);

  const int MB = Ri/128;

  // ---------- pass A: ONE sweep over all SB rows (scratch = per-chunk region) ----------
  {
    float* SA = wsf;                          // SB*HH scratch (fits in per-chunk region)
    gemm_tn<0,1><<<dim3(SB/128,1), 256, 0, stream>>>(X, II, comb_w, 80, comb_b, XcF, CC, SB, CC, 80, Mi, 0);
    gemm_tn<0,0><<<dim3(SB/128,2), 256, 0, stream>>>(XcF, CC, conv1_w, CC, conv1_b, SA, HH, SB, HH, CC, nullptr, 0);
    bn_partial_k<<<SB/64, 256, 0, stream>>>(SA, PS, PQ, 0);
  }
  bn_final_k<<<1, 256, 0, stream>>>(PS, PQ, bn1_g, bn1_b, SCv, SHv);
  fold_k<<<(256*40 + 255)/256, 256, 0, stream>>>(conv1_w, conv1_b, SCv, SHv, W1F, B1F, 40);

  // ---------- pass B: TWO half-sweeps ----------
  {
    float* SA2 = wsf;                         // SB/2*HH
    float* SB2 = wsf + (size_t)(SB/2)*HH;     // SB/2*HH
    for (int hlf=0; hlf<2; hlf++){
      long long r0 = (long long)hlf*(SB/2);
      gemm_tn<1,0><<<dim3(SB/256,2), 256, 0, stream>>>(XcF + r0*CC, CC, W1F, CC, B1F, SA2, HH, SB/2, HH, CC, nullptr, 0);
      gemm_mfp<0><<<dim3(SB/256,2), 256, 0, stream>>>(SA2, HH, C2H, C2L, HH, conv2_b, SB2, HH, HH, HH);
      bn_partial_k<<<(SB/2)/64, 256, 0, stream>>>(SB2, PS, PQ, (int)(r0/64));
    }
  }
  bn_final_k<<<1, 256, 0, stream>>>(PS, PQ, bn2_g, bn2_b, SCv, SHv);
  fold_k<<<(256*256 + 255)/256, 256, 0, stream>>>(conv2_w, conv2_b, SCv, SHv, W2F, B2F, 256);
  split_w_k<<<(HH*HH + 255)/256, 256, 0, stream>>>(W2F, W2FH, W2FL, HH*HH);

  // ---------- h0 -> carries ----------
  h0_k<<<BB, HH, 0, stream>>>(X, i2h_w, i2h_b, H1C, H2C);

  // ---------- pass C: pipelined main loop ----------
  for (int c=0;c<nchunks;c++){
    long long r0 = (long long)c*R;
    long long rp = r0 - (long long)R;   // previous chunk base (valid for c>0)
    // ---- S1(c): {res, out1r} fused, then hx, gi1
    gemm_tn_dual2<<<dim3(MB,2), 256, 0, stream>>>(X, r0, down_w, down_b, A,
                                                  XcF + r0*CC, W1F, B1F, Ee, Ri);
    gemm_mfp<2><<<dim3(MB,2), 256, 0, stream>>>(Ee, HH, W2FH, W2FL, HH, B2F, A, HH, HH, HH);     // hx
    gemm_mfp<0><<<dim3(MB,6), 256, 0, stream>>>(A, HH, WI1H, WI1L, HH, r1_bih, GI1, G3, G3, HH); // gi1
    // ---- fused scan: GRU1(c) || GRU2(c-1)
    gru_scan_mfma_k<<<2*(BB/4), 512, 0, stream>>>(
        GI1, WF1, r1_bhh, mask + r0, H1C, Ee, sc_chunk,
        GI2, WF2, r2_bhh, (c > 0) ? (mask + rp) : mask, H2C, Hh2, (c > 0) ? sc_chunk : 0);
    // ---- S3(c-1): finish previous chunk (Cxp = GI1 region, dead after scan)
    if (c > 0){
      gemm_mfp_dual<<<dim3(MB,2), 256, 0, stream>>>(Hx1, Hh2, CW2H, CW2L, r2_cb, Cxp, HH, HH);   // outs2
      head_ln_k<<<Ri, 256, 0, stream>>>(Cxp, ln2_g, ln2_b, nn1_w, nn1_b, ln3_g, ln3_b, nn2_w, nn2_b, outp, rp);
    }
    // ---- S2(c): GRU1 out-projection, LN1, gi2(c)
    gemm_mfp_dual<<<dim3(MB,2), 256, 0, stream>>>(A, Ee, CW1H, CW1L, r1_cb, Cxp, HH, HH);        // outs1
    ln_rows_k<<<Ri, 256, 0, stream>>>(Cxp, Hx1, ln1_g, ln1_b);                                    // hx1(c)
    gemm_mfp<0><<<dim3(MB,6), 256, 0, stream>>>(Hx1, HH, WI2H, WI2L, HH, r2_bih, GI2, G3, G3, HH); // gi2(c)
  }
  // ---------- drain: GRU2(last chunk) ----------
  {
    long long rl = (long long)(nchunks-1)*R;
    gru_scan_mfma_k<<<2*(BB/4), 512, 0, stream>>>(
        GI1, WF1, r1_bhh, mask, H1C, Ee, 0,
        GI2, WF2, r2_bhh, mask + rl, H2C, Hh2, sc_chunk);
    gemm_mfp_dual<<<dim3(MB,2), 256, 0, stream>>>(Hx1, Hh2, CW2H, CW2L, r2_cb, Cxp, HH, HH);
    head_ln_k<<<Ri, 256, 0, stream>>>(Cxp, ln2_g, ln2_b, nn1_w, nn1_b, ln3_g, ln3_b, nn2_w, nn2_b, outp, rl);
  }
}